// Round 2
// baseline (4723.940 us; speedup 1.0000x reference)
//
#include <hip/hip_runtime.h>
#include <math.h>

#define D_ 1024
#define DI_ 2048
#define HS_ 16
#define PS_ 128
#define NS_ 64
#define HA_ 16
#define HKV_ 4
#define PA_ 64
#define B_ 2
#define L_ 2048
#define NT_ 4096          // B_*L_
#define NC_ 32            // L_/64
#define RMS_EPS_ 1.1920929e-7f

// ---------------- mix + rmsnorm ----------------
__global__ __launch_bounds__(256) void mix_rms_kernel(
    const float* __restrict__ a, const float* __restrict__ b2,
    const float* __restrict__ mix, float* __restrict__ xout,
    float* __restrict__ nout) {
  int row = blockIdx.x;
  size_t base = (size_t)row * D_;
  float v[4]; float ss = 0.f;
#pragma unroll
  for (int i = 0; i < 4; i++) {
    int d = threadIdx.x + i * 256;
    float val = mix[d] * a[base + d] + mix[D_ + d] * b2[base + d];
    v[i] = val; ss += val * val;
  }
  for (int o = 32; o > 0; o >>= 1) ss += __shfl_down(ss, o, 64);
  __shared__ float red[4];
  if ((threadIdx.x & 63) == 0) red[threadIdx.x >> 6] = ss;
  __syncthreads();
  float inv = rsqrtf((red[0] + red[1] + red[2] + red[3]) * (1.f / D_) + RMS_EPS_);
#pragma unroll
  for (int i = 0; i < 4; i++) {
    int d = threadIdx.x + i * 256;
    xout[base + d] = v[i];
    nout[base + d] = v[i] * inv;
  }
}

__global__ __launch_bounds__(256) void rms_kernel(
    const float* __restrict__ a, float* __restrict__ nout) {
  int row = blockIdx.x;
  size_t base = (size_t)row * D_;
  float v[4]; float ss = 0.f;
#pragma unroll
  for (int i = 0; i < 4; i++) {
    int d = threadIdx.x + i * 256;
    float val = a[base + d];
    v[i] = val; ss += val * val;
  }
  for (int o = 32; o > 0; o >>= 1) ss += __shfl_down(ss, o, 64);
  __shared__ float red[4];
  if ((threadIdx.x & 63) == 0) red[threadIdx.x >> 6] = ss;
  __syncthreads();
  float inv = rsqrtf((red[0] + red[1] + red[2] + red[3]) * (1.f / D_) + RMS_EPS_);
#pragma unroll
  for (int i = 0; i < 4; i++) {
    int d = threadIdx.x + i * 256;
    nout[base + d] = v[i] * inv;
  }
}

// ---------------- GEMM: C[M,N] = epi(A[M,K] @ W[K,N]) ----------------
// M,N multiples of 128; K multiple of 16. epi: 0=none, 1=relu-then-square
__global__ __launch_bounds__(256) void gemm_f32(
    const float* __restrict__ A, const float* __restrict__ W,
    float* __restrict__ C, int M, int N, int K, int epi) {
  __shared__ __align__(16) float As[16 * 132];
  __shared__ __align__(16) float Ws[16 * 132];
  int bm = blockIdx.y * 128, bn = blockIdx.x * 128;
  int tid = threadIdx.x;
  int tx = tid & 15, ty = tid >> 4;
  float acc[8][8];
#pragma unroll
  for (int i = 0; i < 8; i++)
#pragma unroll
    for (int j = 0; j < 8; j++) acc[i][j] = 0.f;
  const float4* A4 = (const float4*)A;
  const float4* W4 = (const float4*)W;
  int Kq = K >> 2, Nq = N >> 2;
  for (int k0 = 0; k0 < K; k0 += 16) {
#pragma unroll
    for (int i = 0; i < 2; i++) {
      int e = tid + i * 256;
      int m = e >> 2, kq = e & 3;
      float4 av = A4[(size_t)(bm + m) * Kq + (k0 >> 2) + kq];
      As[(kq * 4 + 0) * 132 + m] = av.x;
      As[(kq * 4 + 1) * 132 + m] = av.y;
      As[(kq * 4 + 2) * 132 + m] = av.z;
      As[(kq * 4 + 3) * 132 + m] = av.w;
    }
#pragma unroll
    for (int i = 0; i < 2; i++) {
      int e = tid + i * 256;
      int kk = e >> 5, n4 = e & 31;
      *(float4*)&Ws[kk * 132 + n4 * 4] = W4[(size_t)(k0 + kk) * Nq + (bn >> 2) + n4];
    }
    __syncthreads();
#pragma unroll
    for (int kk = 0; kk < 16; kk++) {
      float4 a0 = *(const float4*)&As[kk * 132 + ty * 8];
      float4 a1 = *(const float4*)&As[kk * 132 + ty * 8 + 4];
      float4 w0 = *(const float4*)&Ws[kk * 132 + tx * 8];
      float4 w1 = *(const float4*)&Ws[kk * 132 + tx * 8 + 4];
      float av[8] = {a0.x, a0.y, a0.z, a0.w, a1.x, a1.y, a1.z, a1.w};
      float wv[8] = {w0.x, w0.y, w0.z, w0.w, w1.x, w1.y, w1.z, w1.w};
#pragma unroll
      for (int i = 0; i < 8; i++)
#pragma unroll
        for (int j = 0; j < 8; j++) acc[i][j] += av[i] * wv[j];
    }
    __syncthreads();
  }
#pragma unroll
  for (int i = 0; i < 8; i++) {
    size_t ro = (size_t)(bm + ty * 8 + i) * N + bn + tx * 8;
    float r[8];
#pragma unroll
    for (int j = 0; j < 8; j++) {
      float vv = acc[i][j];
      if (epi == 1) { vv = fmaxf(vv, 0.f); vv = vv * vv; }
      r[j] = vv;
    }
    *(float4*)&C[ro] = make_float4(r[0], r[1], r[2], r[3]);
    *(float4*)&C[ro + 4] = make_float4(r[4], r[5], r[6], r[7]);
  }
}

// ---------------- depthwise causal conv (KC=4) + SiLU ----------------
__global__ __launch_bounds__(256) void conv_silu_kernel(
    const float* __restrict__ vg, const float* __restrict__ cw,
    const float* __restrict__ cb, float* __restrict__ xv) {
  int idx = blockIdx.x * 256 + threadIdx.x;   // over NT_*DI_
  int c = idx & (DI_ - 1);
  int bl = idx >> 11;
  int l = bl & (L_ - 1);
  float acc = cb[c];
  float w0 = cw[c * 4 + 0], w1 = cw[c * 4 + 1], w2 = cw[c * 4 + 2], w3 = cw[c * 4 + 3];
  size_t rb = (size_t)bl * (2 * DI_) + c;
  if (l >= 3) acc += vg[rb - (size_t)3 * 2 * DI_] * w0;
  if (l >= 2) acc += vg[rb - (size_t)2 * 2 * DI_] * w1;
  if (l >= 1) acc += vg[rb - (size_t)1 * 2 * DI_] * w2;
  acc += vg[rb] * w3;
  xv[idx] = acc / (1.f + __expf(-acc));
}

// ---------------- scan pass A1: per-chunk states ----------------
__global__ __launch_bounds__(256) void scanA1_kernel(
    const float* __restrict__ xv, const float* __restrict__ Bm,
    const float* __restrict__ dt_bias, const float* __restrict__ A_log,
    float* __restrict__ st) {
  __shared__ __align__(16) float sm[4096 + 8192];
  float* Bs = sm;
  float* Xs = sm + 4096;
  int blk = blockIdx.x;
  int c = blk & 31, h = (blk >> 5) & 15, b = blk >> 9;
  float dt = log1pf(__expf(dt_bias[h]));
  float adt = -__expf(A_log[h]) * dt;
  int tid = threadIdx.x;
  int l0 = c * 64;
  size_t rB = ((size_t)(b * L_ + l0)) * (HS_ * NS_) + h * NS_;
#pragma unroll
  for (int i = 0; i < 16; i++) {
    int e = tid + i * 256;
    int t = e >> 6, n = e & 63;
    Bs[t * 64 + n] = Bm[rB + (size_t)t * (HS_ * NS_) + n];
  }
  size_t rX = ((size_t)(b * L_ + l0)) * DI_ + h * PS_;
#pragma unroll
  for (int i = 0; i < 32; i++) {
    int e = tid + i * 256;
    int t = e >> 7, p = e & 127;
    Xs[t * 128 + p] = xv[rX + (size_t)t * DI_ + p];
  }
  __syncthreads();
  int pg = tid & 31;
  int ng = (tid >> 5) << 3;
  float acc[8][4];
#pragma unroll
  for (int nn = 0; nn < 8; nn++)
#pragma unroll
    for (int i = 0; i < 4; i++) acc[nn][i] = 0.f;
  for (int t = 0; t < 64; t++) {
    float dr = __expf(adt * (float)(63 - t));
    float4 x4 = *(const float4*)&Xs[t * 128 + pg * 4];
    float xd0 = x4.x * dr, xd1 = x4.y * dr, xd2 = x4.z * dr, xd3 = x4.w * dr;
#pragma unroll
    for (int nn = 0; nn < 8; nn++) {
      float bv = Bs[t * 64 + ng + nn];
      acc[nn][0] += bv * xd0; acc[nn][1] += bv * xd1;
      acc[nn][2] += bv * xd2; acc[nn][3] += bv * xd3;
    }
  }
  size_t sb = ((size_t)((b * HS_ + h) * NC_ + c)) * (NS_ * PS_);
#pragma unroll
  for (int nn = 0; nn < 8; nn++) {
    *(float4*)&st[sb + (size_t)(ng + nn) * PS_ + pg * 4] =
        make_float4(acc[nn][0] * dt, acc[nn][1] * dt, acc[nn][2] * dt, acc[nn][3] * dt);
  }
}

// ---------------- scan pass A2: intra-chunk y_diag + D*x ----------------
__global__ __launch_bounds__(256) void scanA2_kernel(
    const float* __restrict__ xv, const float* __restrict__ Bm,
    const float* __restrict__ Cm, const float* __restrict__ dt_bias,
    const float* __restrict__ A_log, const float* __restrict__ D_param,
    float* __restrict__ y) {
  __shared__ __align__(16) float sm[4160 + 8192];
  float* Cb = sm;          // [64][65]: first Cm tile, then CBL (padded)
  float* Bs = sm + 4160;   // [64][64] phase 1
  float* Xs = sm + 4160;   // [64][128] phase 2 (overwrites Bs)
  int blk = blockIdx.x;
  int c = blk & 31, h = (blk >> 5) & 15, b = blk >> 9;
  float dt = log1pf(__expf(dt_bias[h]));
  float adt = -__expf(A_log[h]) * dt;
  float Dp = D_param[h];
  int tid = threadIdx.x;
  int l0 = c * 64;
  size_t rB = ((size_t)(b * L_ + l0)) * (HS_ * NS_) + h * NS_;
#pragma unroll
  for (int i = 0; i < 16; i++) {
    int e = tid + i * 256;
    int t = e >> 6, n = e & 63;
    Bs[t * 64 + n] = Bm[rB + (size_t)t * (HS_ * NS_) + n];
    Cb[t * 65 + n] = Cm[rB + (size_t)t * (HS_ * NS_) + n];
  }
  __syncthreads();
  int q = tid >> 2;
  int kb = (tid & 3) << 4;
  float cbl[16];
#pragma unroll
  for (int kk = 0; kk < 16; kk++) {
    int k = kb + kk;
    float a = 0.f;
    if (k <= q) {
      for (int n = 0; n < 64; n++) a += Cb[q * 65 + n] * Bs[k * 64 + n];
      a *= __expf(adt * (float)(q - k));
    }
    cbl[kk] = a;
  }
  __syncthreads();
#pragma unroll
  for (int kk = 0; kk < 16; kk++) Cb[q * 65 + kb + kk] = cbl[kk];
  size_t rX = ((size_t)(b * L_ + l0)) * DI_ + h * PS_;
#pragma unroll
  for (int i = 0; i < 32; i++) {
    int e = tid + i * 256;
    int t = e >> 7, p = e & 127;
    Xs[t * 128 + p] = xv[rX + (size_t)t * DI_ + p];
  }
  __syncthreads();
  int pg = tid & 31;
  int qg = (tid >> 5) << 3;
  float acc[8][4];
#pragma unroll
  for (int qq = 0; qq < 8; qq++)
#pragma unroll
    for (int i = 0; i < 4; i++) acc[qq][i] = 0.f;
  for (int k = 0; k < 64; k++) {
    float4 x4 = *(const float4*)&Xs[k * 128 + pg * 4];
#pragma unroll
    for (int qq = 0; qq < 8; qq++) {
      float s = Cb[(qg + qq) * 65 + k];
      acc[qq][0] += s * x4.x; acc[qq][1] += s * x4.y;
      acc[qq][2] += s * x4.z; acc[qq][3] += s * x4.w;
    }
  }
#pragma unroll
  for (int qq = 0; qq < 8; qq++) {
    int qr = qg + qq;
    float4 xq = *(const float4*)&Xs[qr * 128 + pg * 4];
    size_t yo = ((size_t)(b * L_ + l0 + qr)) * DI_ + h * PS_ + pg * 4;
    *(float4*)&y[yo] = make_float4(acc[qq][0] * dt + Dp * xq.x,
                                   acc[qq][1] * dt + Dp * xq.y,
                                   acc[qq][2] * dt + Dp * xq.z,
                                   acc[qq][3] * dt + Dp * xq.w);
  }
}

// ---------------- scan pass B1: inter-chunk recurrence (in-place) ----------------
__global__ __launch_bounds__(256) void scanB1_kernel(
    float* __restrict__ st, const float* __restrict__ dt_bias,
    const float* __restrict__ A_log) {
  int h = blockIdx.x & 15, b = blockIdx.x >> 4;
  float dt = log1pf(__expf(dt_bias[h]));
  float adt = -__expf(A_log[h]) * dt;
  float cdec = __expf(adt * 64.f);
  size_t base = ((size_t)(b * HS_ + h)) * NC_ * (NS_ * PS_);
  float hreg[32];
#pragma unroll
  for (int j = 0; j < 32; j++) hreg[j] = 0.f;
  for (int c = 0; c < NC_; c++) {
    size_t o = base + (size_t)c * (NS_ * PS_) + threadIdx.x;
#pragma unroll
    for (int j = 0; j < 32; j++) {
      float tmp = st[o + (size_t)j * 256];
      st[o + (size_t)j * 256] = hreg[j];
      hreg[j] = cdec * hreg[j] + tmp;
    }
  }
}

// ---------------- scan pass B2: y_off + gate SiLU ----------------
__global__ __launch_bounds__(256) void scanB2_kernel(
    const float* __restrict__ Cm, const float* __restrict__ st,
    const float* __restrict__ vg, const float* __restrict__ dt_bias,
    const float* __restrict__ A_log, float* __restrict__ y) {
  __shared__ float Cs[64 * 64];
  __shared__ __align__(16) float Hs[64 * 128];
  int blk = blockIdx.x;
  int c = blk & 31, h = (blk >> 5) & 15, b = blk >> 9;
  float dt = log1pf(__expf(dt_bias[h]));
  float adt = -__expf(A_log[h]) * dt;
  int tid = threadIdx.x;
  int l0 = c * 64;
  size_t rC = ((size_t)(b * L_ + l0)) * (HS_ * NS_) + h * NS_;
#pragma unroll
  for (int i = 0; i < 16; i++) {
    int e = tid + i * 256;
    int t = e >> 6, n = e & 63;
    Cs[t * 64 + n] = Cm[rC + (size_t)t * (HS_ * NS_) + n];
  }
  size_t sb = ((size_t)((b * HS_ + h) * NC_ + c)) * (NS_ * PS_);
#pragma unroll
  for (int i = 0; i < 32; i++) {
    int e = tid + i * 256;
    Hs[e] = st[sb + e];
  }
  __syncthreads();
  int pg = tid & 31;
  int tg = (tid >> 5) << 3;
  float acc[8][4];
#pragma unroll
  for (int tt = 0; tt < 8; tt++)
#pragma unroll
    for (int i = 0; i < 4; i++) acc[tt][i] = 0.f;
  for (int n = 0; n < 64; n++) {
    float4 h4 = *(const float4*)&Hs[n * 128 + pg * 4];
#pragma unroll
    for (int tt = 0; tt < 8; tt++) {
      float cv = Cs[(tg + tt) * 64 + n];
      acc[tt][0] += cv * h4.x; acc[tt][1] += cv * h4.y;
      acc[tt][2] += cv * h4.z; acc[tt][3] += cv * h4.w;
    }
  }
#pragma unroll
  for (int tt = 0; tt < 8; tt++) {
    int t = tg + tt;
    float dout = __expf(adt * (float)(t + 1));
    size_t row = (size_t)(b * L_ + l0 + t);
#pragma unroll
    for (int i = 0; i < 4; i++) {
      int p = pg * 4 + i;
      float g = vg[row * (2 * DI_) + DI_ + h * PS_ + p];
      float yv = y[row * DI_ + h * PS_ + p] + acc[tt][i] * dout;
      y[row * DI_ + h * PS_ + p] = yv * (g / (1.f + __expf(-g)));
    }
  }
}

// ---------------- residual add: dst = base + scale[d]*src ----------------
__global__ __launch_bounds__(256) void add_scaled_kernel(
    const float* __restrict__ base, const float* __restrict__ src,
    const float* __restrict__ scale, float* __restrict__ dst) {
  size_t idx = (size_t)blockIdx.x * 256 + threadIdx.x;
  int d = (int)(idx & (D_ - 1));
  dst[idx] = base[idx] + scale[d] * src[idx];
}

// ---------------- rope tables ----------------
__global__ void rope_fill_kernel(float* __restrict__ cosb, float* __restrict__ sinb) {
  int idx = blockIdx.x * 256 + threadIdx.x;   // L_*32
  int i = idx & 31, l = idx >> 5;
  float inv = __expf(-(2.0f * (float)i / (float)PA_) * logf(10000.0f));
  float ang = (float)l * inv;
  cosb[idx] = cosf(ang);
  sinb[idx] = sinf(ang);
}

// ---------------- per-head rmsnorm + rope (+gain) in place ----------------
__global__ __launch_bounds__(256) void qknorm_rope_kernel(
    float* __restrict__ buf, int nh, const float* __restrict__ cosb,
    const float* __restrict__ sinb, const float* __restrict__ gain) {
  int row = blockIdx.x * 4 + (threadIdx.x >> 6);
  int lane = threadIdx.x & 63;
  int h = row % nh;
  int l = (row / nh) & (L_ - 1);
  float v = buf[(size_t)row * PA_ + lane];
  float ss = v * v;
  for (int o = 32; o > 0; o >>= 1) ss += __shfl_xor(ss, o, 64);
  v *= rsqrtf(ss * (1.f / PA_) + RMS_EPS_);
  float partner = __shfl_xor(v, 32, 64);
  int i = lane & 31;
  float cth = cosb[l * 32 + i], sth = sinb[l * 32 + i];
  float out = (lane < 32) ? (v * cth + partner * sth) : (v * cth - partner * sth);
  if (gain) out *= gain[h];
  buf[(size_t)row * PA_ + lane] = out;
}

// ---------------- causal GQA flash attention (fp32) ----------------
__global__ __launch_bounds__(256) void attn_kernel(
    const float* __restrict__ qb, const float* __restrict__ kb,
    const float* __restrict__ vb, float* __restrict__ ao) {
  __shared__ float Qs[32 * 65];
  __shared__ float Ks[64 * 65];
  __shared__ __align__(16) float Vs[64 * 64];
  __shared__ float Ss[32 * 65];
  int blk = blockIdx.x;
  int qt = blk & 63;                    // L_/32 = 64
  int h = (blk >> 6) & 15;
  int b = blk >> 10;
  int hk = h >> 2;                      // HA_/HKV_ = 4
  int q0 = qt * 32;
  int tid = threadIdx.x;
  int ty = tid >> 3, tx = tid & 7;
#pragma unroll
  for (int i = 0; i < 8; i++) {
    int e = tid + i * 256;
    int r = e >> 6, cc = e & 63;
    Qs[r * 65 + cc] = qb[((size_t)(b * L_ + q0 + r) * HA_ + h) * PA_ + cc] * 0.125f;
  }
  float o0[8];
#pragma unroll
  for (int j = 0; j < 8; j++) o0[j] = 0.f;
  float m = -3.0e38f, lsum = 0.f;
  int nkt = (q0 + 32 + 63) >> 6;
  for (int kt = 0; kt < nkt; kt++) {
    int k0 = kt * 64;
    __syncthreads();
#pragma unroll
    for (int i = 0; i < 16; i++) {
      int e = tid + i * 256;
      int r = e >> 6, cc = e & 63;
      size_t kro = ((size_t)(b * L_ + k0 + r) * HKV_ + hk) * PA_ + cc;
      Ks[r * 65 + cc] = kb[kro];
      Vs[r * 64 + cc] = vb[kro];
    }
    __syncthreads();
    float sc[8];
    float tmax = -3.0e38f;
#pragma unroll
    for (int jj = 0; jj < 8; jj++) {
      int k = tx * 8 + jj;
      float a = 0.f;
      for (int n = 0; n < 64; n++) a += Qs[ty * 65 + n] * Ks[k * 65 + n];
      if (k0 + k > q0 + ty) a = -3.0e38f;
      sc[jj] = a;
      tmax = fmaxf(tmax, a);
    }
    for (int of = 4; of > 0; of >>= 1) tmax = fmaxf(tmax, __shfl_xor(tmax, of, 8));
    float mnew = fmaxf(m, tmax);
    float corr = __expf(m - mnew);
    float rs = 0.f;
#pragma unroll
    for (int jj = 0; jj < 8; jj++) {
      float p = __expf(sc[jj] - mnew);
      Ss[ty * 65 + tx * 8 + jj] = p;
      rs += p;
    }
    for (int of = 4; of > 0; of >>= 1) rs += __shfl_xor(rs, of, 8);
    lsum = lsum * corr + rs;
    m = mnew;
#pragma unroll
    for (int j = 0; j < 8; j++) o0[j] *= corr;
    __syncthreads();
    for (int n = 0; n < 64; n++) {
      float p = Ss[ty * 65 + n];
      float4 va = *(const float4*)&Vs[n * 64 + tx * 8];
      float4 vb4 = *(const float4*)&Vs[n * 64 + tx * 8 + 4];
      o0[0] += p * va.x; o0[1] += p * va.y; o0[2] += p * va.z; o0[3] += p * va.w;
      o0[4] += p * vb4.x; o0[5] += p * vb4.y; o0[6] += p * vb4.z; o0[7] += p * vb4.w;
    }
  }
  float invl = 1.0f / lsum;
  size_t oo = ((size_t)(b * L_ + q0 + ty) * HA_ + h) * PA_ + tx * 8;
  *(float4*)&ao[oo] = make_float4(o0[0] * invl, o0[1] * invl, o0[2] * invl, o0[3] * invl);
  *(float4*)&ao[oo + 4] = make_float4(o0[4] * invl, o0[5] * invl, o0[6] * invl, o0[7] * invl);
}

// ---------------- host ----------------
extern "C" void kernel_launch(void* const* d_in, const int* in_sizes, int n_in,
                              void* d_out, int out_size, void* d_ws, size_t ws_size,
                              hipStream_t stream) {
  (void)in_sizes; (void)n_in; (void)out_size; (void)ws_size;
  const float* x           = (const float*)d_in[0];
  const float* in_proj_w   = (const float*)d_in[1];
  const float* conv_w      = (const float*)d_in[2];
  const float* conv_b      = (const float*)d_in[3];
  const float* B_proj_w    = (const float*)d_in[4];
  const float* C_proj_w    = (const float*)d_in[5];
  const float* dt_bias     = (const float*)d_in[6];
  const float* A_log       = (const float*)d_in[7];
  const float* D_param     = (const float*)d_in[8];
  const float* out_proj_w  = (const float*)d_in[9];
  const float* resid_mix_m = (const float*)d_in[10];
  const float* mamba_scale = (const float*)d_in[11];
  const float* m_fc_w      = (const float*)d_in[12];
  const float* m_proj_w    = (const float*)d_in[13];
  const float* m_mlp_scale = (const float*)d_in[14];
  const float* resid_mix_a = (const float*)d_in[15];
  const float* q_w         = (const float*)d_in[16];
  const float* k_w         = (const float*)d_in[17];
  const float* v_w         = (const float*)d_in[18];
  const float* o_w         = (const float*)d_in[19];
  const float* q_gain      = (const float*)d_in[20];
  const float* attn_scale  = (const float*)d_in[21];
  const float* a_fc_w      = (const float*)d_in[22];
  const float* a_proj_w    = (const float*)d_in[23];
  const float* a_mlp_scale = (const float*)d_in[24];
  float* ws  = (float*)d_ws;
  float* out = (float*)d_out;

  // ---- workspace layout: 14*NTD + 2*L_*32 floats = 224.5 MiB total ----
  const size_t NTD = (size_t)NT_ * D_;           // 4,194,304
  float* xm   = ws;                              // 1 NTD (becomes xa in-place)
  float* nb   = ws + 1 * NTD;                    // 1
  float* vg   = ws + 2 * NTD;                    // 4 (in_proj out / MLP hidden / ao)
  float* xv   = ws + 6 * NTD;                    // 2 (conv out / q,k,v)
  float* Bmb  = ws + 8 * NTD;                    // 1
  float* Cmb  = ws + 9 * NTD;                    // 1
  float* yb   = ws + 10 * NTD;                   // 2
  float* st   = ws + 12 * NTD;                   // 2 (t1 aliases after scan)
  float* cosb = ws + 14 * NTD;                   // L_*32
  float* sinb = cosb + (size_t)L_ * 32;          // L_*32
  float* t1   = st;                              // states dead before first t1 use
  float* qbuf = xv;                              // conv out dead after scanA2
  float* kbuf = xv + NTD;
  float* vbuf = kbuf + (size_t)NT_ * HKV_ * PA_;
  float* ao   = vg;                              // gate/hidden dead by attn time

  // --- mamba branch ---
  mix_rms_kernel<<<NT_, 256, 0, stream>>>(x, x, resid_mix_m, xm, nb);
  gemm_f32<<<dim3(2 * DI_ / 128, NT_ / 128), 256, 0, stream>>>(nb, in_proj_w, vg, NT_, 2 * DI_, D_, 0);
  gemm_f32<<<dim3(HS_ * NS_ / 128, NT_ / 128), 256, 0, stream>>>(xm, B_proj_w, Bmb, NT_, HS_ * NS_, D_, 0);
  gemm_f32<<<dim3(HS_ * NS_ / 128, NT_ / 128), 256, 0, stream>>>(xm, C_proj_w, Cmb, NT_, HS_ * NS_, D_, 0);
  conv_silu_kernel<<<NT_ * DI_ / 256, 256, 0, stream>>>(vg, conv_w, conv_b, xv);
  scanA1_kernel<<<B_ * HS_ * NC_, 256, 0, stream>>>(xv, Bmb, dt_bias, A_log, st);
  scanA2_kernel<<<B_ * HS_ * NC_, 256, 0, stream>>>(xv, Bmb, Cmb, dt_bias, A_log, D_param, yb);
  scanB1_kernel<<<B_ * HS_, 256, 0, stream>>>(st, dt_bias, A_log);
  scanB2_kernel<<<B_ * HS_ * NC_, 256, 0, stream>>>(Cmb, st, vg, dt_bias, A_log, yb);
  gemm_f32<<<dim3(D_ / 128, NT_ / 128), 256, 0, stream>>>(yb, out_proj_w, t1, NT_, D_, DI_, 0);
  add_scaled_kernel<<<NT_ * D_ / 256, 256, 0, stream>>>(xm, t1, mamba_scale, xm);
  // --- mamba MLP ---
  rms_kernel<<<NT_, 256, 0, stream>>>(xm, nb);
  gemm_f32<<<dim3(4 * D_ / 128, NT_ / 128), 256, 0, stream>>>(nb, m_fc_w, vg, NT_, 4 * D_, D_, 1);
  gemm_f32<<<dim3(D_ / 128, NT_ / 128), 256, 0, stream>>>(vg, m_proj_w, t1, NT_, D_, 4 * D_, 0);
  add_scaled_kernel<<<NT_ * D_ / 256, 256, 0, stream>>>(xm, t1, m_mlp_scale, xm);
  // --- attention branch (xa computed in-place over xm) ---
  mix_rms_kernel<<<NT_, 256, 0, stream>>>(xm, x, resid_mix_a, xm, nb);
  gemm_f32<<<dim3(D_ / 128, NT_ / 128), 256, 0, stream>>>(nb, q_w, qbuf, NT_, D_, D_, 0);
  gemm_f32<<<dim3(HKV_ * PA_ / 128, NT_ / 128), 256, 0, stream>>>(nb, k_w, kbuf, NT_, HKV_ * PA_, D_, 0);
  gemm_f32<<<dim3(HKV_ * PA_ / 128, NT_ / 128), 256, 0, stream>>>(nb, v_w, vbuf, NT_, HKV_ * PA_, D_, 0);
  rope_fill_kernel<<<L_ * 32 / 256, 256, 0, stream>>>(cosb, sinb);
  qknorm_rope_kernel<<<NT_ * HA_ / 4, 256, 0, stream>>>(qbuf, HA_, cosb, sinb, q_gain);
  qknorm_rope_kernel<<<NT_ * HKV_ / 4, 256, 0, stream>>>(kbuf, HKV_, cosb, sinb, nullptr);
  attn_kernel<<<B_ * HA_ * (L_ / 32), 256, 0, stream>>>(qbuf, kbuf, vbuf, ao);
  gemm_f32<<<dim3(D_ / 128, NT_ / 128), 256, 0, stream>>>(ao, o_w, t1, NT_, D_, D_, 0);
  add_scaled_kernel<<<NT_ * D_ / 256, 256, 0, stream>>>(xm, t1, attn_scale, xm);
  // --- attention MLP ---
  rms_kernel<<<NT_, 256, 0, stream>>>(xm, nb);
  gemm_f32<<<dim3(4 * D_ / 128, NT_ / 128), 256, 0, stream>>>(nb, a_fc_w, vg, NT_, 4 * D_, D_, 1);
  gemm_f32<<<dim3(D_ / 128, NT_ / 128), 256, 0, stream>>>(vg, a_proj_w, t1, NT_, D_, 4 * D_, 0);
  add_scaled_kernel<<<NT_ * D_ / 256, 256, 0, stream>>>(xm, t1, a_mlp_scale, out);
}

// Round 3
// 1825.722 us; speedup vs baseline: 2.5874x; 2.5874x over previous
//
#include <hip/hip_runtime.h>
#include <hip/hip_bf16.h>
#include <math.h>

#define D_ 1024
#define DI_ 2048
#define HS_ 16
#define PS_ 128
#define NS_ 64
#define HA_ 16
#define HKV_ 4
#define PA_ 64
#define B_ 2
#define L_ 2048
#define NT_ 4096          // B_*L_
#define NC_ 32            // L_/64
#define RMS_EPS_ 1.1920929e-7f

typedef __attribute__((ext_vector_type(8))) short short8;
typedef __attribute__((ext_vector_type(4))) float f32x4;

#define GLOAD_LDS16(gp, lp)                                                        \
  __builtin_amdgcn_global_load_lds(                                               \
      (const __attribute__((address_space(1))) unsigned int*)(gp),                \
      (__attribute__((address_space(3))) unsigned int*)(lp), 16, 0, 0)

// ---------------- weight transpose + fp32->bf16: W[K,N] -> Wt[N,K] ----------------
__global__ __launch_bounds__(256) void transpose_cvt(
    const float* __restrict__ W, __hip_bfloat16* __restrict__ Wt, int K, int N) {
  __shared__ float t[32][33];
  int n0 = blockIdx.x * 32, k0 = blockIdx.y * 32;
  int tx = threadIdx.x & 31, ty = threadIdx.x >> 5;
#pragma unroll
  for (int i = 0; i < 4; i++)
    t[ty + i * 8][tx] = W[(size_t)(k0 + ty + i * 8) * N + n0 + tx];
  __syncthreads();
#pragma unroll
  for (int i = 0; i < 4; i++)
    Wt[(size_t)(n0 + ty + i * 8) * K + k0 + tx] = __float2bfloat16(t[tx][ty + i * 8]);
}

// ---------------- bf16 MFMA GEMM: C[M,N] = epi(A[M,K] @ Wt[N,K]^T) ----------------
// A row-major bf16 [M,K]; Wt row-major bf16 [N,K]; K mult of 64, M,N mult of 128.
// mode 0: f32 out; 1: relu^2 -> bf16 out; 2: bf16 out
__global__ __launch_bounds__(256) void gemm_bf16(
    const unsigned short* __restrict__ A, const unsigned short* __restrict__ Wt,
    float* __restrict__ Cf, __hip_bfloat16* __restrict__ Cb,
    int N, int K, int mode) {
  __shared__ unsigned short As[128 * 64];
  __shared__ unsigned short Bs[128 * 64];
  int bm = blockIdx.y * 128, bn = blockIdx.x * 128;
  int tid = threadIdx.x;
  int w = tid >> 6, l = tid & 63;
  int wr = w >> 1, wc = w & 1;
  f32x4 acc[4][4];
#pragma unroll
  for (int i = 0; i < 4; i++)
#pragma unroll
    for (int j = 0; j < 4; j++) acc[i][j] = (f32x4){0.f, 0.f, 0.f, 0.f};
  int r_ = tid >> 3;   // 0..31
  int s_ = tid & 7;    // chunk slot
  for (int k0 = 0; k0 < K; k0 += 64) {
    __syncthreads();
#pragma unroll
    for (int i = 0; i < 4; i++) {
      int r = i * 32 + r_;
      int kq = s_ ^ (r & 7);
      GLOAD_LDS16(A + (size_t)(bm + r) * K + k0 + kq * 8, &As[r * 64 + s_ * 8]);
    }
#pragma unroll
    for (int i = 0; i < 4; i++) {
      int r = i * 32 + r_;
      int kq = s_ ^ (r & 7);
      GLOAD_LDS16(Wt + (size_t)(bn + r) * K + k0 + kq * 8, &Bs[r * 64 + s_ * 8]);
    }
    __syncthreads();
#pragma unroll
    for (int h = 0; h < 2; h++) {
      short8 af[4], bfr[4];
#pragma unroll
      for (int i = 0; i < 4; i++) {
        int row = wr * 64 + i * 16 + (l & 15);
        int c = h * 4 + (l >> 4);
        af[i] = *(const short8*)&As[row * 64 + ((c ^ (row & 7)) << 3)];
      }
#pragma unroll
      for (int j = 0; j < 4; j++) {
        int row = wc * 64 + j * 16 + (l & 15);
        int c = h * 4 + (l >> 4);
        bfr[j] = *(const short8*)&Bs[row * 64 + ((c ^ (row & 7)) << 3)];
      }
#pragma unroll
      for (int i = 0; i < 4; i++)
#pragma unroll
        for (int j = 0; j < 4; j++)
          acc[i][j] = __builtin_amdgcn_mfma_f32_16x16x32_bf16(af[i], bfr[j], acc[i][j], 0, 0, 0);
    }
  }
  int rb = (l >> 4) * 4, cb2 = l & 15;
#pragma unroll
  for (int i = 0; i < 4; i++)
#pragma unroll
    for (int j = 0; j < 4; j++) {
      int gr = bm + wr * 64 + i * 16 + rb;
      int gc = bn + wc * 64 + j * 16 + cb2;
#pragma unroll
      for (int reg = 0; reg < 4; reg++) {
        float v = acc[i][j][reg];
        if (mode == 1) { v = fmaxf(v, 0.f); v = v * v; }
        if (mode == 0) Cf[(size_t)(gr + reg) * N + gc] = v;
        else Cb[(size_t)(gr + reg) * N + gc] = __float2bfloat16(v);
      }
    }
}

// ---------------- mix + rmsnorm (fp32 resid out + bf16 normed/raw out) ----------------
__global__ __launch_bounds__(256) void mix_rms_kernel(
    const float* __restrict__ a, const float* __restrict__ b2,
    const float* __restrict__ mix, float* __restrict__ xout,
    __hip_bfloat16* __restrict__ nbf, __hip_bfloat16* __restrict__ rawbf) {
  int row = blockIdx.x;
  size_t base = (size_t)row * D_;
  float v[4]; float ss = 0.f;
#pragma unroll
  for (int i = 0; i < 4; i++) {
    int d = threadIdx.x + i * 256;
    float val = mix[d] * a[base + d] + mix[D_ + d] * b2[base + d];
    v[i] = val; ss += val * val;
  }
  for (int o = 32; o > 0; o >>= 1) ss += __shfl_down(ss, o, 64);
  __shared__ float red[4];
  if ((threadIdx.x & 63) == 0) red[threadIdx.x >> 6] = ss;
  __syncthreads();
  float inv = rsqrtf((red[0] + red[1] + red[2] + red[3]) * (1.f / D_) + RMS_EPS_);
#pragma unroll
  for (int i = 0; i < 4; i++) {
    int d = threadIdx.x + i * 256;
    xout[base + d] = v[i];
    nbf[base + d] = __float2bfloat16(v[i] * inv);
    if (rawbf) rawbf[base + d] = __float2bfloat16(v[i]);
  }
}

__global__ __launch_bounds__(256) void rms_kernel(
    const float* __restrict__ a, __hip_bfloat16* __restrict__ nbf) {
  int row = blockIdx.x;
  size_t base = (size_t)row * D_;
  float v[4]; float ss = 0.f;
#pragma unroll
  for (int i = 0; i < 4; i++) {
    int d = threadIdx.x + i * 256;
    float val = a[base + d];
    v[i] = val; ss += val * val;
  }
  for (int o = 32; o > 0; o >>= 1) ss += __shfl_down(ss, o, 64);
  __shared__ float red[4];
  if ((threadIdx.x & 63) == 0) red[threadIdx.x >> 6] = ss;
  __syncthreads();
  float inv = rsqrtf((red[0] + red[1] + red[2] + red[3]) * (1.f / D_) + RMS_EPS_);
#pragma unroll
  for (int i = 0; i < 4; i++) {
    int d = threadIdx.x + i * 256;
    nbf[base + d] = __float2bfloat16(v[i] * inv);
  }
}

// ---------------- depthwise causal conv (KC=4) + SiLU; val [NT][DI] f32 ----------------
__global__ __launch_bounds__(256) void conv_silu_kernel(
    const float* __restrict__ val, const float* __restrict__ cw,
    const float* __restrict__ cb, float* __restrict__ xv) {
  int idx = blockIdx.x * 256 + threadIdx.x;
  int c = idx & (DI_ - 1);
  int bl = idx >> 11;
  int l = bl & (L_ - 1);
  float acc = cb[c];
  float w0 = cw[c * 4 + 0], w1 = cw[c * 4 + 1], w2 = cw[c * 4 + 2], w3 = cw[c * 4 + 3];
  size_t rb = (size_t)bl * DI_ + c;
  if (l >= 3) acc += val[rb - (size_t)3 * DI_] * w0;
  if (l >= 2) acc += val[rb - (size_t)2 * DI_] * w1;
  if (l >= 1) acc += val[rb - (size_t)1 * DI_] * w2;
  acc += val[rb] * w3;
  xv[idx] = acc / (1.f + __expf(-acc));
}

// ---------------- scan pass A1: per-chunk states ----------------
__global__ __launch_bounds__(256) void scanA1_kernel(
    const float* __restrict__ xv, const __hip_bfloat16* __restrict__ Bm,
    const float* __restrict__ dt_bias, const float* __restrict__ A_log,
    float* __restrict__ st) {
  __shared__ __align__(16) float sm[4096 + 8192];
  float* Bs = sm;
  float* Xs = sm + 4096;
  int blk = blockIdx.x;
  int c = blk & 31, h = (blk >> 5) & 15, b = blk >> 9;
  float dt = log1pf(__expf(dt_bias[h]));
  float adt = -__expf(A_log[h]) * dt;
  int tid = threadIdx.x;
  int l0 = c * 64;
  size_t rB = ((size_t)(b * L_ + l0)) * (HS_ * NS_) + h * NS_;
#pragma unroll
  for (int i = 0; i < 16; i++) {
    int e = tid + i * 256;
    int t = e >> 6, n = e & 63;
    Bs[t * 64 + n] = __bfloat162float(Bm[rB + (size_t)t * (HS_ * NS_) + n]);
  }
  size_t rX = ((size_t)(b * L_ + l0)) * DI_ + h * PS_;
#pragma unroll
  for (int i = 0; i < 32; i++) {
    int e = tid + i * 256;
    int t = e >> 7, p = e & 127;
    Xs[t * 128 + p] = xv[rX + (size_t)t * DI_ + p];
  }
  __syncthreads();
  int pg = tid & 31;
  int ng = (tid >> 5) << 3;
  float acc[8][4];
#pragma unroll
  for (int nn = 0; nn < 8; nn++)
#pragma unroll
    for (int i = 0; i < 4; i++) acc[nn][i] = 0.f;
  for (int t = 0; t < 64; t++) {
    float dr = __expf(adt * (float)(63 - t));
    float4 x4 = *(const float4*)&Xs[t * 128 + pg * 4];
    float xd0 = x4.x * dr, xd1 = x4.y * dr, xd2 = x4.z * dr, xd3 = x4.w * dr;
#pragma unroll
    for (int nn = 0; nn < 8; nn++) {
      float bv = Bs[t * 64 + ng + nn];
      acc[nn][0] += bv * xd0; acc[nn][1] += bv * xd1;
      acc[nn][2] += bv * xd2; acc[nn][3] += bv * xd3;
    }
  }
  size_t sb = ((size_t)((b * HS_ + h) * NC_ + c)) * (NS_ * PS_);
#pragma unroll
  for (int nn = 0; nn < 8; nn++) {
    *(float4*)&st[sb + (size_t)(ng + nn) * PS_ + pg * 4] =
        make_float4(acc[nn][0] * dt, acc[nn][1] * dt, acc[nn][2] * dt, acc[nn][3] * dt);
  }
}

// ---------------- scan pass A2: intra-chunk y_diag + D*x (y in-place over xv) ----------------
__global__ __launch_bounds__(256) void scanA2_kernel(
    const float* __restrict__ xv, const __hip_bfloat16* __restrict__ Bm,
    const __hip_bfloat16* __restrict__ Cm, const float* __restrict__ dt_bias,
    const float* __restrict__ A_log, const float* __restrict__ D_param,
    float* __restrict__ y) {
  __shared__ __align__(16) float sm[4160 + 8192];
  float* Cb = sm;          // [64][65]
  float* Bs = sm + 4160;   // [64][64] phase 1
  float* Xs = sm + 4160;   // [64][128] phase 2
  int blk = blockIdx.x;
  int c = blk & 31, h = (blk >> 5) & 15, b = blk >> 9;
  float dt = log1pf(__expf(dt_bias[h]));
  float adt = -__expf(A_log[h]) * dt;
  float Dp = D_param[h];
  int tid = threadIdx.x;
  int l0 = c * 64;
  size_t rB = ((size_t)(b * L_ + l0)) * (HS_ * NS_) + h * NS_;
#pragma unroll
  for (int i = 0; i < 16; i++) {
    int e = tid + i * 256;
    int t = e >> 6, n = e & 63;
    Bs[t * 64 + n] = __bfloat162float(Bm[rB + (size_t)t * (HS_ * NS_) + n]);
    Cb[t * 65 + n] = __bfloat162float(Cm[rB + (size_t)t * (HS_ * NS_) + n]);
  }
  __syncthreads();
  int q = tid >> 2;
  int kb = (tid & 3) << 4;
  float cbl[16];
#pragma unroll
  for (int kk = 0; kk < 16; kk++) {
    int k = kb + kk;
    float a = 0.f;
    if (k <= q) {
      for (int n = 0; n < 64; n++) a += Cb[q * 65 + n] * Bs[k * 64 + n];
      a *= __expf(adt * (float)(q - k));
    }
    cbl[kk] = a;
  }
  __syncthreads();
#pragma unroll
  for (int kk = 0; kk < 16; kk++) Cb[q * 65 + kb + kk] = cbl[kk];
  size_t rX = ((size_t)(b * L_ + l0)) * DI_ + h * PS_;
#pragma unroll
  for (int i = 0; i < 32; i++) {
    int e = tid + i * 256;
    int t = e >> 7, p = e & 127;
    Xs[t * 128 + p] = xv[rX + (size_t)t * DI_ + p];
  }
  __syncthreads();
  int pg = tid & 31;
  int qg = (tid >> 5) << 3;
  float acc[8][4];
#pragma unroll
  for (int qq = 0; qq < 8; qq++)
#pragma unroll
    for (int i = 0; i < 4; i++) acc[qq][i] = 0.f;
  for (int k = 0; k < 64; k++) {
    float4 x4 = *(const float4*)&Xs[k * 128 + pg * 4];
#pragma unroll
    for (int qq = 0; qq < 8; qq++) {
      float s = Cb[(qg + qq) * 65 + k];
      acc[qq][0] += s * x4.x; acc[qq][1] += s * x4.y;
      acc[qq][2] += s * x4.z; acc[qq][3] += s * x4.w;
    }
  }
#pragma unroll
  for (int qq = 0; qq < 8; qq++) {
    int qr = qg + qq;
    float4 xq = *(const float4*)&Xs[qr * 128 + pg * 4];
    size_t yo = ((size_t)(b * L_ + l0 + qr)) * DI_ + h * PS_ + pg * 4;
    *(float4*)&y[yo] = make_float4(acc[qq][0] * dt + Dp * xq.x,
                                   acc[qq][1] * dt + Dp * xq.y,
                                   acc[qq][2] * dt + Dp * xq.z,
                                   acc[qq][3] * dt + Dp * xq.w);
  }
}

// ---------------- scan pass B1: inter-chunk recurrence (in-place) ----------------
__global__ __launch_bounds__(256) void scanB1_kernel(
    float* __restrict__ st, const float* __restrict__ dt_bias,
    const float* __restrict__ A_log) {
  int h = blockIdx.x & 15, b = blockIdx.x >> 4;
  float dt = log1pf(__expf(dt_bias[h]));
  float adt = -__expf(A_log[h]) * dt;
  float cdec = __expf(adt * 64.f);
  size_t base = ((size_t)(b * HS_ + h)) * NC_ * (NS_ * PS_);
  float hreg[32];
#pragma unroll
  for (int j = 0; j < 32; j++) hreg[j] = 0.f;
  for (int c = 0; c < NC_; c++) {
    size_t o = base + (size_t)c * (NS_ * PS_) + threadIdx.x;
#pragma unroll
    for (int j = 0; j < 32; j++) {
      float tmp = st[o + (size_t)j * 256];
      st[o + (size_t)j * 256] = hreg[j];
      hreg[j] = cdec * hreg[j] + tmp;
    }
  }
}

// ---------------- scan pass B2: y_off + gate SiLU -> bf16 out ----------------
__global__ __launch_bounds__(256) void scanB2_kernel(
    const __hip_bfloat16* __restrict__ Cm, const float* __restrict__ st,
    const float* __restrict__ gate, const float* __restrict__ dt_bias,
    const float* __restrict__ A_log, const float* __restrict__ y,
    __hip_bfloat16* __restrict__ yout) {
  __shared__ float Cs[64 * 64];
  __shared__ __align__(16) float Hs[64 * 128];
  int blk = blockIdx.x;
  int c = blk & 31, h = (blk >> 5) & 15, b = blk >> 9;
  float dt = log1pf(__expf(dt_bias[h]));
  float adt = -__expf(A_log[h]) * dt;
  int tid = threadIdx.x;
  int l0 = c * 64;
  size_t rC = ((size_t)(b * L_ + l0)) * (HS_ * NS_) + h * NS_;
#pragma unroll
  for (int i = 0; i < 16; i++) {
    int e = tid + i * 256;
    int t = e >> 6, n = e & 63;
    Cs[t * 64 + n] = __bfloat162float(Cm[rC + (size_t)t * (HS_ * NS_) + n]);
  }
  size_t sb = ((size_t)((b * HS_ + h) * NC_ + c)) * (NS_ * PS_);
#pragma unroll
  for (int i = 0; i < 32; i++) {
    int e = tid + i * 256;
    Hs[e] = st[sb + e];
  }
  __syncthreads();
  int pg = tid & 31;
  int tg = (tid >> 5) << 3;
  float acc[8][4];
#pragma unroll
  for (int tt = 0; tt < 8; tt++)
#pragma unroll
    for (int i = 0; i < 4; i++) acc[tt][i] = 0.f;
  for (int n = 0; n < 64; n++) {
    float4 h4 = *(const float4*)&Hs[n * 128 + pg * 4];
#pragma unroll
    for (int tt = 0; tt < 8; tt++) {
      float cv = Cs[(tg + tt) * 64 + n];
      acc[tt][0] += cv * h4.x; acc[tt][1] += cv * h4.y;
      acc[tt][2] += cv * h4.z; acc[tt][3] += cv * h4.w;
    }
  }
#pragma unroll
  for (int tt = 0; tt < 8; tt++) {
    int t = tg + tt;
    float dout = __expf(adt * (float)(t + 1));
    size_t row = (size_t)(b * L_ + l0 + t);
#pragma unroll
    for (int i = 0; i < 4; i++) {
      int p = pg * 4 + i;
      float g = gate[row * DI_ + h * PS_ + p];
      float yv = y[row * DI_ + h * PS_ + p] + acc[tt][i] * dout;
      yout[row * DI_ + h * PS_ + p] = __float2bfloat16(yv * (g / (1.f + __expf(-g))));
    }
  }
}

// ---------------- residual add ----------------
__global__ __launch_bounds__(256) void add_scaled_kernel(
    const float* __restrict__ base, const float* __restrict__ src,
    const float* __restrict__ scale, float* __restrict__ dst) {
  size_t idx = (size_t)blockIdx.x * 256 + threadIdx.x;
  int d = (int)(idx & (D_ - 1));
  dst[idx] = base[idx] + scale[d] * src[idx];
}

// ---------------- rope tables ----------------
__global__ void rope_fill_kernel(float* __restrict__ cosb, float* __restrict__ sinb) {
  int idx = blockIdx.x * 256 + threadIdx.x;
  int i = idx & 31, l = idx >> 5;
  float inv = __expf(-(2.0f * (float)i / (float)PA_) * logf(10000.0f));
  float ang = (float)l * inv;
  cosb[idx] = cosf(ang);
  sinb[idx] = sinf(ang);
}

// ---------------- per-head rmsnorm + rope (+gain) in place ----------------
__global__ __launch_bounds__(256) void qknorm_rope_kernel(
    float* __restrict__ buf, int nh, const float* __restrict__ cosb,
    const float* __restrict__ sinb, const float* __restrict__ gain) {
  int row = blockIdx.x * 4 + (threadIdx.x >> 6);
  int lane = threadIdx.x & 63;
  int h = row % nh;
  int l = (row / nh) & (L_ - 1);
  float v = buf[(size_t)row * PA_ + lane];
  float ss = v * v;
  for (int o = 32; o > 0; o >>= 1) ss += __shfl_xor(ss, o, 64);
  v *= rsqrtf(ss * (1.f / PA_) + RMS_EPS_);
  float partner = __shfl_xor(v, 32, 64);
  int i = lane & 31;
  float cth = cosb[l * 32 + i], sth = sinb[l * 32 + i];
  float out = (lane < 32) ? (v * cth + partner * sth) : (v * cth - partner * sth);
  if (gain) out *= gain[h];
  buf[(size_t)row * PA_ + lane] = out;
}

// ---------------- causal GQA flash attention (fp32 compute, bf16 out) ----------------
__global__ __launch_bounds__(256) void attn_kernel(
    const float* __restrict__ qb, const float* __restrict__ kb,
    const float* __restrict__ vb, __hip_bfloat16* __restrict__ ao) {
  __shared__ float Qs[32 * 65];
  __shared__ float Ks[64 * 65];
  __shared__ __align__(16) float Vs[64 * 64];
  __shared__ float Ss[32 * 65];
  int blk = blockIdx.x;
  int qt = blk & 63;
  int h = (blk >> 6) & 15;
  int b = blk >> 10;
  int hk = h >> 2;
  int q0 = qt * 32;
  int tid = threadIdx.x;
  int ty = tid >> 3, tx = tid & 7;
#pragma unroll
  for (int i = 0; i < 8; i++) {
    int e = tid + i * 256;
    int r = e >> 6, cc = e & 63;
    Qs[r * 65 + cc] = qb[((size_t)(b * L_ + q0 + r) * HA_ + h) * PA_ + cc] * 0.125f;
  }
  float o0[8];
#pragma unroll
  for (int j = 0; j < 8; j++) o0[j] = 0.f;
  float m = -3.0e38f, lsum = 0.f;
  int nkt = (q0 + 32 + 63) >> 6;
  for (int kt = 0; kt < nkt; kt++) {
    int k0 = kt * 64;
    __syncthreads();
#pragma unroll
    for (int i = 0; i < 16; i++) {
      int e = tid + i * 256;
      int r = e >> 6, cc = e & 63;
      size_t kro = ((size_t)(b * L_ + k0 + r) * HKV_ + hk) * PA_ + cc;
      Ks[r * 65 + cc] = kb[kro];
      Vs[r * 64 + cc] = vb[kro];
    }
    __syncthreads();
    float sc[8];
    float tmax = -3.0e38f;
#pragma unroll
    for (int jj = 0; jj < 8; jj++) {
      int k = tx * 8 + jj;
      float a = 0.f;
      for (int n = 0; n < 64; n++) a += Qs[ty * 65 + n] * Ks[k * 65 + n];
      if (k0 + k > q0 + ty) a = -3.0e38f;
      sc[jj] = a;
      tmax = fmaxf(tmax, a);
    }
    for (int of = 4; of > 0; of >>= 1) tmax = fmaxf(tmax, __shfl_xor(tmax, of, 8));
    float mnew = fmaxf(m, tmax);
    float corr = __expf(m - mnew);
    float rs = 0.f;
#pragma unroll
    for (int jj = 0; jj < 8; jj++) {
      float p = __expf(sc[jj] - mnew);
      Ss[ty * 65 + tx * 8 + jj] = p;
      rs += p;
    }
    for (int of = 4; of > 0; of >>= 1) rs += __shfl_xor(rs, of, 8);
    lsum = lsum * corr + rs;
    m = mnew;
#pragma unroll
    for (int j = 0; j < 8; j++) o0[j] *= corr;
    __syncthreads();
    for (int n = 0; n < 64; n++) {
      float p = Ss[ty * 65 + n];
      float4 va = *(const float4*)&Vs[n * 64 + tx * 8];
      float4 vb4 = *(const float4*)&Vs[n * 64 + tx * 8 + 4];
      o0[0] += p * va.x; o0[1] += p * va.y; o0[2] += p * va.z; o0[3] += p * va.w;
      o0[4] += p * vb4.x; o0[5] += p * vb4.y; o0[6] += p * vb4.z; o0[7] += p * vb4.w;
    }
  }
  float invl = 1.0f / lsum;
  size_t oo = ((size_t)(b * L_ + q0 + ty) * HA_ + h) * PA_ + tx * 8;
#pragma unroll
  for (int j = 0; j < 8; j++) ao[oo + j] = __float2bfloat16(o0[j] * invl);
}

// ---------------- host ----------------
extern "C" void kernel_launch(void* const* d_in, const int* in_sizes, int n_in,
                              void* d_out, int out_size, void* d_ws, size_t ws_size,
                              hipStream_t stream) {
  (void)in_sizes; (void)n_in; (void)out_size; (void)ws_size;
  const float* x           = (const float*)d_in[0];
  const float* in_proj_w   = (const float*)d_in[1];
  const float* conv_w      = (const float*)d_in[2];
  const float* conv_b      = (const float*)d_in[3];
  const float* B_proj_w    = (const float*)d_in[4];
  const float* C_proj_w    = (const float*)d_in[5];
  const float* dt_bias     = (const float*)d_in[6];
  const float* A_log       = (const float*)d_in[7];
  const float* D_param     = (const float*)d_in[8];
  const float* out_proj_w  = (const float*)d_in[9];
  const float* resid_mix_m = (const float*)d_in[10];
  const float* mamba_scale = (const float*)d_in[11];
  const float* m_fc_w      = (const float*)d_in[12];
  const float* m_proj_w    = (const float*)d_in[13];
  const float* m_mlp_scale = (const float*)d_in[14];
  const float* resid_mix_a = (const float*)d_in[15];
  const float* q_w         = (const float*)d_in[16];
  const float* k_w         = (const float*)d_in[17];
  const float* v_w         = (const float*)d_in[18];
  const float* o_w         = (const float*)d_in[19];
  const float* q_gain      = (const float*)d_in[20];
  const float* attn_scale  = (const float*)d_in[21];
  const float* a_fc_w      = (const float*)d_in[22];
  const float* a_proj_w    = (const float*)d_in[23];
  const float* a_mlp_scale = (const float*)d_in[24];
  float* ws  = (float*)d_ws;
  float* out = (float*)d_out;

  // ---- workspace layout (float units), total ~212.3 MB ----
  const size_t NTDf = (size_t)NT_ * D_;            // 4,194,304
  float* xm    = ws;                               // 16 MB f32
  float* Eb    = ws + NTDf;                        // 34 MB: val f32 / st f32 / t1 f32
  float* Fb    = Eb + 8912896;                     // 32 MB: gate f32 / hidden bf16 / qkv f32
  float* Gb    = Fb + 8388608;                     // 32 MB: xv f32 (y in-place)
  float* Crg   = Gb + 8388608;                     // 8 MB: nbb bf16 / aob bf16 / ybb lo
  float* Drg   = Crg + 2097152;                    // 8 MB: xmb bf16 / ybb hi
  float* BmbF  = Drg + 2097152;                    // 8 MB: Bmb bf16
  float* CmbF  = BmbF + 2097152;                   // 8 MB: Cmb bf16
  float* WtF   = CmbF + 2097152;                   // 56 MB: all weights bf16 [N,K]
  float* cosb  = WtF + 14680064;
  float* sinb  = cosb + (size_t)L_ * 32;

  __hip_bfloat16* nbb = (__hip_bfloat16*)Crg;
  __hip_bfloat16* xmb = (__hip_bfloat16*)Drg;
  __hip_bfloat16* ybb = (__hip_bfloat16*)Crg;      // 16 MB spans Crg+Drg
  __hip_bfloat16* aob = (__hip_bfloat16*)Crg;
  __hip_bfloat16* Bmb = (__hip_bfloat16*)BmbF;
  __hip_bfloat16* Cmb = (__hip_bfloat16*)CmbF;
  __hip_bfloat16* hb  = (__hip_bfloat16*)Fb;       // MLP hidden bf16 [NT,4096]
  float* val  = Eb;
  float* st   = Eb;
  float* t1   = Eb;
  float* gate = Fb;
  float* qbuf = Fb;
  float* kbuf = Fb + NTDf;
  float* vbuf = kbuf + (size_t)NT_ * HKV_ * PA_;
  float* xv   = Gb;
  float* yb   = Gb;

  __hip_bfloat16* Wt = (__hip_bfloat16*)WtF;
  size_t o_in  = 0;
  size_t o_B   = o_in  + (size_t)4096 * 1024;
  size_t o_C   = o_B   + (size_t)1024 * 1024;
  size_t o_out = o_C   + (size_t)1024 * 1024;
  size_t o_mfc = o_out + (size_t)1024 * 2048;
  size_t o_mpj = o_mfc + (size_t)4096 * 1024;
  size_t o_q   = o_mpj + (size_t)1024 * 4096;
  size_t o_k   = o_q   + (size_t)1024 * 1024;
  size_t o_v   = o_k   + (size_t)256 * 1024;
  size_t o_o   = o_v   + (size_t)256 * 1024;
  size_t o_afc = o_o   + (size_t)1024 * 1024;
  size_t o_apj = o_afc + (size_t)4096 * 1024;

  // ---- weight transpose-convert: W[K,N] -> Wt[N,K] bf16 ----
#define TCVT(Wp, off, K, N) \
  transpose_cvt<<<dim3((N) / 32, (K) / 32), 256, 0, stream>>>((Wp), Wt + (off), (K), (N))
  TCVT(in_proj_w,  o_in,  1024, 4096);
  TCVT(B_proj_w,   o_B,   1024, 1024);
  TCVT(C_proj_w,   o_C,   1024, 1024);
  TCVT(out_proj_w, o_out, 2048, 1024);
  TCVT(m_fc_w,     o_mfc, 1024, 4096);
  TCVT(m_proj_w,   o_mpj, 4096, 1024);
  TCVT(q_w,        o_q,   1024, 1024);
  TCVT(k_w,        o_k,   1024, 256);
  TCVT(v_w,        o_v,   1024, 256);
  TCVT(o_w,        o_o,   1024, 1024);
  TCVT(a_fc_w,     o_afc, 1024, 4096);
  TCVT(a_proj_w,   o_apj, 4096, 1024);
#undef TCVT

#define GEMM(Abuf, Woff, Cfp, Cbp, N, K, mode) \
  gemm_bf16<<<dim3((N) / 128, NT_ / 128), 256, 0, stream>>>( \
      (const unsigned short*)(Abuf), (const unsigned short*)(Wt + (Woff)), \
      (Cfp), (Cbp), (N), (K), (mode))

  // --- mamba branch ---
  mix_rms_kernel<<<NT_, 256, 0, stream>>>(x, x, resid_mix_m, xm, nbb, xmb);
  GEMM(nbb, o_in, val, (__hip_bfloat16*)0, 2048, 1024, 0);                       // value
  GEMM(nbb, o_in + (size_t)2048 * 1024, gate, (__hip_bfloat16*)0, 2048, 1024, 0); // gate
  GEMM(xmb, o_B, (float*)0, Bmb, 1024, 1024, 2);
  GEMM(xmb, o_C, (float*)0, Cmb, 1024, 1024, 2);
  conv_silu_kernel<<<NT_ * DI_ / 256, 256, 0, stream>>>(val, conv_w, conv_b, xv);
  scanA1_kernel<<<B_ * HS_ * NC_, 256, 0, stream>>>(xv, Bmb, dt_bias, A_log, st);
  scanA2_kernel<<<B_ * HS_ * NC_, 256, 0, stream>>>(xv, Bmb, Cmb, dt_bias, A_log, D_param, yb);
  scanB1_kernel<<<B_ * HS_, 256, 0, stream>>>(st, dt_bias, A_log);
  scanB2_kernel<<<B_ * HS_ * NC_, 256, 0, stream>>>(Cmb, st, gate, dt_bias, A_log, yb, ybb);
  GEMM(ybb, o_out, t1, (__hip_bfloat16*)0, 1024, 2048, 0);
  add_scaled_kernel<<<NT_ * D_ / 256, 256, 0, stream>>>(xm, t1, mamba_scale, xm);
  // --- mamba MLP ---
  rms_kernel<<<NT_, 256, 0, stream>>>(xm, nbb);
  GEMM(nbb, o_mfc, (float*)0, hb, 4096, 1024, 1);
  GEMM(hb, o_mpj, t1, (__hip_bfloat16*)0, 1024, 4096, 0);
  add_scaled_kernel<<<NT_ * D_ / 256, 256, 0, stream>>>(xm, t1, m_mlp_scale, xm);
  // --- attention branch ---
  mix_rms_kernel<<<NT_, 256, 0, stream>>>(xm, x, resid_mix_a, xm, nbb, (__hip_bfloat16*)0);
  GEMM(nbb, o_q, qbuf, (__hip_bfloat16*)0, 1024, 1024, 0);
  GEMM(nbb, o_k, kbuf, (__hip_bfloat16*)0, 256, 1024, 0);
  GEMM(nbb, o_v, vbuf, (__hip_bfloat16*)0, 256, 1024, 0);
  rope_fill_kernel<<<L_ * 32 / 256, 256, 0, stream>>>(cosb, sinb);
  qknorm_rope_kernel<<<NT_ * HA_ / 4, 256, 0, stream>>>(qbuf, HA_, cosb, sinb, q_gain);
  qknorm_rope_kernel<<<NT_ * HKV_ / 4, 256, 0, stream>>>(kbuf, HKV_, cosb, sinb, (const float*)0);
  attn_kernel<<<B_ * HA_ * (L_ / 32), 256, 0, stream>>>(qbuf, kbuf, vbuf, aob);
  GEMM(aob, o_o, t1, (__hip_bfloat16*)0, 1024, 1024, 0);
  add_scaled_kernel<<<NT_ * D_ / 256, 256, 0, stream>>>(xm, t1, attn_scale, xm);
  // --- attention MLP ---
  rms_kernel<<<NT_, 256, 0, stream>>>(xm, nbb);
  GEMM(nbb, o_afc, (float*)0, hb, 4096, 1024, 1);
  GEMM(hb, o_apj, t1, (__hip_bfloat16*)0, 1024, 4096, 0);
  add_scaled_kernel<<<NT_ * D_ / 256, 256, 0, stream>>>(xm, t1, a_mlp_scale, out);
#undef GEMM
}

// Round 4
// 935.692 us; speedup vs baseline: 5.0486x; 1.9512x over previous
//
#include <hip/hip_runtime.h>
#include <hip/hip_bf16.h>
#include <math.h>

#define D_ 1024
#define DI_ 2048
#define HS_ 16
#define PS_ 128
#define NS_ 64
#define HA_ 16
#define HKV_ 4
#define PA_ 64
#define B_ 2
#define L_ 2048
#define NT_ 4096          // B_*L_
#define NC_ 32            // L_/64
#define RMS_EPS_ 1.1920929e-7f

typedef __attribute__((ext_vector_type(8))) short short8;
typedef __attribute__((ext_vector_type(4))) float f32x4;

#define GLOAD_LDS16(gp, lp)                                                        \
  __builtin_amdgcn_global_load_lds(                                               \
      (const __attribute__((address_space(1))) unsigned int*)(gp),                \
      (__attribute__((address_space(3))) unsigned int*)(lp), 16, 0, 0)

// ---------------- weight transpose + fp32->bf16: W[K,N] -> Wt[N,K] ----------------
__global__ __launch_bounds__(256) void transpose_cvt(
    const float* __restrict__ W, __hip_bfloat16* __restrict__ Wt, int K, int N) {
  __shared__ float t[32][33];
  int n0 = blockIdx.x * 32, k0 = blockIdx.y * 32;
  int tx = threadIdx.x & 31, ty = threadIdx.x >> 5;
#pragma unroll
  for (int i = 0; i < 4; i++)
    t[ty + i * 8][tx] = W[(size_t)(k0 + ty + i * 8) * N + n0 + tx];
  __syncthreads();
#pragma unroll
  for (int i = 0; i < 4; i++)
    Wt[(size_t)(n0 + ty + i * 8) * K + k0 + tx] = __float2bfloat16(t[tx][ty + i * 8]);
}

// ---------------- bf16 MFMA GEMM: C[M,N] = epi(A[M,K] @ Wt[N,K]^T) ----------------
__global__ __launch_bounds__(256) void gemm_bf16(
    const unsigned short* __restrict__ A, const unsigned short* __restrict__ Wt,
    float* __restrict__ Cf, __hip_bfloat16* __restrict__ Cb,
    int N, int K, int mode) {
  __shared__ unsigned short As[128 * 64];
  __shared__ unsigned short Bs[128 * 64];
  int bm = blockIdx.y * 128, bn = blockIdx.x * 128;
  int tid = threadIdx.x;
  int w = tid >> 6, l = tid & 63;
  int wr = w >> 1, wc = w & 1;
  f32x4 acc[4][4];
#pragma unroll
  for (int i = 0; i < 4; i++)
#pragma unroll
    for (int j = 0; j < 4; j++) acc[i][j] = (f32x4){0.f, 0.f, 0.f, 0.f};
  int r_ = tid >> 3;
  int s_ = tid & 7;
  for (int k0 = 0; k0 < K; k0 += 64) {
    __syncthreads();
#pragma unroll
    for (int i = 0; i < 4; i++) {
      int r = i * 32 + r_;
      int kq = s_ ^ (r & 7);
      GLOAD_LDS16(A + (size_t)(bm + r) * K + k0 + kq * 8, &As[r * 64 + s_ * 8]);
    }
#pragma unroll
    for (int i = 0; i < 4; i++) {
      int r = i * 32 + r_;
      int kq = s_ ^ (r & 7);
      GLOAD_LDS16(Wt + (size_t)(bn + r) * K + k0 + kq * 8, &Bs[r * 64 + s_ * 8]);
    }
    __syncthreads();
#pragma unroll
    for (int h = 0; h < 2; h++) {
      short8 af[4], bfr[4];
#pragma unroll
      for (int i = 0; i < 4; i++) {
        int row = wr * 64 + i * 16 + (l & 15);
        int c = h * 4 + (l >> 4);
        af[i] = *(const short8*)&As[row * 64 + ((c ^ (row & 7)) << 3)];
      }
#pragma unroll
      for (int j = 0; j < 4; j++) {
        int row = wc * 64 + j * 16 + (l & 15);
        int c = h * 4 + (l >> 4);
        bfr[j] = *(const short8*)&Bs[row * 64 + ((c ^ (row & 7)) << 3)];
      }
#pragma unroll
      for (int i = 0; i < 4; i++)
#pragma unroll
        for (int j = 0; j < 4; j++)
          acc[i][j] = __builtin_amdgcn_mfma_f32_16x16x32_bf16(af[i], bfr[j], acc[i][j], 0, 0, 0);
    }
  }
  int rb = (l >> 4) * 4, cb2 = l & 15;
#pragma unroll
  for (int i = 0; i < 4; i++)
#pragma unroll
    for (int j = 0; j < 4; j++) {
      int gr = bm + wr * 64 + i * 16 + rb;
      int gc = bn + wc * 64 + j * 16 + cb2;
#pragma unroll
      for (int reg = 0; reg < 4; reg++) {
        float v = acc[i][j][reg];
        if (mode == 1) { v = fmaxf(v, 0.f); v = v * v; }
        if (mode == 0) Cf[(size_t)(gr + reg) * N + gc] = v;
        else Cb[(size_t)(gr + reg) * N + gc] = __float2bfloat16(v);
      }
    }
}

// ---------------- mix + rmsnorm ----------------
__global__ __launch_bounds__(256) void mix_rms_kernel(
    const float* __restrict__ a, const float* __restrict__ b2,
    const float* __restrict__ mix, float* __restrict__ xout,
    __hip_bfloat16* __restrict__ nbf, __hip_bfloat16* __restrict__ rawbf) {
  int row = blockIdx.x;
  size_t base = (size_t)row * D_;
  float v[4]; float ss = 0.f;
#pragma unroll
  for (int i = 0; i < 4; i++) {
    int d = threadIdx.x + i * 256;
    float val = mix[d] * a[base + d] + mix[D_ + d] * b2[base + d];
    v[i] = val; ss += val * val;
  }
  for (int o = 32; o > 0; o >>= 1) ss += __shfl_down(ss, o, 64);
  __shared__ float red[4];
  if ((threadIdx.x & 63) == 0) red[threadIdx.x >> 6] = ss;
  __syncthreads();
  float inv = rsqrtf((red[0] + red[1] + red[2] + red[3]) * (1.f / D_) + RMS_EPS_);
#pragma unroll
  for (int i = 0; i < 4; i++) {
    int d = threadIdx.x + i * 256;
    xout[base + d] = v[i];
    nbf[base + d] = __float2bfloat16(v[i] * inv);
    if (rawbf) rawbf[base + d] = __float2bfloat16(v[i]);
  }
}

__global__ __launch_bounds__(256) void rms_kernel(
    const float* __restrict__ a, __hip_bfloat16* __restrict__ nbf) {
  int row = blockIdx.x;
  size_t base = (size_t)row * D_;
  float v[4]; float ss = 0.f;
#pragma unroll
  for (int i = 0; i < 4; i++) {
    int d = threadIdx.x + i * 256;
    float val = a[base + d];
    v[i] = val; ss += val * val;
  }
  for (int o = 32; o > 0; o >>= 1) ss += __shfl_down(ss, o, 64);
  __shared__ float red[4];
  if ((threadIdx.x & 63) == 0) red[threadIdx.x >> 6] = ss;
  __syncthreads();
  float inv = rsqrtf((red[0] + red[1] + red[2] + red[3]) * (1.f / D_) + RMS_EPS_);
#pragma unroll
  for (int i = 0; i < 4; i++) {
    int d = threadIdx.x + i * 256;
    nbf[base + d] = __float2bfloat16(v[i] * inv);
  }
}

// ---------------- depthwise causal conv (KC=4) + SiLU ----------------
__global__ __launch_bounds__(256) void conv_silu_kernel(
    const float* __restrict__ val, const float* __restrict__ cw,
    const float* __restrict__ cb, float* __restrict__ xv) {
  int idx = blockIdx.x * 256 + threadIdx.x;
  int c = idx & (DI_ - 1);
  int bl = idx >> 11;
  int l = bl & (L_ - 1);
  float acc = cb[c];
  float w0 = cw[c * 4 + 0], w1 = cw[c * 4 + 1], w2 = cw[c * 4 + 2], w3 = cw[c * 4 + 3];
  size_t rb = (size_t)bl * DI_ + c;
  if (l >= 3) acc += val[rb - (size_t)3 * DI_] * w0;
  if (l >= 2) acc += val[rb - (size_t)2 * DI_] * w1;
  if (l >= 1) acc += val[rb - (size_t)1 * DI_] * w2;
  acc += val[rb] * w3;
  xv[idx] = acc / (1.f + __expf(-acc));
}

// ---------------- scan pass A1 ----------------
__global__ __launch_bounds__(256) void scanA1_kernel(
    const float* __restrict__ xv, const __hip_bfloat16* __restrict__ Bm,
    const float* __restrict__ dt_bias, const float* __restrict__ A_log,
    float* __restrict__ st) {
  __shared__ __align__(16) float sm[4096 + 8192];
  float* Bs = sm;
  float* Xs = sm + 4096;
  int blk = blockIdx.x;
  int c = blk & 31, h = (blk >> 5) & 15, b = blk >> 9;
  float dt = log1pf(__expf(dt_bias[h]));
  float adt = -__expf(A_log[h]) * dt;
  int tid = threadIdx.x;
  int l0 = c * 64;
  size_t rB = ((size_t)(b * L_ + l0)) * (HS_ * NS_) + h * NS_;
#pragma unroll
  for (int i = 0; i < 16; i++) {
    int e = tid + i * 256;
    int t = e >> 6, n = e & 63;
    Bs[t * 64 + n] = __bfloat162float(Bm[rB + (size_t)t * (HS_ * NS_) + n]);
  }
  size_t rX = ((size_t)(b * L_ + l0)) * DI_ + h * PS_;
#pragma unroll
  for (int i = 0; i < 32; i++) {
    int e = tid + i * 256;
    int t = e >> 7, p = e & 127;
    Xs[t * 128 + p] = xv[rX + (size_t)t * DI_ + p];
  }
  __syncthreads();
  int pg = tid & 31;
  int ng = (tid >> 5) << 3;
  float acc[8][4];
#pragma unroll
  for (int nn = 0; nn < 8; nn++)
#pragma unroll
    for (int i = 0; i < 4; i++) acc[nn][i] = 0.f;
  for (int t = 0; t < 64; t++) {
    float dr = __expf(adt * (float)(63 - t));
    float4 x4 = *(const float4*)&Xs[t * 128 + pg * 4];
    float xd0 = x4.x * dr, xd1 = x4.y * dr, xd2 = x4.z * dr, xd3 = x4.w * dr;
#pragma unroll
    for (int nn = 0; nn < 8; nn++) {
      float bv = Bs[t * 64 + ng + nn];
      acc[nn][0] += bv * xd0; acc[nn][1] += bv * xd1;
      acc[nn][2] += bv * xd2; acc[nn][3] += bv * xd3;
    }
  }
  size_t sb = ((size_t)((b * HS_ + h) * NC_ + c)) * (NS_ * PS_);
#pragma unroll
  for (int nn = 0; nn < 8; nn++) {
    *(float4*)&st[sb + (size_t)(ng + nn) * PS_ + pg * 4] =
        make_float4(acc[nn][0] * dt, acc[nn][1] * dt, acc[nn][2] * dt, acc[nn][3] * dt);
  }
}

// ---------------- scan pass A2 ----------------
__global__ __launch_bounds__(256) void scanA2_kernel(
    const float* __restrict__ xv, const __hip_bfloat16* __restrict__ Bm,
    const __hip_bfloat16* __restrict__ Cm, const float* __restrict__ dt_bias,
    const float* __restrict__ A_log, const float* __restrict__ D_param,
    float* __restrict__ y) {
  __shared__ __align__(16) float sm[4160 + 8192];
  float* Cb = sm;
  float* Bs = sm + 4160;
  float* Xs = sm + 4160;
  int blk = blockIdx.x;
  int c = blk & 31, h = (blk >> 5) & 15, b = blk >> 9;
  float dt = log1pf(__expf(dt_bias[h]));
  float adt = -__expf(A_log[h]) * dt;
  float Dp = D_param[h];
  int tid = threadIdx.x;
  int l0 = c * 64;
  size_t rB = ((size_t)(b * L_ + l0)) * (HS_ * NS_) + h * NS_;
#pragma unroll
  for (int i = 0; i < 16; i++) {
    int e = tid + i * 256;
    int t = e >> 6, n = e & 63;
    Bs[t * 64 + n] = __bfloat162float(Bm[rB + (size_t)t * (HS_ * NS_) + n]);
    Cb[t * 65 + n] = __bfloat162float(Cm[rB + (size_t)t * (HS_ * NS_) + n]);
  }
  __syncthreads();
  int q = tid >> 2;
  int kb = (tid & 3) << 4;
  float cbl[16];
#pragma unroll
  for (int kk = 0; kk < 16; kk++) {
    int k = kb + kk;
    float a = 0.f;
    if (k <= q) {
      for (int n = 0; n < 64; n++) a += Cb[q * 65 + n] * Bs[k * 64 + n];
      a *= __expf(adt * (float)(q - k));
    }
    cbl[kk] = a;
  }
  __syncthreads();
#pragma unroll
  for (int kk = 0; kk < 16; kk++) Cb[q * 65 + kb + kk] = cbl[kk];
  size_t rX = ((size_t)(b * L_ + l0)) * DI_ + h * PS_;
#pragma unroll
  for (int i = 0; i < 32; i++) {
    int e = tid + i * 256;
    int t = e >> 7, p = e & 127;
    Xs[t * 128 + p] = xv[rX + (size_t)t * DI_ + p];
  }
  __syncthreads();
  int pg = tid & 31;
  int qg = (tid >> 5) << 3;
  float acc[8][4];
#pragma unroll
  for (int qq = 0; qq < 8; qq++)
#pragma unroll
    for (int i = 0; i < 4; i++) acc[qq][i] = 0.f;
  for (int k = 0; k < 64; k++) {
    float4 x4 = *(const float4*)&Xs[k * 128 + pg * 4];
#pragma unroll
    for (int qq = 0; qq < 8; qq++) {
      float s = Cb[(qg + qq) * 65 + k];
      acc[qq][0] += s * x4.x; acc[qq][1] += s * x4.y;
      acc[qq][2] += s * x4.z; acc[qq][3] += s * x4.w;
    }
  }
#pragma unroll
  for (int qq = 0; qq < 8; qq++) {
    int qr = qg + qq;
    float4 xq = *(const float4*)&Xs[qr * 128 + pg * 4];
    size_t yo = ((size_t)(b * L_ + l0 + qr)) * DI_ + h * PS_ + pg * 4;
    *(float4*)&y[yo] = make_float4(acc[qq][0] * dt + Dp * xq.x,
                                   acc[qq][1] * dt + Dp * xq.y,
                                   acc[qq][2] * dt + Dp * xq.z,
                                   acc[qq][3] * dt + Dp * xq.w);
  }
}

// ---------------- scan pass B1 ----------------
__global__ __launch_bounds__(256) void scanB1_kernel(
    float* __restrict__ st, const float* __restrict__ dt_bias,
    const float* __restrict__ A_log) {
  int h = blockIdx.x & 15, b = blockIdx.x >> 4;
  float dt = log1pf(__expf(dt_bias[h]));
  float adt = -__expf(A_log[h]) * dt;
  float cdec = __expf(adt * 64.f);
  size_t base = ((size_t)(b * HS_ + h)) * NC_ * (NS_ * PS_);
  float hreg[32];
#pragma unroll
  for (int j = 0; j < 32; j++) hreg[j] = 0.f;
  for (int c = 0; c < NC_; c++) {
    size_t o = base + (size_t)c * (NS_ * PS_) + threadIdx.x;
#pragma unroll
    for (int j = 0; j < 32; j++) {
      float tmp = st[o + (size_t)j * 256];
      st[o + (size_t)j * 256] = hreg[j];
      hreg[j] = cdec * hreg[j] + tmp;
    }
  }
}

// ---------------- scan pass B2 ----------------
__global__ __launch_bounds__(256) void scanB2_kernel(
    const __hip_bfloat16* __restrict__ Cm, const float* __restrict__ st,
    const float* __restrict__ gate, const float* __restrict__ dt_bias,
    const float* __restrict__ A_log, const float* __restrict__ y,
    __hip_bfloat16* __restrict__ yout) {
  __shared__ float Cs[64 * 64];
  __shared__ __align__(16) float Hs[64 * 128];
  int blk = blockIdx.x;
  int c = blk & 31, h = (blk >> 5) & 15, b = blk >> 9;
  float dt = log1pf(__expf(dt_bias[h]));
  float adt = -__expf(A_log[h]) * dt;
  int tid = threadIdx.x;
  int l0 = c * 64;
  size_t rC = ((size_t)(b * L_ + l0)) * (HS_ * NS_) + h * NS_;
#pragma unroll
  for (int i = 0; i < 16; i++) {
    int e = tid + i * 256;
    int t = e >> 6, n = e & 63;
    Cs[t * 64 + n] = __bfloat162float(Cm[rC + (size_t)t * (HS_ * NS_) + n]);
  }
  size_t sb = ((size_t)((b * HS_ + h) * NC_ + c)) * (NS_ * PS_);
#pragma unroll
  for (int i = 0; i < 32; i++) {
    int e = tid + i * 256;
    Hs[e] = st[sb + e];
  }
  __syncthreads();
  int pg = tid & 31;
  int tg = (tid >> 5) << 3;
  float acc[8][4];
#pragma unroll
  for (int tt = 0; tt < 8; tt++)
#pragma unroll
    for (int i = 0; i < 4; i++) acc[tt][i] = 0.f;
  for (int n = 0; n < 64; n++) {
    float4 h4 = *(const float4*)&Hs[n * 128 + pg * 4];
#pragma unroll
    for (int tt = 0; tt < 8; tt++) {
      float cv = Cs[(tg + tt) * 64 + n];
      acc[tt][0] += cv * h4.x; acc[tt][1] += cv * h4.y;
      acc[tt][2] += cv * h4.z; acc[tt][3] += cv * h4.w;
    }
  }
#pragma unroll
  for (int tt = 0; tt < 8; tt++) {
    int t = tg + tt;
    float dout = __expf(adt * (float)(t + 1));
    size_t row = (size_t)(b * L_ + l0 + t);
#pragma unroll
    for (int i = 0; i < 4; i++) {
      int p = pg * 4 + i;
      float g = gate[row * DI_ + h * PS_ + p];
      float yv = y[row * DI_ + h * PS_ + p] + acc[tt][i] * dout;
      yout[row * DI_ + h * PS_ + p] = __float2bfloat16(yv * (g / (1.f + __expf(-g))));
    }
  }
}

// ---------------- residual add ----------------
__global__ __launch_bounds__(256) void add_scaled_kernel(
    const float* __restrict__ base, const float* __restrict__ src,
    const float* __restrict__ scale, float* __restrict__ dst) {
  size_t idx = (size_t)blockIdx.x * 256 + threadIdx.x;
  int d = (int)(idx & (D_ - 1));
  dst[idx] = base[idx] + scale[d] * src[idx];
}

// ---------------- rope tables ----------------
__global__ void rope_fill_kernel(float* __restrict__ cosb, float* __restrict__ sinb) {
  int idx = blockIdx.x * 256 + threadIdx.x;
  int i = idx & 31, l = idx >> 5;
  float inv = __expf(-(2.0f * (float)i / (float)PA_) * logf(10000.0f));
  float ang = (float)l * inv;
  cosb[idx] = cosf(ang);
  sinb[idx] = sinf(ang);
}

// ---------------- per-head rmsnorm + rope (+gain) -> bf16 out ----------------
__global__ __launch_bounds__(256) void qknorm_rope_bf16_kernel(
    const float* __restrict__ buf, __hip_bfloat16* __restrict__ obf, int nh,
    const float* __restrict__ cosb, const float* __restrict__ sinb,
    const float* __restrict__ gain) {
  int row = blockIdx.x * 4 + (threadIdx.x >> 6);
  int lane = threadIdx.x & 63;
  int h = row % nh;
  int l = (row / nh) & (L_ - 1);
  float v = buf[(size_t)row * PA_ + lane];
  float ss = v * v;
  for (int o = 32; o > 0; o >>= 1) ss += __shfl_xor(ss, o, 64);
  v *= rsqrtf(ss * (1.f / PA_) + RMS_EPS_);
  float partner = __shfl_xor(v, 32, 64);
  int i = lane & 31;
  float cth = cosb[l * 32 + i], sth = sinb[l * 32 + i];
  float out = (lane < 32) ? (v * cth + partner * sth) : (v * cth - partner * sth);
  if (gain) out *= gain[h];
  obf[(size_t)row * PA_ + lane] = __float2bfloat16(out);
}

// ---------------- causal GQA flash attention, bf16 MFMA ----------------
// qb [NT][HA*PA] bf16; kb [NT][HKV*PA] bf16; vt [B*HKV*PA][L] bf16; ao [NT][D] bf16
__global__ __launch_bounds__(256) void attn_mfma_kernel(
    const unsigned short* __restrict__ qb, const unsigned short* __restrict__ kb,
    const unsigned short* __restrict__ vt, __hip_bfloat16* __restrict__ ao) {
  __shared__ unsigned short Ks[64][72];   // [key][d]
  __shared__ unsigned short Vs[64][72];   // [d][key]
  __shared__ unsigned short Psm[4][16][72]; // per-wave P [q][key]
  int blk = blockIdx.x;
  int qt = blk & 31;               // L_/64
  int h  = (blk >> 5) & 15;
  int b  = blk >> 9;
  int hk = h >> 2;
  int q0 = qt * 64;
  int tid = threadIdx.x;
  int w = tid >> 6, l = tid & 63;
  int l15 = l & 15, lg = l >> 4;
  int qw = q0 + w * 16;            // this wave's 16 q rows
  // Q fragments (row=l15, k = lg*8 + j + 32*half)
  short8 qf[2];
  {
    size_t qrow = ((size_t)(b * L_ + qw + l15)) * (HA_ * PA_) + h * PA_;
    qf[0] = *(const short8*)&qb[qrow + lg * 8];
    qf[1] = *(const short8*)&qb[qrow + 32 + lg * 8];
  }
  f32x4 o_acc[4];
#pragma unroll
  for (int db = 0; db < 4; db++) o_acc[db] = (f32x4){0.f, 0.f, 0.f, 0.f};
  float mrow[4] = {-3.0e38f, -3.0e38f, -3.0e38f, -3.0e38f};
  float lsum[4] = {0.f, 0.f, 0.f, 0.f};
  int nkt = qt + 1;
  for (int kt = 0; kt < nkt; kt++) {
    int k0 = kt * 64;
    __syncthreads();
    // stage K [key][d] and V^T [d][key]
#pragma unroll
    for (int i = 0; i < 2; i++) {
      int e = tid + i * 256;
      int r = e >> 3, s = e & 7;
      *(short8*)&Ks[r][s * 8] =
          *(const short8*)&kb[((size_t)(b * L_ + k0 + r)) * (HKV_ * PA_) + hk * PA_ + s * 8];
      *(short8*)&Vs[r][s * 8] =
          *(const short8*)&vt[((size_t)((b * HKV_ + hk) * PA_ + r)) * L_ + k0 + s * 8];
    }
    __syncthreads();
    // QK^T: S[16q][64key] per wave
    f32x4 s_acc[4];
#pragma unroll
    for (int kb2 = 0; kb2 < 4; kb2++) {
      short8 b0 = *(const short8*)&Ks[kb2 * 16 + l15][lg * 8];
      short8 b1 = *(const short8*)&Ks[kb2 * 16 + l15][32 + lg * 8];
      f32x4 s = (f32x4){0.f, 0.f, 0.f, 0.f};
      s = __builtin_amdgcn_mfma_f32_16x16x32_bf16(qf[0], b0, s, 0, 0, 0);
      s = __builtin_amdgcn_mfma_f32_16x16x32_bf16(qf[1], b1, s, 0, 0, 0);
      s_acc[kb2] = s;
    }
    bool diag = (kt == qt);
    // online softmax per row (row = lg*4 + reg)
#pragma unroll
    for (int reg = 0; reg < 4; reg++) {
      float sc[4];
      float tm = -3.0e38f;
#pragma unroll
      for (int kb2 = 0; kb2 < 4; kb2++) {
        float s = s_acc[kb2][reg] * 0.125f;
        if (diag) {
          int key = k0 + kb2 * 16 + l15;
          int qg = qw + lg * 4 + reg;
          if (key > qg) s = -3.0e38f;
        }
        sc[kb2] = s;
        tm = fmaxf(tm, s);
      }
#pragma unroll
      for (int of = 1; of < 16; of <<= 1) tm = fmaxf(tm, __shfl_xor(tm, of, 64));
      float mn = fmaxf(mrow[reg], tm);
      float corr = __expf(mrow[reg] - mn);
      mrow[reg] = mn;
      float rs = 0.f;
      int prow = lg * 4 + reg;
#pragma unroll
      for (int kb2 = 0; kb2 < 4; kb2++) {
        float p = __expf(sc[kb2] - mn);
        rs += p;
        __hip_bfloat16 hv = __float2bfloat16(p);
        Psm[w][prow][kb2 * 16 + l15] = *(unsigned short*)&hv;
      }
#pragma unroll
      for (int of = 1; of < 16; of <<= 1) rs += __shfl_xor(rs, of, 64);
      lsum[reg] = lsum[reg] * corr + rs;
#pragma unroll
      for (int db = 0; db < 4; db++) o_acc[db][reg] *= corr;
    }
    __syncthreads();
    // PV: O[16q][64d] += P[16q][64k] @ V[64k][64d]
#pragma unroll
    for (int ks = 0; ks < 2; ks++) {
      short8 pa = *(const short8*)&Psm[w][l15][ks * 32 + lg * 8];
#pragma unroll
      for (int db = 0; db < 4; db++) {
        short8 vb8 = *(const short8*)&Vs[db * 16 + l15][ks * 32 + lg * 8];
        o_acc[db] = __builtin_amdgcn_mfma_f32_16x16x32_bf16(pa, vb8, o_acc[db], 0, 0, 0);
      }
    }
  }
  // write out
#pragma unroll
  for (int reg = 0; reg < 4; reg++) {
    float invl = 1.0f / lsum[reg];
    size_t row = (size_t)(b * L_ + qw + lg * 4 + reg);
#pragma unroll
    for (int db = 0; db < 4; db++)
      ao[row * D_ + h * PA_ + db * 16 + l15] = __float2bfloat16(o_acc[db][reg] * invl);
  }
}

// ---------------- host ----------------
extern "C" void kernel_launch(void* const* d_in, const int* in_sizes, int n_in,
                              void* d_out, int out_size, void* d_ws, size_t ws_size,
                              hipStream_t stream) {
  (void)in_sizes; (void)n_in; (void)out_size; (void)ws_size;
  const float* x           = (const float*)d_in[0];
  const float* in_proj_w   = (const float*)d_in[1];
  const float* conv_w      = (const float*)d_in[2];
  const float* conv_b      = (const float*)d_in[3];
  const float* B_proj_w    = (const float*)d_in[4];
  const float* C_proj_w    = (const float*)d_in[5];
  const float* dt_bias     = (const float*)d_in[6];
  const float* A_log       = (const float*)d_in[7];
  const float* D_param     = (const float*)d_in[8];
  const float* out_proj_w  = (const float*)d_in[9];
  const float* resid_mix_m = (const float*)d_in[10];
  const float* mamba_scale = (const float*)d_in[11];
  const float* m_fc_w      = (const float*)d_in[12];
  const float* m_proj_w    = (const float*)d_in[13];
  const float* m_mlp_scale = (const float*)d_in[14];
  const float* resid_mix_a = (const float*)d_in[15];
  const float* q_w         = (const float*)d_in[16];
  const float* k_w         = (const float*)d_in[17];
  const float* v_w         = (const float*)d_in[18];
  const float* o_w         = (const float*)d_in[19];
  const float* q_gain      = (const float*)d_in[20];
  const float* attn_scale  = (const float*)d_in[21];
  const float* a_fc_w      = (const float*)d_in[22];
  const float* a_proj_w    = (const float*)d_in[23];
  const float* a_mlp_scale = (const float*)d_in[24];
  float* ws  = (float*)d_ws;
  float* out = (float*)d_out;

  // ---- workspace layout (float units), ~212.3 MB ----
  const size_t NTDf = (size_t)NT_ * D_;            // 4,194,304
  float* xm    = ws;                               // 16 MB f32
  float* Eb    = ws + NTDf;                        // 34 MB: val f32 / st f32 / t1 f32
  float* Fb    = Eb + 8912896;                     // 32 MB: gate f32 / hidden bf16 / qkv f32
  float* Gb    = Fb + 8388608;                     // 32 MB: xv f32 / qbb,kbb,vtb bf16
  float* Crg   = Gb + 8388608;                     // 8 MB: nbb bf16 / aob bf16 / ybb lo
  float* Drg   = Crg + 2097152;                    // 8 MB: xmb bf16 / ybb hi
  float* BmbF  = Drg + 2097152;                    // 8 MB
  float* CmbF  = BmbF + 2097152;                   // 8 MB
  float* WtF   = CmbF + 2097152;                   // 56 MB
  float* cosb  = WtF + 14680064;
  float* sinb  = cosb + (size_t)L_ * 32;

  __hip_bfloat16* nbb = (__hip_bfloat16*)Crg;
  __hip_bfloat16* xmb = (__hip_bfloat16*)Drg;
  __hip_bfloat16* ybb = (__hip_bfloat16*)Crg;
  __hip_bfloat16* aob = (__hip_bfloat16*)Crg;
  __hip_bfloat16* Bmb = (__hip_bfloat16*)BmbF;
  __hip_bfloat16* Cmb = (__hip_bfloat16*)CmbF;
  __hip_bfloat16* hb  = (__hip_bfloat16*)Fb;
  float* val  = Eb;
  float* st   = Eb;
  float* t1   = Eb;
  float* gate = Fb;
  float* qbuf = Fb;
  float* kbuf = Fb + NTDf;
  float* vbuf = kbuf + (size_t)NT_ * HKV_ * PA_;
  float* xv   = Gb;
  float* yb   = Gb;
  // attention bf16 buffers in Gb (xv dead after scan)
  __hip_bfloat16* qbb = (__hip_bfloat16*)Gb;                    // 8 MB
  __hip_bfloat16* kbb = (__hip_bfloat16*)(Gb + 2097152);       // 2 MB
  __hip_bfloat16* vtb = (__hip_bfloat16*)(Gb + 2621440);       // 2 MB

  __hip_bfloat16* Wt = (__hip_bfloat16*)WtF;
  size_t o_in  = 0;
  size_t o_B   = o_in  + (size_t)4096 * 1024;
  size_t o_C   = o_B   + (size_t)1024 * 1024;
  size_t o_out = o_C   + (size_t)1024 * 1024;
  size_t o_mfc = o_out + (size_t)1024 * 2048;
  size_t o_mpj = o_mfc + (size_t)4096 * 1024;
  size_t o_q   = o_mpj + (size_t)1024 * 4096;
  size_t o_k   = o_q   + (size_t)1024 * 1024;
  size_t o_v   = o_k   + (size_t)256 * 1024;
  size_t o_o   = o_v   + (size_t)256 * 1024;
  size_t o_afc = o_o   + (size_t)1024 * 1024;
  size_t o_apj = o_afc + (size_t)4096 * 1024;

#define TCVT(Wp, off, K, N) \
  transpose_cvt<<<dim3((N) / 32, (K) / 32), 256, 0, stream>>>((Wp), Wt + (off), (K), (N))
  TCVT(in_proj_w,  o_in,  1024, 4096);
  TCVT(B_proj_w,   o_B,   1024, 1024);
  TCVT(C_proj_w,   o_C,   1024, 1024);
  TCVT(out_proj_w, o_out, 2048, 1024);
  TCVT(m_fc_w,     o_mfc, 1024, 4096);
  TCVT(m_proj_w,   o_mpj, 4096, 1024);
  TCVT(q_w,        o_q,   1024, 1024);
  TCVT(k_w,        o_k,   1024, 256);
  TCVT(v_w,        o_v,   1024, 256);
  TCVT(o_w,        o_o,   1024, 1024);
  TCVT(a_fc_w,     o_afc, 1024, 4096);
  TCVT(a_proj_w,   o_apj, 4096, 1024);
#undef TCVT

#define GEMM(Abuf, Woff, Cfp, Cbp, N, K, mode) \
  gemm_bf16<<<dim3((N) / 128, NT_ / 128), 256, 0, stream>>>( \
      (const unsigned short*)(Abuf), (const unsigned short*)(Wt + (Woff)), \
      (Cfp), (Cbp), (N), (K), (mode))

  // --- mamba branch ---
  mix_rms_kernel<<<NT_, 256, 0, stream>>>(x, x, resid_mix_m, xm, nbb, xmb);
  GEMM(nbb, o_in, val, (__hip_bfloat16*)0, 2048, 1024, 0);
  GEMM(nbb, o_in + (size_t)2048 * 1024, gate, (__hip_bfloat16*)0, 2048, 1024, 0);
  GEMM(xmb, o_B, (float*)0, Bmb, 1024, 1024, 2);
  GEMM(xmb, o_C, (float*)0, Cmb, 1024, 1024, 2);
  conv_silu_kernel<<<NT_ * DI_ / 256, 256, 0, stream>>>(val, conv_w, conv_b, xv);
  scanA1_kernel<<<B_ * HS_ * NC_, 256, 0, stream>>>(xv, Bmb, dt_bias, A_log, st);
  scanA2_kernel<<<B_ * HS_ * NC_, 256, 0, stream>>>(xv, Bmb, Cmb, dt_bias, A_log, D_param, yb);
  scanB1_kernel<<<B_ * HS_, 256, 0, stream>>>(st, dt_bias, A_log);
  scanB2_kernel<<<B_ * HS_ * NC_, 256, 0, stream>>>(Cmb, st, gate, dt_bias, A_log, yb, ybb);
  GEMM(ybb, o_out, t1, (__hip_bfloat16*)0, 1024, 2048, 0);
  add_scaled_kernel<<<NT_ * D_ / 256, 256, 0, stream>>>(xm, t1, mamba_scale, xm);
  // --- mamba MLP ---
  rms_kernel<<<NT_, 256, 0, stream>>>(xm, nbb);
  GEMM(nbb, o_mfc, (float*)0, hb, 4096, 1024, 1);
  GEMM(hb, o_mpj, t1, (__hip_bfloat16*)0, 1024, 4096, 0);
  add_scaled_kernel<<<NT_ * D_ / 256, 256, 0, stream>>>(xm, t1, m_mlp_scale, xm);
  // --- attention branch ---
  mix_rms_kernel<<<NT_, 256, 0, stream>>>(xm, x, resid_mix_a, xm, nbb, (__hip_bfloat16*)0);
  GEMM(nbb, o_q, qbuf, (__hip_bfloat16*)0, 1024, 1024, 0);
  GEMM(nbb, o_k, kbuf, (__hip_bfloat16*)0, 256, 1024, 0);
  GEMM(nbb, o_v, vbuf, (__hip_bfloat16*)0, 256, 1024, 0);
  rope_fill_kernel<<<L_ * 32 / 256, 256, 0, stream>>>(cosb, sinb);
  qknorm_rope_bf16_kernel<<<NT_ * HA_ / 4, 256, 0, stream>>>(qbuf, qbb, HA_, cosb, sinb, q_gain);
  qknorm_rope_bf16_kernel<<<NT_ * HKV_ / 4, 256, 0, stream>>>(kbuf, kbb, HKV_, cosb, sinb, (const float*)0);
  transpose_cvt<<<dim3(256 / 32, 2048 / 32), 256, 0, stream>>>(vbuf, vtb, 2048, 256);
  transpose_cvt<<<dim3(256 / 32, 2048 / 32), 256, 0, stream>>>(vbuf + (size_t)L_ * 256, vtb + (size_t)256 * L_, 2048, 256);
  attn_mfma_kernel<<<B_ * HA_ * (L_ / 64), 256, 0, stream>>>(
      (const unsigned short*)qbb, (const unsigned short*)kbb, (const unsigned short*)vtb, aob);
  GEMM(aob, o_o, t1, (__hip_bfloat16*)0, 1024, 1024, 0);
  add_scaled_kernel<<<NT_ * D_ / 256, 256, 0, stream>>>(xm, t1, attn_scale, xm);
  // --- attention MLP ---
  rms_kernel<<<NT_, 256, 0, stream>>>(xm, nbb);
  GEMM(nbb, o_afc, (float*)0, hb, 4096, 1024, 1);
  GEMM(hb, o_apj, t1, (__hip_bfloat16*)0, 1024, 4096, 0);
  add_scaled_kernel<<<NT_ * D_ / 256, 256, 0, stream>>>(xm, t1, a_mlp_scale, out);
#undef GEMM
}

// Round 5
// 895.459 us; speedup vs baseline: 5.2754x; 1.0449x over previous
//
#include <hip/hip_runtime.h>
#include <hip/hip_bf16.h>
#include <math.h>

#define D_ 1024
#define DI_ 2048
#define HS_ 16
#define PS_ 128
#define NS_ 64
#define HA_ 16
#define HKV_ 4
#define PA_ 64
#define B_ 2
#define L_ 2048
#define NT_ 4096          // B_*L_
#define NC_ 32            // L_/64
#define RMS_EPS_ 1.1920929e-7f

typedef __attribute__((ext_vector_type(8))) short short8;
typedef __attribute__((ext_vector_type(4))) float f32x4;

#define GLOAD_LDS16(gp, lp)                                                        \
  __builtin_amdgcn_global_load_lds(                                               \
      (const __attribute__((address_space(1))) unsigned int*)(gp),                \
      (__attribute__((address_space(3))) unsigned int*)(lp), 16, 0, 0)

// ---------------- transpose + fp32->bf16: W[K rows x N cols, row-stride ldw] -> Wt[N][K] ----------------
__global__ __launch_bounds__(256) void transpose_cvt(
    const float* __restrict__ W, __hip_bfloat16* __restrict__ Wt, int K, int N, int ldw) {
  __shared__ float t[32][33];
  int n0 = blockIdx.x * 32, k0 = blockIdx.y * 32;
  int tx = threadIdx.x & 31, ty = threadIdx.x >> 5;
#pragma unroll
  for (int i = 0; i < 4; i++)
    t[ty + i * 8][tx] = W[(size_t)(k0 + ty + i * 8) * ldw + n0 + tx];
  __syncthreads();
#pragma unroll
  for (int i = 0; i < 4; i++)
    Wt[(size_t)(n0 + ty + i * 8) * K + k0 + tx] = __float2bfloat16(t[tx][ty + i * 8]);
}

// ---------------- bf16 MFMA GEMM, double-buffered 2-phase ----------------
// A row-major bf16 [M,K]; Wt row-major bf16 [N,K]; K mult of 64, M,N mult of 128.
// mode 0: f32 out; 1: relu^2 -> bf16; 2: bf16; 3: f32 out = base + scale[col]*acc
__global__ __launch_bounds__(256) void gemm_bf16(
    const unsigned short* __restrict__ A, const unsigned short* __restrict__ Wt,
    float* __restrict__ Cf, __hip_bfloat16* __restrict__ Cb,
    const float* __restrict__ baseb, const float* __restrict__ scale,
    int N, int K, int mode) {
  __shared__ unsigned short As[2][128 * 64];
  __shared__ unsigned short Bs[2][128 * 64];
  int bm = blockIdx.y * 128, bn = blockIdx.x * 128;
  int tid = threadIdx.x;
  int w = tid >> 6, l = tid & 63;
  int wr = w >> 1, wc = w & 1;
  f32x4 acc[4][4];
#pragma unroll
  for (int i = 0; i < 4; i++)
#pragma unroll
    for (int j = 0; j < 4; j++) acc[i][j] = (f32x4){0.f, 0.f, 0.f, 0.f};
  int r_ = tid >> 3;
  int s_ = tid & 7;

  auto STAGE = [&](int k0, int nb) {
#pragma unroll
    for (int i = 0; i < 4; i++) {
      int r = i * 32 + r_;
      int kq = s_ ^ (r & 7);
      GLOAD_LDS16(A + (size_t)(bm + r) * K + k0 + kq * 8, &As[nb][r * 64 + s_ * 8]);
    }
#pragma unroll
    for (int i = 0; i < 4; i++) {
      int r = i * 32 + r_;
      int kq = s_ ^ (r & 7);
      GLOAD_LDS16(Wt + (size_t)(bn + r) * K + k0 + kq * 8, &Bs[nb][r * 64 + s_ * 8]);
    }
  };

  STAGE(0, 0);
  __syncthreads();
  int cur = 0;
  for (int k0 = 0; k0 < K; k0 += 64) {
    if (k0 + 64 < K) STAGE(k0 + 64, cur ^ 1);
#pragma unroll
    for (int h = 0; h < 2; h++) {
      short8 af[4], bfr[4];
#pragma unroll
      for (int i = 0; i < 4; i++) {
        int row = wr * 64 + i * 16 + (l & 15);
        int c = h * 4 + (l >> 4);
        af[i] = *(const short8*)&As[cur][row * 64 + ((c ^ (row & 7)) << 3)];
      }
#pragma unroll
      for (int j = 0; j < 4; j++) {
        int row = wc * 64 + j * 16 + (l & 15);
        int c = h * 4 + (l >> 4);
        bfr[j] = *(const short8*)&Bs[cur][row * 64 + ((c ^ (row & 7)) << 3)];
      }
#pragma unroll
      for (int i = 0; i < 4; i++)
#pragma unroll
        for (int j = 0; j < 4; j++)
          acc[i][j] = __builtin_amdgcn_mfma_f32_16x16x32_bf16(af[i], bfr[j], acc[i][j], 0, 0, 0);
    }
    __syncthreads();   // drains vmcnt (prefetch) + joins waves; next tile ready
    cur ^= 1;
  }
  int rb = (l >> 4) * 4, cb2 = l & 15;
#pragma unroll
  for (int i = 0; i < 4; i++)
#pragma unroll
    for (int j = 0; j < 4; j++) {
      int gr = bm + wr * 64 + i * 16 + rb;
      int gc = bn + wc * 64 + j * 16 + cb2;
#pragma unroll
      for (int reg = 0; reg < 4; reg++) {
        float v = acc[i][j][reg];
        size_t idx = (size_t)(gr + reg) * N + gc;
        if (mode == 0) {
          Cf[idx] = v;
        } else if (mode == 1) {
          v = fmaxf(v, 0.f);
          Cb[idx] = __float2bfloat16(v * v);
        } else if (mode == 2) {
          Cb[idx] = __float2bfloat16(v);
        } else {
          Cf[idx] = baseb[idx] + scale[gc] * v;
        }
      }
    }
}

// ---------------- mix + rmsnorm ----------------
__global__ __launch_bounds__(256) void mix_rms_kernel(
    const float* __restrict__ a, const float* __restrict__ b2,
    const float* __restrict__ mix, float* __restrict__ xout,
    __hip_bfloat16* __restrict__ nbf, __hip_bfloat16* __restrict__ rawbf) {
  int row = blockIdx.x;
  size_t base = (size_t)row * D_;
  float v[4]; float ss = 0.f;
#pragma unroll
  for (int i = 0; i < 4; i++) {
    int d = threadIdx.x + i * 256;
    float val = mix[d] * a[base + d] + mix[D_ + d] * b2[base + d];
    v[i] = val; ss += val * val;
  }
  for (int o = 32; o > 0; o >>= 1) ss += __shfl_down(ss, o, 64);
  __shared__ float red[4];
  if ((threadIdx.x & 63) == 0) red[threadIdx.x >> 6] = ss;
  __syncthreads();
  float inv = rsqrtf((red[0] + red[1] + red[2] + red[3]) * (1.f / D_) + RMS_EPS_);
#pragma unroll
  for (int i = 0; i < 4; i++) {
    int d = threadIdx.x + i * 256;
    xout[base + d] = v[i];
    nbf[base + d] = __float2bfloat16(v[i] * inv);
    if (rawbf) rawbf[base + d] = __float2bfloat16(v[i]);
  }
}

__global__ __launch_bounds__(256) void rms_kernel(
    const float* __restrict__ a, __hip_bfloat16* __restrict__ nbf) {
  int row = blockIdx.x;
  size_t base = (size_t)row * D_;
  float v[4]; float ss = 0.f;
#pragma unroll
  for (int i = 0; i < 4; i++) {
    int d = threadIdx.x + i * 256;
    float val = a[base + d];
    v[i] = val; ss += val * val;
  }
  for (int o = 32; o > 0; o >>= 1) ss += __shfl_down(ss, o, 64);
  __shared__ float red[4];
  if ((threadIdx.x & 63) == 0) red[threadIdx.x >> 6] = ss;
  __syncthreads();
  float inv = rsqrtf((red[0] + red[1] + red[2] + red[3]) * (1.f / D_) + RMS_EPS_);
#pragma unroll
  for (int i = 0; i < 4; i++) {
    int d = threadIdx.x + i * 256;
    nbf[base + d] = __float2bfloat16(v[i] * inv);
  }
}

// ---------------- depthwise causal conv (KC=4) + SiLU; vg bf16 [NT][4096] cols 0..2047 ----------------
__global__ __launch_bounds__(256) void conv_silu_kernel(
    const __hip_bfloat16* __restrict__ vg, const float* __restrict__ cw,
    const float* __restrict__ cb, float* __restrict__ xv) {
  int idx = blockIdx.x * 256 + threadIdx.x;
  int c = idx & (DI_ - 1);
  int bl = idx >> 11;
  int l = bl & (L_ - 1);
  float acc = cb[c];
  float w0 = cw[c * 4 + 0], w1 = cw[c * 4 + 1], w2 = cw[c * 4 + 2], w3 = cw[c * 4 + 3];
  size_t rb = (size_t)bl * 4096 + c;
  if (l >= 3) acc += __bfloat162float(vg[rb - (size_t)3 * 4096]) * w0;
  if (l >= 2) acc += __bfloat162float(vg[rb - (size_t)2 * 4096]) * w1;
  if (l >= 1) acc += __bfloat162float(vg[rb - (size_t)1 * 4096]) * w2;
  acc += __bfloat162float(vg[rb]) * w3;
  xv[idx] = acc / (1.f + __expf(-acc));
}

// ---------------- scan pass A1 ----------------
__global__ __launch_bounds__(256) void scanA1_kernel(
    const float* __restrict__ xv, const __hip_bfloat16* __restrict__ Bm,
    const float* __restrict__ dt_bias, const float* __restrict__ A_log,
    float* __restrict__ st) {
  __shared__ __align__(16) float sm[4096 + 8192];
  float* Bs = sm;
  float* Xs = sm + 4096;
  int blk = blockIdx.x;
  int c = blk & 31, h = (blk >> 5) & 15, b = blk >> 9;
  float dt = log1pf(__expf(dt_bias[h]));
  float adt = -__expf(A_log[h]) * dt;
  int tid = threadIdx.x;
  int l0 = c * 64;
  size_t rB = ((size_t)(b * L_ + l0)) * (HS_ * NS_) + h * NS_;
#pragma unroll
  for (int i = 0; i < 16; i++) {
    int e = tid + i * 256;
    int t = e >> 6, n = e & 63;
    Bs[t * 64 + n] = __bfloat162float(Bm[rB + (size_t)t * (HS_ * NS_) + n]);
  }
  size_t rX = ((size_t)(b * L_ + l0)) * DI_ + h * PS_;
#pragma unroll
  for (int i = 0; i < 32; i++) {
    int e = tid + i * 256;
    int t = e >> 7, p = e & 127;
    Xs[t * 128 + p] = xv[rX + (size_t)t * DI_ + p];
  }
  __syncthreads();
  int pg = tid & 31;
  int ng = (tid >> 5) << 3;
  float acc[8][4];
#pragma unroll
  for (int nn = 0; nn < 8; nn++)
#pragma unroll
    for (int i = 0; i < 4; i++) acc[nn][i] = 0.f;
  for (int t = 0; t < 64; t++) {
    float dr = __expf(adt * (float)(63 - t));
    float4 x4 = *(const float4*)&Xs[t * 128 + pg * 4];
    float xd0 = x4.x * dr, xd1 = x4.y * dr, xd2 = x4.z * dr, xd3 = x4.w * dr;
#pragma unroll
    for (int nn = 0; nn < 8; nn++) {
      float bv = Bs[t * 64 + ng + nn];
      acc[nn][0] += bv * xd0; acc[nn][1] += bv * xd1;
      acc[nn][2] += bv * xd2; acc[nn][3] += bv * xd3;
    }
  }
  size_t sb = ((size_t)((b * HS_ + h) * NC_ + c)) * (NS_ * PS_);
#pragma unroll
  for (int nn = 0; nn < 8; nn++) {
    *(float4*)&st[sb + (size_t)(ng + nn) * PS_ + pg * 4] =
        make_float4(acc[nn][0] * dt, acc[nn][1] * dt, acc[nn][2] * dt, acc[nn][3] * dt);
  }
}

// ---------------- scan pass A2 ----------------
__global__ __launch_bounds__(256) void scanA2_kernel(
    const float* __restrict__ xv, const __hip_bfloat16* __restrict__ Bm,
    const __hip_bfloat16* __restrict__ Cm, const float* __restrict__ dt_bias,
    const float* __restrict__ A_log, const float* __restrict__ D_param,
    float* __restrict__ y) {
  __shared__ __align__(16) float sm[4160 + 8192];
  float* Cb = sm;
  float* Bs = sm + 4160;
  float* Xs = sm + 4160;
  int blk = blockIdx.x;
  int c = blk & 31, h = (blk >> 5) & 15, b = blk >> 9;
  float dt = log1pf(__expf(dt_bias[h]));
  float adt = -__expf(A_log[h]) * dt;
  float Dp = D_param[h];
  int tid = threadIdx.x;
  int l0 = c * 64;
  size_t rB = ((size_t)(b * L_ + l0)) * (HS_ * NS_) + h * NS_;
#pragma unroll
  for (int i = 0; i < 16; i++) {
    int e = tid + i * 256;
    int t = e >> 6, n = e & 63;
    Bs[t * 64 + n] = __bfloat162float(Bm[rB + (size_t)t * (HS_ * NS_) + n]);
    Cb[t * 65 + n] = __bfloat162float(Cm[rB + (size_t)t * (HS_ * NS_) + n]);
  }
  __syncthreads();
  int q = tid >> 2;
  int kb = (tid & 3) << 4;
  float cbl[16];
#pragma unroll
  for (int kk = 0; kk < 16; kk++) {
    int k = kb + kk;
    float a = 0.f;
    if (k <= q) {
      for (int n = 0; n < 64; n++) a += Cb[q * 65 + n] * Bs[k * 64 + n];
      a *= __expf(adt * (float)(q - k));
    }
    cbl[kk] = a;
  }
  __syncthreads();
#pragma unroll
  for (int kk = 0; kk < 16; kk++) Cb[q * 65 + kb + kk] = cbl[kk];
  size_t rX = ((size_t)(b * L_ + l0)) * DI_ + h * PS_;
#pragma unroll
  for (int i = 0; i < 32; i++) {
    int e = tid + i * 256;
    int t = e >> 7, p = e & 127;
    Xs[t * 128 + p] = xv[rX + (size_t)t * DI_ + p];
  }
  __syncthreads();
  int pg = tid & 31;
  int qg = (tid >> 5) << 3;
  float acc[8][4];
#pragma unroll
  for (int qq = 0; qq < 8; qq++)
#pragma unroll
    for (int i = 0; i < 4; i++) acc[qq][i] = 0.f;
  for (int k = 0; k < 64; k++) {
    float4 x4 = *(const float4*)&Xs[k * 128 + pg * 4];
#pragma unroll
    for (int qq = 0; qq < 8; qq++) {
      float s = Cb[(qg + qq) * 65 + k];
      acc[qq][0] += s * x4.x; acc[qq][1] += s * x4.y;
      acc[qq][2] += s * x4.z; acc[qq][3] += s * x4.w;
    }
  }
#pragma unroll
  for (int qq = 0; qq < 8; qq++) {
    int qr = qg + qq;
    float4 xq = *(const float4*)&Xs[qr * 128 + pg * 4];
    size_t yo = ((size_t)(b * L_ + l0 + qr)) * DI_ + h * PS_ + pg * 4;
    *(float4*)&y[yo] = make_float4(acc[qq][0] * dt + Dp * xq.x,
                                   acc[qq][1] * dt + Dp * xq.y,
                                   acc[qq][2] * dt + Dp * xq.z,
                                   acc[qq][3] * dt + Dp * xq.w);
  }
}

// ---------------- scan pass B1: inter-chunk recurrence, 128 blocks ----------------
__global__ __launch_bounds__(256) void scanB1_kernel(
    float* __restrict__ st, const float* __restrict__ dt_bias,
    const float* __restrict__ A_log) {
  int slice = blockIdx.x & 3;
  int h = (blockIdx.x >> 2) & 15, b = blockIdx.x >> 6;
  float dt = log1pf(__expf(dt_bias[h]));
  float adt = -__expf(A_log[h]) * dt;
  float cdec = __expf(adt * 64.f);
  size_t base = ((size_t)(b * HS_ + h)) * NC_ * (NS_ * PS_) + slice * 2048 + threadIdx.x;
  float hreg[8];
#pragma unroll
  for (int j = 0; j < 8; j++) hreg[j] = 0.f;
  for (int c = 0; c < NC_; c++) {
    size_t o = base + (size_t)c * (NS_ * PS_);
#pragma unroll
    for (int j = 0; j < 8; j++) {
      float tmp = st[o + (size_t)j * 256];
      st[o + (size_t)j * 256] = hreg[j];
      hreg[j] = cdec * hreg[j] + tmp;
    }
  }
}

// ---------------- scan pass B2: y_off + gate SiLU -> bf16 ----------------
__global__ __launch_bounds__(256) void scanB2_kernel(
    const __hip_bfloat16* __restrict__ Cm, const float* __restrict__ st,
    const __hip_bfloat16* __restrict__ vg, const float* __restrict__ dt_bias,
    const float* __restrict__ A_log, const float* __restrict__ y,
    __hip_bfloat16* __restrict__ yout) {
  __shared__ float Cs[64 * 64];
  __shared__ __align__(16) float Hs[64 * 128];
  int blk = blockIdx.x;
  int c = blk & 31, h = (blk >> 5) & 15, b = blk >> 9;
  float dt = log1pf(__expf(dt_bias[h]));
  float adt = -__expf(A_log[h]) * dt;
  int tid = threadIdx.x;
  int l0 = c * 64;
  size_t rC = ((size_t)(b * L_ + l0)) * (HS_ * NS_) + h * NS_;
#pragma unroll
  for (int i = 0; i < 16; i++) {
    int e = tid + i * 256;
    int t = e >> 6, n = e & 63;
    Cs[t * 64 + n] = __bfloat162float(Cm[rC + (size_t)t * (HS_ * NS_) + n]);
  }
  size_t sb = ((size_t)((b * HS_ + h) * NC_ + c)) * (NS_ * PS_);
#pragma unroll
  for (int i = 0; i < 32; i++) {
    int e = tid + i * 256;
    Hs[e] = st[sb + e];
  }
  __syncthreads();
  int pg = tid & 31;
  int tg = (tid >> 5) << 3;
  float acc[8][4];
#pragma unroll
  for (int tt = 0; tt < 8; tt++)
#pragma unroll
    for (int i = 0; i < 4; i++) acc[tt][i] = 0.f;
  for (int n = 0; n < 64; n++) {
    float4 h4 = *(const float4*)&Hs[n * 128 + pg * 4];
#pragma unroll
    for (int tt = 0; tt < 8; tt++) {
      float cv = Cs[(tg + tt) * 64 + n];
      acc[tt][0] += cv * h4.x; acc[tt][1] += cv * h4.y;
      acc[tt][2] += cv * h4.z; acc[tt][3] += cv * h4.w;
    }
  }
#pragma unroll
  for (int tt = 0; tt < 8; tt++) {
    int t = tg + tt;
    float dout = __expf(adt * (float)(t + 1));
    size_t row = (size_t)(b * L_ + l0 + t);
#pragma unroll
    for (int i = 0; i < 4; i++) {
      int p = pg * 4 + i;
      float g = __bfloat162float(vg[row * 4096 + 2048 + h * PS_ + p]);
      float yv = y[row * DI_ + h * PS_ + p] + acc[tt][i] * dout;
      yout[row * DI_ + h * PS_ + p] = __float2bfloat16(yv * (g / (1.f + __expf(-g))));
    }
  }
}

// ---------------- rope tables ----------------
__global__ void rope_fill_kernel(float* __restrict__ cosb, float* __restrict__ sinb) {
  int idx = blockIdx.x * 256 + threadIdx.x;
  int i = idx & 31, l = idx >> 5;
  float inv = __expf(-(2.0f * (float)i / (float)PA_) * logf(10000.0f));
  float ang = (float)l * inv;
  cosb[idx] = cosf(ang);
  sinb[idx] = sinf(ang);
}

// ---------------- per-head rmsnorm + rope (+gain), strided src -> packed bf16 dst ----------------
__global__ __launch_bounds__(256) void qknorm_rope_bf16_kernel(
    const float* __restrict__ src, int srcstride, int srcofs,
    __hip_bfloat16* __restrict__ dst, int nh,
    const float* __restrict__ cosb, const float* __restrict__ sinb,
    const float* __restrict__ gain) {
  int row = blockIdx.x * 4 + (threadIdx.x >> 6);   // row in [0, NT*nh)
  int lane = threadIdx.x & 63;
  int h = row % nh;
  int tok = row / nh;
  int l = tok & (L_ - 1);
  float v = src[(size_t)tok * srcstride + srcofs + h * 64 + lane];
  float ss = v * v;
  for (int o = 32; o > 0; o >>= 1) ss += __shfl_xor(ss, o, 64);
  v *= rsqrtf(ss * (1.f / PA_) + RMS_EPS_);
  float partner = __shfl_xor(v, 32, 64);
  int i = lane & 31;
  float cth = cosb[l * 32 + i], sth = sinb[l * 32 + i];
  float out = (lane < 32) ? (v * cth + partner * sth) : (v * cth - partner * sth);
  if (gain) out *= gain[h];
  dst[(size_t)tok * (nh * 64) + h * 64 + lane] = __float2bfloat16(out);
}

// ---------------- causal GQA flash attention, bf16 MFMA ----------------
__global__ __launch_bounds__(256) void attn_mfma_kernel(
    const unsigned short* __restrict__ qb, const unsigned short* __restrict__ kb,
    const unsigned short* __restrict__ vt, __hip_bfloat16* __restrict__ ao) {
  __shared__ unsigned short Ks[64][72];
  __shared__ unsigned short Vs[64][72];
  __shared__ unsigned short Psm[4][16][72];
  int blk = blockIdx.x;
  int qt = blk & 31;
  int h  = (blk >> 5) & 15;
  int b  = blk >> 9;
  int hk = h >> 2;
  int q0 = qt * 64;
  int tid = threadIdx.x;
  int w = tid >> 6, l = tid & 63;
  int l15 = l & 15, lg = l >> 4;
  int qw = q0 + w * 16;
  short8 qf[2];
  {
    size_t qrow = ((size_t)(b * L_ + qw + l15)) * (HA_ * PA_) + h * PA_;
    qf[0] = *(const short8*)&qb[qrow + lg * 8];
    qf[1] = *(const short8*)&qb[qrow + 32 + lg * 8];
  }
  f32x4 o_acc[4];
#pragma unroll
  for (int db = 0; db < 4; db++) o_acc[db] = (f32x4){0.f, 0.f, 0.f, 0.f};
  float mrow[4] = {-3.0e38f, -3.0e38f, -3.0e38f, -3.0e38f};
  float lsum[4] = {0.f, 0.f, 0.f, 0.f};
  int nkt = qt + 1;
  for (int kt = 0; kt < nkt; kt++) {
    int k0 = kt * 64;
    __syncthreads();
#pragma unroll
    for (int i = 0; i < 2; i++) {
      int e = tid + i * 256;
      int r = e >> 3, s = e & 7;
      *(short8*)&Ks[r][s * 8] =
          *(const short8*)&kb[((size_t)(b * L_ + k0 + r)) * (HKV_ * PA_) + hk * PA_ + s * 8];
      *(short8*)&Vs[r][s * 8] =
          *(const short8*)&vt[((size_t)((b * HKV_ + hk) * PA_ + r)) * L_ + k0 + s * 8];
    }
    __syncthreads();
    f32x4 s_acc[4];
#pragma unroll
    for (int kb2 = 0; kb2 < 4; kb2++) {
      short8 b0 = *(const short8*)&Ks[kb2 * 16 + l15][lg * 8];
      short8 b1 = *(const short8*)&Ks[kb2 * 16 + l15][32 + lg * 8];
      f32x4 s = (f32x4){0.f, 0.f, 0.f, 0.f};
      s = __builtin_amdgcn_mfma_f32_16x16x32_bf16(qf[0], b0, s, 0, 0, 0);
      s = __builtin_amdgcn_mfma_f32_16x16x32_bf16(qf[1], b1, s, 0, 0, 0);
      s_acc[kb2] = s;
    }
    bool diag = (kt == qt);
#pragma unroll
    for (int reg = 0; reg < 4; reg++) {
      float sc[4];
      float tm = -3.0e38f;
#pragma unroll
      for (int kb2 = 0; kb2 < 4; kb2++) {
        float s = s_acc[kb2][reg] * 0.125f;
        if (diag) {
          int key = k0 + kb2 * 16 + l15;
          int qg = qw + lg * 4 + reg;
          if (key > qg) s = -3.0e38f;
        }
        sc[kb2] = s;
        tm = fmaxf(tm, s);
      }
#pragma unroll
      for (int of = 1; of < 16; of <<= 1) tm = fmaxf(tm, __shfl_xor(tm, of, 64));
      float mn = fmaxf(mrow[reg], tm);
      float corr = __expf(mrow[reg] - mn);
      mrow[reg] = mn;
      float rs = 0.f;
      int prow = lg * 4 + reg;
#pragma unroll
      for (int kb2 = 0; kb2 < 4; kb2++) {
        float p = __expf(sc[kb2] - mn);
        rs += p;
        __hip_bfloat16 hv = __float2bfloat16(p);
        Psm[w][prow][kb2 * 16 + l15] = *(unsigned short*)&hv;
      }
#pragma unroll
      for (int of = 1; of < 16; of <<= 1) rs += __shfl_xor(rs, of, 64);
      lsum[reg] = lsum[reg] * corr + rs;
#pragma unroll
      for (int db = 0; db < 4; db++) o_acc[db][reg] *= corr;
    }
    __syncthreads();
#pragma unroll
    for (int ks = 0; ks < 2; ks++) {
      short8 pa = *(const short8*)&Psm[w][l15][ks * 32 + lg * 8];
#pragma unroll
      for (int db = 0; db < 4; db++) {
        short8 vb8 = *(const short8*)&Vs[db * 16 + l15][ks * 32 + lg * 8];
        o_acc[db] = __builtin_amdgcn_mfma_f32_16x16x32_bf16(pa, vb8, o_acc[db], 0, 0, 0);
      }
    }
  }
#pragma unroll
  for (int reg = 0; reg < 4; reg++) {
    float invl = 1.0f / lsum[reg];
    size_t row = (size_t)(b * L_ + qw + lg * 4 + reg);
#pragma unroll
    for (int db = 0; db < 4; db++)
      ao[row * D_ + h * PA_ + db * 16 + l15] = __float2bfloat16(o_acc[db][reg] * invl);
  }
}

// ---------------- host ----------------
extern "C" void kernel_launch(void* const* d_in, const int* in_sizes, int n_in,
                              void* d_out, int out_size, void* d_ws, size_t ws_size,
                              hipStream_t stream) {
  (void)in_sizes; (void)n_in; (void)out_size; (void)ws_size;
  const float* x           = (const float*)d_in[0];
  const float* in_proj_w   = (const float*)d_in[1];
  const float* conv_w      = (const float*)d_in[2];
  const float* conv_b      = (const float*)d_in[3];
  const float* B_proj_w    = (const float*)d_in[4];
  const float* C_proj_w    = (const float*)d_in[5];
  const float* dt_bias     = (const float*)d_in[6];
  const float* A_log       = (const float*)d_in[7];
  const float* D_param     = (const float*)d_in[8];
  const float* out_proj_w  = (const float*)d_in[9];
  const float* resid_mix_m = (const float*)d_in[10];
  const float* mamba_scale = (const float*)d_in[11];
  const float* m_fc_w      = (const float*)d_in[12];
  const float* m_proj_w    = (const float*)d_in[13];
  const float* m_mlp_scale = (const float*)d_in[14];
  const float* resid_mix_a = (const float*)d_in[15];
  const float* q_w         = (const float*)d_in[16];
  const float* k_w         = (const float*)d_in[17];
  const float* v_w         = (const float*)d_in[18];
  const float* o_w         = (const float*)d_in[19];
  const float* q_gain      = (const float*)d_in[20];
  const float* attn_scale  = (const float*)d_in[21];
  const float* a_fc_w      = (const float*)d_in[22];
  const float* a_proj_w    = (const float*)d_in[23];
  const float* a_mlp_scale = (const float*)d_in[24];
  float* ws  = (float*)d_ws;
  float* out = (float*)d_out;

  // ---- workspace layout (float units), total ~207.1 MB ----
  float* xm    = ws;                                   // 4,194,304
  float* vgR   = ws + 4194304;                         // 8,388,608 (vg bf16 / qkv f32)
  float* xvR   = ws + 12582912;                        // 8,388,608 (xv f32 / attn bufs)
  float* stR   = ws + 20971520;                        // 8,388,608 (st f32 / hb bf16)
  float* nbR   = ws + 29360128;                        // 2,097,152 (nbb bf16 / ybb lo)
  float* xmbR  = ws + 31457280;                        // 2,097,152 (xmb bf16 / ybb hi)
  float* BmbR  = ws + 33554432;                        // 2,097,152
  float* CmbR  = ws + 35651584;                        // 2,097,152
  float* WtR   = ws + 37748736;                        // 13,893,632
  float* cosb  = ws + 51642368;                        // 65,536
  float* sinb  = cosb + 65536;

  __hip_bfloat16* vg  = (__hip_bfloat16*)vgR;          // [NT][4096] bf16
  float*          qkvf = vgR;                          // [NT][1536] f32 (aliases vg)
  float*          xv  = xvR;                           // [NT][2048] f32
  float*          st  = stR;
  __hip_bfloat16* hb  = (__hip_bfloat16*)stR;          // [NT][4096] bf16
  __hip_bfloat16* nbb = (__hip_bfloat16*)nbR;
  __hip_bfloat16* xmb = (__hip_bfloat16*)xmbR;
  __hip_bfloat16* ybb = (__hip_bfloat16*)nbR;          // [NT][2048] bf16 spans nbR+xmbR
  __hip_bfloat16* Bmb = (__hip_bfloat16*)BmbR;
  __hip_bfloat16* Cmb = (__hip_bfloat16*)CmbR;
  // attn buffers alias xv region
  __hip_bfloat16* qbb = (__hip_bfloat16*)xvR;                      // [NT][1024]
  __hip_bfloat16* kbb = (__hip_bfloat16*)(xvR + 2097152);          // [NT][256]
  __hip_bfloat16* vtb = (__hip_bfloat16*)(xvR + 2621440);          // [2][256][2048]
  __hip_bfloat16* aob = (__hip_bfloat16*)(xvR + 3145728);          // [NT][1024]

  __hip_bfloat16* Wt = (__hip_bfloat16*)WtR;
  size_t o_in  = 0;
  size_t o_B   = o_in  + (size_t)4096 * 1024;
  size_t o_C   = o_B   + (size_t)1024 * 1024;
  size_t o_out = o_C   + (size_t)1024 * 1024;
  size_t o_mfc = o_out + (size_t)1024 * 2048;
  size_t o_mpj = o_mfc + (size_t)4096 * 1024;
  size_t o_qkv = o_mpj + (size_t)1024 * 4096;          // q,k,v contiguous: 1536*1024
  size_t o_o   = o_qkv + (size_t)1536 * 1024;
  size_t o_afc = o_o   + (size_t)1024 * 1024;
  size_t o_apj = o_afc + (size_t)4096 * 1024;

#define TCVT(Wp, off, K, N) \
  transpose_cvt<<<dim3((N) / 32, (K) / 32), 256, 0, stream>>>((Wp), Wt + (off), (K), (N), (N))
  TCVT(in_proj_w,  o_in,  1024, 4096);
  TCVT(B_proj_w,   o_B,   1024, 1024);
  TCVT(C_proj_w,   o_C,   1024, 1024);
  TCVT(out_proj_w, o_out, 2048, 1024);
  TCVT(m_fc_w,     o_mfc, 1024, 4096);
  TCVT(m_proj_w,   o_mpj, 4096, 1024);
  TCVT(q_w,        o_qkv, 1024, 1024);
  TCVT(k_w,        o_qkv + (size_t)1024 * 1024, 1024, 256);
  TCVT(v_w,        o_qkv + (size_t)1280 * 1024, 1024, 256);
  TCVT(o_w,        o_o,   1024, 1024);
  TCVT(a_fc_w,     o_afc, 1024, 4096);
  TCVT(a_proj_w,   o_apj, 4096, 1024);
#undef TCVT

#define GEMM(Abuf, Woff, Cfp, Cbp, basep, scalep, N, K, mode) \
  gemm_bf16<<<dim3((N) / 128, NT_ / 128), 256, 0, stream>>>( \
      (const unsigned short*)(Abuf), (const unsigned short*)(Wt + (Woff)), \
      (Cfp), (Cbp), (basep), (scalep), (N), (K), (mode))

  // --- mamba branch ---
  mix_rms_kernel<<<NT_, 256, 0, stream>>>(x, x, resid_mix_m, xm, nbb, xmb);
  GEMM(nbb, o_in, (float*)0, vg, (const float*)0, (const float*)0, 4096, 1024, 2);
  GEMM(xmb, o_B, (float*)0, Bmb, (const float*)0, (const float*)0, 1024, 1024, 2);
  GEMM(xmb, o_C, (float*)0, Cmb, (const float*)0, (const float*)0, 1024, 1024, 2);
  conv_silu_kernel<<<NT_ * DI_ / 256, 256, 0, stream>>>(vg, conv_w, conv_b, xv);
  scanA1_kernel<<<B_ * HS_ * NC_, 256, 0, stream>>>(xv, Bmb, dt_bias, A_log, st);
  scanA2_kernel<<<B_ * HS_ * NC_, 256, 0, stream>>>(xv, Bmb, Cmb, dt_bias, A_log, D_param, xv);
  scanB1_kernel<<<B_ * HS_ * 4, 256, 0, stream>>>(st, dt_bias, A_log);
  scanB2_kernel<<<B_ * HS_ * NC_, 256, 0, stream>>>(Cmb, st, vg, dt_bias, A_log, xv, ybb);
  GEMM(ybb, o_out, xm, (__hip_bfloat16*)0, xm, mamba_scale, 1024, 2048, 3);
  // --- mamba MLP ---
  rms_kernel<<<NT_, 256, 0, stream>>>(xm, nbb);
  GEMM(nbb, o_mfc, (float*)0, hb, (const float*)0, (const float*)0, 4096, 1024, 1);
  GEMM(hb, o_mpj, xm, (__hip_bfloat16*)0, xm, m_mlp_scale, 1024, 4096, 3);
  // --- attention branch ---
  mix_rms_kernel<<<NT_, 256, 0, stream>>>(xm, x, resid_mix_a, xm, nbb, (__hip_bfloat16*)0);
  GEMM(nbb, o_qkv, qkvf, (__hip_bfloat16*)0, (const float*)0, (const float*)0, 1536, 1024, 0);
  rope_fill_kernel<<<L_ * 32 / 256, 256, 0, stream>>>(cosb, sinb);
  qknorm_rope_bf16_kernel<<<NT_ * HA_ / 4, 256, 0, stream>>>(qkvf, 1536, 0, qbb, HA_, cosb, sinb, q_gain);
  qknorm_rope_bf16_kernel<<<NT_ * HKV_ / 4, 256, 0, stream>>>(qkvf, 1536, 1024, kbb, HKV_, cosb, sinb, (const float*)0);
  transpose_cvt<<<dim3(256 / 32, 2048 / 32), 256, 0, stream>>>(qkvf + 1280, vtb, 2048, 256, 1536);
  transpose_cvt<<<dim3(256 / 32, 2048 / 32), 256, 0, stream>>>(qkvf + (size_t)L_ * 1536 + 1280, vtb + (size_t)256 * L_, 2048, 256, 1536);
  attn_mfma_kernel<<<B_ * HA_ * (L_ / 64), 256, 0, stream>>>(
      (const unsigned short*)qbb, (const unsigned short*)kbb, (const unsigned short*)vtb, aob);
  GEMM(aob, o_o, xm, (__hip_bfloat16*)0, xm, attn_scale, 1024, 1024, 3);
  // --- attention MLP ---
  rms_kernel<<<NT_, 256, 0, stream>>>(xm, nbb);
  GEMM(nbb, o_afc, (float*)0, hb, (const float*)0, (const float*)0, 4096, 1024, 1);
  GEMM(hb, o_apj, out, (__hip_bfloat16*)0, xm, a_mlp_scale, 1024, 4096, 3);
#undef GEMM
}

// Round 6
// 765.989 us; speedup vs baseline: 6.1671x; 1.1690x over previous
//
#include <hip/hip_runtime.h>
#include <hip/hip_bf16.h>
#include <math.h>

#define D_ 1024
#define DI_ 2048
#define HS_ 16
#define PS_ 128
#define NS_ 64
#define HA_ 16
#define HKV_ 4
#define PA_ 64
#define B_ 2
#define L_ 2048
#define NT_ 4096          // B_*L_
#define NC_ 32            // L_/64
#define RMS_EPS_ 1.1920929e-7f

typedef __attribute__((ext_vector_type(8))) short short8;
typedef __attribute__((ext_vector_type(4))) float f32x4;

#define GLOAD_LDS16(gp, lp)                                                        \
  __builtin_amdgcn_global_load_lds(                                               \
      (const __attribute__((address_space(1))) unsigned int*)(gp),                \
      (__attribute__((address_space(3))) unsigned int*)(lp), 16, 0, 0)

// ---------------- transpose + fp32->bf16: W[K rows x N cols, row-stride ldw] -> Wt[N][K] ----------------
__global__ __launch_bounds__(256) void transpose_cvt(
    const float* __restrict__ W, __hip_bfloat16* __restrict__ Wt, int K, int N, int ldw) {
  __shared__ float t[32][33];
  int n0 = blockIdx.x * 32, k0 = blockIdx.y * 32;
  int tx = threadIdx.x & 31, ty = threadIdx.x >> 5;
#pragma unroll
  for (int i = 0; i < 4; i++)
    t[ty + i * 8][tx] = W[(size_t)(k0 + ty + i * 8) * ldw + n0 + tx];
  __syncthreads();
#pragma unroll
  for (int i = 0; i < 4; i++)
    Wt[(size_t)(n0 + ty + i * 8) * K + k0 + tx] = __float2bfloat16(t[tx][ty + i * 8]);
}

// ---------------- bf16 MFMA GEMM, double-buffered, tile 128 x BN ----------------
// A row-major bf16 [M,K]; Wt row-major bf16 [N,K]; K mult of 64, M mult of 128, N mult of BN.
// mode 0: f32 out; 1: relu^2 -> bf16; 2: bf16; 3: f32 out = base + scale[col]*acc
template<int BN>
__global__ __launch_bounds__(256) void gemm_bf16_t(
    const unsigned short* __restrict__ A, const unsigned short* __restrict__ Wt,
    float* __restrict__ Cf, __hip_bfloat16* __restrict__ Cb,
    const float* __restrict__ baseb, const float* __restrict__ scale,
    int N, int K, int mode) {
  constexpr int nWc = BN / 64;       // wave columns: 2 (BN=128) or 1 (BN=64)
  constexpr int nWr = 4 / nWc;       // wave rows: 2 or 4
  constexpr int MF  = 8 / nWr;       // M fragments/wave: 4 or 2
  __shared__ unsigned short As[2][128 * 64];
  __shared__ unsigned short Bs[2][BN * 64];
  int bm = blockIdx.y * 128, bn = blockIdx.x * BN;
  int tid = threadIdx.x;
  int w = tid >> 6, l = tid & 63;
  int wr = w / nWc, wc = w % nWc;
  int l15 = l & 15, lg = l >> 4;
  f32x4 acc[MF][4];
#pragma unroll
  for (int i = 0; i < MF; i++)
#pragma unroll
    for (int j = 0; j < 4; j++) acc[i][j] = (f32x4){0.f, 0.f, 0.f, 0.f};
  int r_ = tid >> 3;
  int s_ = tid & 7;

  auto STAGE = [&](int k0, int nb) {
#pragma unroll
    for (int i = 0; i < 4; i++) {
      int r = i * 32 + r_;
      int kq = s_ ^ (r & 7);
      GLOAD_LDS16(A + (size_t)(bm + r) * K + k0 + kq * 8, &As[nb][r * 64 + s_ * 8]);
    }
#pragma unroll
    for (int i = 0; i < BN / 32; i++) {
      int r = i * 32 + r_;
      int kq = s_ ^ (r & 7);
      GLOAD_LDS16(Wt + (size_t)(bn + r) * K + k0 + kq * 8, &Bs[nb][r * 64 + s_ * 8]);
    }
  };

  STAGE(0, 0);
  __syncthreads();
  int cur = 0;
  for (int k0 = 0; k0 < K; k0 += 64) {
    if (k0 + 64 < K) STAGE(k0 + 64, cur ^ 1);
#pragma unroll
    for (int h = 0; h < 2; h++) {
      short8 af[MF], bfr[4];
#pragma unroll
      for (int i = 0; i < MF; i++) {
        int row = wr * (16 * MF) + i * 16 + l15;
        int c = h * 4 + lg;
        af[i] = *(const short8*)&As[cur][row * 64 + ((c ^ (row & 7)) << 3)];
      }
#pragma unroll
      for (int j = 0; j < 4; j++) {
        int row = wc * 64 + j * 16 + l15;
        int c = h * 4 + lg;
        bfr[j] = *(const short8*)&Bs[cur][row * 64 + ((c ^ (row & 7)) << 3)];
      }
#pragma unroll
      for (int i = 0; i < MF; i++)
#pragma unroll
        for (int j = 0; j < 4; j++)
          acc[i][j] = __builtin_amdgcn_mfma_f32_16x16x32_bf16(af[i], bfr[j], acc[i][j], 0, 0, 0);
    }
    __syncthreads();
    cur ^= 1;
  }
  int rb = lg * 4, cb2 = l15;
#pragma unroll
  for (int i = 0; i < MF; i++)
#pragma unroll
    for (int j = 0; j < 4; j++) {
      int gr = bm + wr * (16 * MF) + i * 16 + rb;
      int gc = bn + wc * 64 + j * 16 + cb2;
#pragma unroll
      for (int reg = 0; reg < 4; reg++) {
        float v = acc[i][j][reg];
        size_t idx = (size_t)(gr + reg) * N + gc;
        if (mode == 0) {
          Cf[idx] = v;
        } else if (mode == 1) {
          v = fmaxf(v, 0.f);
          Cb[idx] = __float2bfloat16(v * v);
        } else if (mode == 2) {
          Cb[idx] = __float2bfloat16(v);
        } else {
          Cf[idx] = baseb[idx] + scale[gc] * v;
        }
      }
    }
}

// ---------------- mix + rmsnorm ----------------
__global__ __launch_bounds__(256) void mix_rms_kernel(
    const float* __restrict__ a, const float* __restrict__ b2,
    const float* __restrict__ mix, float* __restrict__ xout,
    __hip_bfloat16* __restrict__ nbf, __hip_bfloat16* __restrict__ rawbf) {
  int row = blockIdx.x;
  size_t base = (size_t)row * D_;
  float v[4]; float ss = 0.f;
#pragma unroll
  for (int i = 0; i < 4; i++) {
    int d = threadIdx.x + i * 256;
    float val = mix[d] * a[base + d] + mix[D_ + d] * b2[base + d];
    v[i] = val; ss += val * val;
  }
  for (int o = 32; o > 0; o >>= 1) ss += __shfl_down(ss, o, 64);
  __shared__ float red[4];
  if ((threadIdx.x & 63) == 0) red[threadIdx.x >> 6] = ss;
  __syncthreads();
  float inv = rsqrtf((red[0] + red[1] + red[2] + red[3]) * (1.f / D_) + RMS_EPS_);
#pragma unroll
  for (int i = 0; i < 4; i++) {
    int d = threadIdx.x + i * 256;
    xout[base + d] = v[i];
    nbf[base + d] = __float2bfloat16(v[i] * inv);
    if (rawbf) rawbf[base + d] = __float2bfloat16(v[i]);
  }
}

__global__ __launch_bounds__(256) void rms_kernel(
    const float* __restrict__ a, __hip_bfloat16* __restrict__ nbf) {
  int row = blockIdx.x;
  size_t base = (size_t)row * D_;
  float v[4]; float ss = 0.f;
#pragma unroll
  for (int i = 0; i < 4; i++) {
    int d = threadIdx.x + i * 256;
    float val = a[base + d];
    v[i] = val; ss += val * val;
  }
  for (int o = 32; o > 0; o >>= 1) ss += __shfl_down(ss, o, 64);
  __shared__ float red[4];
  if ((threadIdx.x & 63) == 0) red[threadIdx.x >> 6] = ss;
  __syncthreads();
  float inv = rsqrtf((red[0] + red[1] + red[2] + red[3]) * (1.f / D_) + RMS_EPS_);
#pragma unroll
  for (int i = 0; i < 4; i++) {
    int d = threadIdx.x + i * 256;
    nbf[base + d] = __float2bfloat16(v[i] * inv);
  }
}

// ---------------- depthwise causal conv (KC=4) + SiLU; vg bf16 [NT][4096] cols 0..2047 ----------------
__global__ __launch_bounds__(256) void conv_silu_kernel(
    const __hip_bfloat16* __restrict__ vg, const float* __restrict__ cw,
    const float* __restrict__ cb, float* __restrict__ xv) {
  int idx = blockIdx.x * 256 + threadIdx.x;
  int c = idx & (DI_ - 1);
  int bl = idx >> 11;
  int l = bl & (L_ - 1);
  float acc = cb[c];
  float w0 = cw[c * 4 + 0], w1 = cw[c * 4 + 1], w2 = cw[c * 4 + 2], w3 = cw[c * 4 + 3];
  size_t rb = (size_t)bl * 4096 + c;
  if (l >= 3) acc += __bfloat162float(vg[rb - (size_t)3 * 4096]) * w0;
  if (l >= 2) acc += __bfloat162float(vg[rb - (size_t)2 * 4096]) * w1;
  if (l >= 1) acc += __bfloat162float(vg[rb - (size_t)1 * 4096]) * w2;
  acc += __bfloat162float(vg[rb]) * w3;
  xv[idx] = acc / (1.f + __expf(-acc));
}

// ---------------- scan pass A1; BC combined [NT][2048]: B at +0 ----------------
__global__ __launch_bounds__(256) void scanA1_kernel(
    const float* __restrict__ xv, const __hip_bfloat16* __restrict__ BCm,
    const float* __restrict__ dt_bias, const float* __restrict__ A_log,
    float* __restrict__ st) {
  __shared__ __align__(16) float sm[4096 + 8192];
  float* Bs = sm;
  float* Xs = sm + 4096;
  int blk = blockIdx.x;
  int c = blk & 31, h = (blk >> 5) & 15, b = blk >> 9;
  float dt = log1pf(__expf(dt_bias[h]));
  float adt = -__expf(A_log[h]) * dt;
  int tid = threadIdx.x;
  int l0 = c * 64;
  size_t rB = ((size_t)(b * L_ + l0)) * 2048 + h * NS_;
#pragma unroll
  for (int i = 0; i < 16; i++) {
    int e = tid + i * 256;
    int t = e >> 6, n = e & 63;
    Bs[t * 64 + n] = __bfloat162float(BCm[rB + (size_t)t * 2048 + n]);
  }
  size_t rX = ((size_t)(b * L_ + l0)) * DI_ + h * PS_;
#pragma unroll
  for (int i = 0; i < 32; i++) {
    int e = tid + i * 256;
    int t = e >> 7, p = e & 127;
    Xs[t * 128 + p] = xv[rX + (size_t)t * DI_ + p];
  }
  __syncthreads();
  int pg = tid & 31;
  int ng = (tid >> 5) << 3;
  float acc[8][4];
#pragma unroll
  for (int nn = 0; nn < 8; nn++)
#pragma unroll
    for (int i = 0; i < 4; i++) acc[nn][i] = 0.f;
  for (int t = 0; t < 64; t++) {
    float dr = __expf(adt * (float)(63 - t));
    float4 x4 = *(const float4*)&Xs[t * 128 + pg * 4];
    float xd0 = x4.x * dr, xd1 = x4.y * dr, xd2 = x4.z * dr, xd3 = x4.w * dr;
#pragma unroll
    for (int nn = 0; nn < 8; nn++) {
      float bv = Bs[t * 64 + ng + nn];
      acc[nn][0] += bv * xd0; acc[nn][1] += bv * xd1;
      acc[nn][2] += bv * xd2; acc[nn][3] += bv * xd3;
    }
  }
  size_t sb = ((size_t)((b * HS_ + h) * NC_ + c)) * (NS_ * PS_);
#pragma unroll
  for (int nn = 0; nn < 8; nn++) {
    *(float4*)&st[sb + (size_t)(ng + nn) * PS_ + pg * 4] =
        make_float4(acc[nn][0] * dt, acc[nn][1] * dt, acc[nn][2] * dt, acc[nn][3] * dt);
  }
}

// ---------------- scan pass A2; BC combined: B at +0, C at +1024 ----------------
__global__ __launch_bounds__(256) void scanA2_kernel(
    const float* __restrict__ xv, const __hip_bfloat16* __restrict__ BCm,
    const float* __restrict__ dt_bias,
    const float* __restrict__ A_log, const float* __restrict__ D_param,
    float* __restrict__ y) {
  __shared__ __align__(16) float sm[4160 + 8192];
  float* Cb = sm;
  float* Bs = sm + 4160;
  float* Xs = sm + 4160;
  int blk = blockIdx.x;
  int c = blk & 31, h = (blk >> 5) & 15, b = blk >> 9;
  float dt = log1pf(__expf(dt_bias[h]));
  float adt = -__expf(A_log[h]) * dt;
  float Dp = D_param[h];
  int tid = threadIdx.x;
  int l0 = c * 64;
  size_t rB = ((size_t)(b * L_ + l0)) * 2048 + h * NS_;
#pragma unroll
  for (int i = 0; i < 16; i++) {
    int e = tid + i * 256;
    int t = e >> 6, n = e & 63;
    Bs[t * 64 + n] = __bfloat162float(BCm[rB + (size_t)t * 2048 + n]);
    Cb[t * 65 + n] = __bfloat162float(BCm[rB + 1024 + (size_t)t * 2048 + n]);
  }
  __syncthreads();
  int q = tid >> 2;
  int kb = (tid & 3) << 4;
  float cbl[16];
#pragma unroll
  for (int kk = 0; kk < 16; kk++) {
    int k = kb + kk;
    float a = 0.f;
    if (k <= q) {
      for (int n = 0; n < 64; n++) a += Cb[q * 65 + n] * Bs[k * 64 + n];
      a *= __expf(adt * (float)(q - k));
    }
    cbl[kk] = a;
  }
  __syncthreads();
#pragma unroll
  for (int kk = 0; kk < 16; kk++) Cb[q * 65 + kb + kk] = cbl[kk];
  size_t rX = ((size_t)(b * L_ + l0)) * DI_ + h * PS_;
#pragma unroll
  for (int i = 0; i < 32; i++) {
    int e = tid + i * 256;
    int t = e >> 7, p = e & 127;
    Xs[t * 128 + p] = xv[rX + (size_t)t * DI_ + p];
  }
  __syncthreads();
  int pg = tid & 31;
  int qg = (tid >> 5) << 3;
  float acc[8][4];
#pragma unroll
  for (int qq = 0; qq < 8; qq++)
#pragma unroll
    for (int i = 0; i < 4; i++) acc[qq][i] = 0.f;
  for (int k = 0; k < 64; k++) {
    float4 x4 = *(const float4*)&Xs[k * 128 + pg * 4];
#pragma unroll
    for (int qq = 0; qq < 8; qq++) {
      float s = Cb[(qg + qq) * 65 + k];
      acc[qq][0] += s * x4.x; acc[qq][1] += s * x4.y;
      acc[qq][2] += s * x4.z; acc[qq][3] += s * x4.w;
    }
  }
#pragma unroll
  for (int qq = 0; qq < 8; qq++) {
    int qr = qg + qq;
    float4 xq = *(const float4*)&Xs[qr * 128 + pg * 4];
    size_t yo = ((size_t)(b * L_ + l0 + qr)) * DI_ + h * PS_ + pg * 4;
    *(float4*)&y[yo] = make_float4(acc[qq][0] * dt + Dp * xq.x,
                                   acc[qq][1] * dt + Dp * xq.y,
                                   acc[qq][2] * dt + Dp * xq.z,
                                   acc[qq][3] * dt + Dp * xq.w);
  }
}

// ---------------- scan pass B1: inter-chunk recurrence, 128 blocks ----------------
__global__ __launch_bounds__(256) void scanB1_kernel(
    float* __restrict__ st, const float* __restrict__ dt_bias,
    const float* __restrict__ A_log) {
  int slice = blockIdx.x & 3;
  int h = (blockIdx.x >> 2) & 15, b = blockIdx.x >> 6;
  float dt = log1pf(__expf(dt_bias[h]));
  float adt = -__expf(A_log[h]) * dt;
  float cdec = __expf(adt * 64.f);
  size_t base = ((size_t)(b * HS_ + h)) * NC_ * (NS_ * PS_) + slice * 2048 + threadIdx.x;
  float hreg[8];
#pragma unroll
  for (int j = 0; j < 8; j++) hreg[j] = 0.f;
  for (int c = 0; c < NC_; c++) {
    size_t o = base + (size_t)c * (NS_ * PS_);
#pragma unroll
    for (int j = 0; j < 8; j++) {
      float tmp = st[o + (size_t)j * 256];
      st[o + (size_t)j * 256] = hreg[j];
      hreg[j] = cdec * hreg[j] + tmp;
    }
  }
}

// ---------------- scan pass B2: y_off + gate SiLU -> bf16; C at +1024 ----------------
__global__ __launch_bounds__(256) void scanB2_kernel(
    const __hip_bfloat16* __restrict__ BCm, const float* __restrict__ st,
    const __hip_bfloat16* __restrict__ vg, const float* __restrict__ dt_bias,
    const float* __restrict__ A_log, const float* __restrict__ y,
    __hip_bfloat16* __restrict__ yout) {
  __shared__ float Cs[64 * 64];
  __shared__ __align__(16) float Hs[64 * 128];
  int blk = blockIdx.x;
  int c = blk & 31, h = (blk >> 5) & 15, b = blk >> 9;
  float dt = log1pf(__expf(dt_bias[h]));
  float adt = -__expf(A_log[h]) * dt;
  int tid = threadIdx.x;
  int l0 = c * 64;
  size_t rC = ((size_t)(b * L_ + l0)) * 2048 + 1024 + h * NS_;
#pragma unroll
  for (int i = 0; i < 16; i++) {
    int e = tid + i * 256;
    int t = e >> 6, n = e & 63;
    Cs[t * 64 + n] = __bfloat162float(BCm[rC + (size_t)t * 2048 + n]);
  }
  size_t sb = ((size_t)((b * HS_ + h) * NC_ + c)) * (NS_ * PS_);
#pragma unroll
  for (int i = 0; i < 32; i++) {
    int e = tid + i * 256;
    Hs[e] = st[sb + e];
  }
  __syncthreads();
  int pg = tid & 31;
  int tg = (tid >> 5) << 3;
  float acc[8][4];
#pragma unroll
  for (int tt = 0; tt < 8; tt++)
#pragma unroll
    for (int i = 0; i < 4; i++) acc[tt][i] = 0.f;
  for (int n = 0; n < 64; n++) {
    float4 h4 = *(const float4*)&Hs[n * 128 + pg * 4];
#pragma unroll
    for (int tt = 0; tt < 8; tt++) {
      float cv = Cs[(tg + tt) * 64 + n];
      acc[tt][0] += cv * h4.x; acc[tt][1] += cv * h4.y;
      acc[tt][2] += cv * h4.z; acc[tt][3] += cv * h4.w;
    }
  }
#pragma unroll
  for (int tt = 0; tt < 8; tt++) {
    int t = tg + tt;
    float dout = __expf(adt * (float)(t + 1));
    size_t row = (size_t)(b * L_ + l0 + t);
#pragma unroll
    for (int i = 0; i < 4; i++) {
      int p = pg * 4 + i;
      float g = __bfloat162float(vg[row * 4096 + 2048 + h * PS_ + p]);
      float yv = y[row * DI_ + h * PS_ + p] + acc[tt][i] * dout;
      yout[row * DI_ + h * PS_ + p] = __float2bfloat16(yv * (g / (1.f + __expf(-g))));
    }
  }
}

// ---------------- rope tables ----------------
__global__ void rope_fill_kernel(float* __restrict__ cosb, float* __restrict__ sinb) {
  int idx = blockIdx.x * 256 + threadIdx.x;
  int i = idx & 31, l = idx >> 5;
  float inv = __expf(-(2.0f * (float)i / (float)PA_) * logf(10000.0f));
  float ang = (float)l * inv;
  cosb[idx] = cosf(ang);
  sinb[idx] = sinf(ang);
}

// ---------------- per-head rmsnorm + rope (+gain), strided src -> packed bf16 dst ----------------
__global__ __launch_bounds__(256) void qknorm_rope_bf16_kernel(
    const float* __restrict__ src, int srcstride, int srcofs,
    __hip_bfloat16* __restrict__ dst, int nh,
    const float* __restrict__ cosb, const float* __restrict__ sinb,
    const float* __restrict__ gain) {
  int row = blockIdx.x * 4 + (threadIdx.x >> 6);
  int lane = threadIdx.x & 63;
  int h = row % nh;
  int tok = row / nh;
  int l = tok & (L_ - 1);
  float v = src[(size_t)tok * srcstride + srcofs + h * 64 + lane];
  float ss = v * v;
  for (int o = 32; o > 0; o >>= 1) ss += __shfl_xor(ss, o, 64);
  v *= rsqrtf(ss * (1.f / PA_) + RMS_EPS_);
  float partner = __shfl_xor(v, 32, 64);
  int i = lane & 31;
  float cth = cosb[l * 32 + i], sth = sinb[l * 32 + i];
  float out = (lane < 32) ? (v * cth + partner * sth) : (v * cth - partner * sth);
  if (gain) out *= gain[h];
  dst[(size_t)tok * (nh * 64) + h * 64 + lane] = __float2bfloat16(out);
}

// ---------------- causal GQA flash attention, bf16 MFMA, paired q-tiles ----------------
__global__ __launch_bounds__(256) void attn_mfma_kernel(
    const unsigned short* __restrict__ qb, const unsigned short* __restrict__ kb,
    const unsigned short* __restrict__ vt, __hip_bfloat16* __restrict__ ao) {
  __shared__ unsigned short Ks[64][72];
  __shared__ unsigned short Vs[64][72];
  __shared__ unsigned short Psm[4][16][72];
  int blk = blockIdx.x;
  int qi = blk & 15;                 // pair index: handles qt = qi and qt = 31-qi
  int h  = (blk >> 4) & 15;
  int b  = blk >> 8;
  int hk = h >> 2;
  int tid = threadIdx.x;
  int w = tid >> 6, l = tid & 63;
  int l15 = l & 15, lg = l >> 4;

  for (int pass = 0; pass < 2; pass++) {
    int qt = pass ? (31 - qi) : qi;
    int q0 = qt * 64;
    int qw = q0 + w * 16;
    short8 qf[2];
    {
      size_t qrow = ((size_t)(b * L_ + qw + l15)) * (HA_ * PA_) + h * PA_;
      qf[0] = *(const short8*)&qb[qrow + lg * 8];
      qf[1] = *(const short8*)&qb[qrow + 32 + lg * 8];
    }
    f32x4 o_acc[4];
#pragma unroll
    for (int db = 0; db < 4; db++) o_acc[db] = (f32x4){0.f, 0.f, 0.f, 0.f};
    float mrow[4] = {-3.0e38f, -3.0e38f, -3.0e38f, -3.0e38f};
    float lsum[4] = {0.f, 0.f, 0.f, 0.f};
    int nkt = qt + 1;
    for (int kt = 0; kt < nkt; kt++) {
      int k0 = kt * 64;
      __syncthreads();
#pragma unroll
      for (int i = 0; i < 2; i++) {
        int e = tid + i * 256;
        int r = e >> 3, s = e & 7;
        *(short8*)&Ks[r][s * 8] =
            *(const short8*)&kb[((size_t)(b * L_ + k0 + r)) * (HKV_ * PA_) + hk * PA_ + s * 8];
        *(short8*)&Vs[r][s * 8] =
            *(const short8*)&vt[((size_t)((b * HKV_ + hk) * PA_ + r)) * L_ + k0 + s * 8];
      }
      __syncthreads();
      f32x4 s_acc[4];
#pragma unroll
      for (int kb2 = 0; kb2 < 4; kb2++) {
        short8 b0 = *(const short8*)&Ks[kb2 * 16 + l15][lg * 8];
        short8 b1 = *(const short8*)&Ks[kb2 * 16 + l15][32 + lg * 8];
        f32x4 s = (f32x4){0.f, 0.f, 0.f, 0.f};
        s = __builtin_amdgcn_mfma_f32_16x16x32_bf16(qf[0], b0, s, 0, 0, 0);
        s = __builtin_amdgcn_mfma_f32_16x16x32_bf16(qf[1], b1, s, 0, 0, 0);
        s_acc[kb2] = s;
      }
      bool diag = (kt == qt);
#pragma unroll
      for (int reg = 0; reg < 4; reg++) {
        float sc[4];
        float tm = -3.0e38f;
#pragma unroll
        for (int kb2 = 0; kb2 < 4; kb2++) {
          float s = s_acc[kb2][reg] * 0.125f;
          if (diag) {
            int key = k0 + kb2 * 16 + l15;
            int qg = qw + lg * 4 + reg;
            if (key > qg) s = -3.0e38f;
          }
          sc[kb2] = s;
          tm = fmaxf(tm, s);
        }
#pragma unroll
        for (int of = 1; of < 16; of <<= 1) tm = fmaxf(tm, __shfl_xor(tm, of, 64));
        float mn = fmaxf(mrow[reg], tm);
        float corr = __expf(mrow[reg] - mn);
        mrow[reg] = mn;
        float rs = 0.f;
        int prow = lg * 4 + reg;
#pragma unroll
        for (int kb2 = 0; kb2 < 4; kb2++) {
          float p = __expf(sc[kb2] - mn);
          rs += p;
          __hip_bfloat16 hv = __float2bfloat16(p);
          Psm[w][prow][kb2 * 16 + l15] = *(unsigned short*)&hv;
        }
#pragma unroll
        for (int of = 1; of < 16; of <<= 1) rs += __shfl_xor(rs, of, 64);
        lsum[reg] = lsum[reg] * corr + rs;
#pragma unroll
        for (int db = 0; db < 4; db++) o_acc[db][reg] *= corr;
      }
      __syncthreads();
#pragma unroll
      for (int ks = 0; ks < 2; ks++) {
        short8 pa = *(const short8*)&Psm[w][l15][ks * 32 + lg * 8];
#pragma unroll
        for (int db = 0; db < 4; db++) {
          short8 vb8 = *(const short8*)&Vs[db * 16 + l15][ks * 32 + lg * 8];
          o_acc[db] = __builtin_amdgcn_mfma_f32_16x16x32_bf16(pa, vb8, o_acc[db], 0, 0, 0);
        }
      }
    }
#pragma unroll
    for (int reg = 0; reg < 4; reg++) {
      float invl = 1.0f / lsum[reg];
      size_t row = (size_t)(b * L_ + qw + lg * 4 + reg);
#pragma unroll
      for (int db = 0; db < 4; db++)
        ao[row * D_ + h * PA_ + db * 16 + l15] = __float2bfloat16(o_acc[db][reg] * invl);
    }
  }
}

// ---------------- host ----------------
extern "C" void kernel_launch(void* const* d_in, const int* in_sizes, int n_in,
                              void* d_out, int out_size, void* d_ws, size_t ws_size,
                              hipStream_t stream) {
  (void)in_sizes; (void)n_in; (void)out_size; (void)ws_size;
  const float* x           = (const float*)d_in[0];
  const float* in_proj_w   = (const float*)d_in[1];
  const float* conv_w      = (const float*)d_in[2];
  const float* conv_b      = (const float*)d_in[3];
  const float* B_proj_w    = (const float*)d_in[4];
  const float* C_proj_w    = (const float*)d_in[5];
  const float* dt_bias     = (const float*)d_in[6];
  const float* A_log       = (const float*)d_in[7];
  const float* D_param     = (const float*)d_in[8];
  const float* out_proj_w  = (const float*)d_in[9];
  const float* resid_mix_m = (const float*)d_in[10];
  const float* mamba_scale = (const float*)d_in[11];
  const float* m_fc_w      = (const float*)d_in[12];
  const float* m_proj_w    = (const float*)d_in[13];
  const float* m_mlp_scale = (const float*)d_in[14];
  const float* resid_mix_a = (const float*)d_in[15];
  const float* q_w         = (const float*)d_in[16];
  const float* k_w         = (const float*)d_in[17];
  const float* v_w         = (const float*)d_in[18];
  const float* o_w         = (const float*)d_in[19];
  const float* q_gain      = (const float*)d_in[20];
  const float* attn_scale  = (const float*)d_in[21];
  const float* a_fc_w      = (const float*)d_in[22];
  const float* a_proj_w    = (const float*)d_in[23];
  const float* a_mlp_scale = (const float*)d_in[24];
  float* ws  = (float*)d_ws;
  float* out = (float*)d_out;

  // ---- workspace layout (float units) ----
  float* xm    = ws;                                   // 4,194,304
  float* vgR   = ws + 4194304;                         // 8,388,608 (vg bf16 / qkv f32)
  float* xvR   = ws + 12582912;                        // 8,388,608 (xv f32 / attn bufs)
  float* stR   = ws + 20971520;                        // 8,388,608 (st f32 / hb bf16)
  float* nbR   = ws + 29360128;                        // 2,097,152 (nbb bf16 / ybb lo)
  float* xmbR  = ws + 31457280;                        // 2,097,152 (xmb bf16 / ybb hi)
  float* BCR   = ws + 33554432;                        // 4,194,304 (BC combined bf16 [NT][2048])
  float* WtR   = ws + 37748736;                        // 13,893,632
  float* cosb  = ws + 51642368;                        // 65,536
  float* sinb  = cosb + 65536;

  __hip_bfloat16* vg  = (__hip_bfloat16*)vgR;          // [NT][4096] bf16
  float*          qkvf = vgR;                          // [NT][1536] f32 (aliases vg)
  float*          xv  = xvR;                           // [NT][2048] f32
  float*          st  = stR;
  __hip_bfloat16* hb  = (__hip_bfloat16*)stR;          // [NT][4096] bf16
  __hip_bfloat16* nbb = (__hip_bfloat16*)nbR;
  __hip_bfloat16* xmb = (__hip_bfloat16*)xmbR;
  __hip_bfloat16* ybb = (__hip_bfloat16*)nbR;          // [NT][2048] bf16 spans nbR+xmbR
  __hip_bfloat16* BCm = (__hip_bfloat16*)BCR;          // [NT][2048] bf16
  __hip_bfloat16* qbb = (__hip_bfloat16*)xvR;                      // [NT][1024]
  __hip_bfloat16* kbb = (__hip_bfloat16*)(xvR + 2097152);          // [NT][256]
  __hip_bfloat16* vtb = (__hip_bfloat16*)(xvR + 2621440);          // [2][256][2048]
  __hip_bfloat16* aob = (__hip_bfloat16*)(xvR + 3145728);          // [NT][1024]

  __hip_bfloat16* Wt = (__hip_bfloat16*)WtR;
  size_t o_in  = 0;
  size_t o_B   = o_in  + (size_t)4096 * 1024;          // B then C contiguous (N=2048)
  size_t o_out = o_B   + (size_t)2048 * 1024;
  size_t o_mfc = o_out + (size_t)1024 * 2048;
  size_t o_mpj = o_mfc + (size_t)4096 * 1024;
  size_t o_qkv = o_mpj + (size_t)1024 * 4096;
  size_t o_o   = o_qkv + (size_t)1536 * 1024;
  size_t o_afc = o_o   + (size_t)1024 * 1024;
  size_t o_apj = o_afc + (size_t)4096 * 1024;

#define TCVT(Wp, off, K, N) \
  transpose_cvt<<<dim3((N) / 32, (K) / 32), 256, 0, stream>>>((Wp), Wt + (off), (K), (N), (N))
  TCVT(in_proj_w,  o_in,  1024, 4096);
  TCVT(B_proj_w,   o_B,   1024, 1024);
  TCVT(C_proj_w,   o_B + (size_t)1024 * 1024, 1024, 1024);
  TCVT(out_proj_w, o_out, 2048, 1024);
  TCVT(m_fc_w,     o_mfc, 1024, 4096);
  TCVT(m_proj_w,   o_mpj, 4096, 1024);
  TCVT(q_w,        o_qkv, 1024, 1024);
  TCVT(k_w,        o_qkv + (size_t)1024 * 1024, 1024, 256);
  TCVT(v_w,        o_qkv + (size_t)1280 * 1024, 1024, 256);
  TCVT(o_w,        o_o,   1024, 1024);
  TCVT(a_fc_w,     o_afc, 1024, 4096);
  TCVT(a_proj_w,   o_apj, 4096, 1024);
#undef TCVT

#define GEMM(BN, Abuf, Woff, Cfp, Cbp, basep, scalep, N, K, mode) \
  gemm_bf16_t<BN><<<dim3((N) / (BN), NT_ / 128), 256, 0, stream>>>( \
      (const unsigned short*)(Abuf), (const unsigned short*)(Wt + (Woff)), \
      (Cfp), (Cbp), (basep), (scalep), (N), (K), (mode))

  // --- mamba branch ---
  mix_rms_kernel<<<NT_, 256, 0, stream>>>(x, x, resid_mix_m, xm, nbb, xmb);
  GEMM(128, nbb, o_in, (float*)0, vg, (const float*)0, (const float*)0, 4096, 1024, 2);
  GEMM(128, xmb, o_B, (float*)0, BCm, (const float*)0, (const float*)0, 2048, 1024, 2);
  conv_silu_kernel<<<NT_ * DI_ / 256, 256, 0, stream>>>(vg, conv_w, conv_b, xv);
  scanA1_kernel<<<B_ * HS_ * NC_, 256, 0, stream>>>(xv, BCm, dt_bias, A_log, st);
  scanA2_kernel<<<B_ * HS_ * NC_, 256, 0, stream>>>(xv, BCm, dt_bias, A_log, D_param, xv);
  scanB1_kernel<<<B_ * HS_ * 4, 256, 0, stream>>>(st, dt_bias, A_log);
  scanB2_kernel<<<B_ * HS_ * NC_, 256, 0, stream>>>(BCm, st, vg, dt_bias, A_log, xv, ybb);
  GEMM(64, ybb, o_out, xm, (__hip_bfloat16*)0, xm, mamba_scale, 1024, 2048, 3);
  // --- mamba MLP ---
  rms_kernel<<<NT_, 256, 0, stream>>>(xm, nbb);
  GEMM(128, nbb, o_mfc, (float*)0, hb, (const float*)0, (const float*)0, 4096, 1024, 1);
  GEMM(64, hb, o_mpj, xm, (__hip_bfloat16*)0, xm, m_mlp_scale, 1024, 4096, 3);
  // --- attention branch ---
  mix_rms_kernel<<<NT_, 256, 0, stream>>>(xm, x, resid_mix_a, xm, nbb, (__hip_bfloat16*)0);
  GEMM(64, nbb, o_qkv, qkvf, (__hip_bfloat16*)0, (const float*)0, (const float*)0, 1536, 1024, 0);
  rope_fill_kernel<<<L_ * 32 / 256, 256, 0, stream>>>(cosb, sinb);
  qknorm_rope_bf16_kernel<<<NT_ * HA_ / 4, 256, 0, stream>>>(qkvf, 1536, 0, qbb, HA_, cosb, sinb, q_gain);
  qknorm_rope_bf16_kernel<<<NT_ * HKV_ / 4, 256, 0, stream>>>(qkvf, 1536, 1024, kbb, HKV_, cosb, sinb, (const float*)0);
  transpose_cvt<<<dim3(256 / 32, 2048 / 32), 256, 0, stream>>>(qkvf + 1280, vtb, 2048, 256, 1536);
  transpose_cvt<<<dim3(256 / 32, 2048 / 32), 256, 0, stream>>>(qkvf + (size_t)L_ * 1536 + 1280, vtb + (size_t)256 * L_, 2048, 256, 1536);
  attn_mfma_kernel<<<B_ * HA_ * 16, 256, 0, stream>>>(
      (const unsigned short*)qbb, (const unsigned short*)kbb, (const unsigned short*)vtb, aob);
  GEMM(64, aob, o_o, xm, (__hip_bfloat16*)0, xm, attn_scale, 1024, 1024, 3);
  // --- attention MLP ---
  rms_kernel<<<NT_, 256, 0, stream>>>(xm, nbb);
  GEMM(128, nbb, o_afc, (float*)0, hb, (const float*)0, (const float*)0, 4096, 1024, 1);
  GEMM(64, hb, o_apj, out, (__hip_bfloat16*)0, xm, a_mlp_scale, 1024, 4096, 3);
#undef GEMM
}

// Round 7
// 711.334 us; speedup vs baseline: 6.6410x; 1.0768x over previous
//
#include <hip/hip_runtime.h>
#include <hip/hip_bf16.h>
#include <math.h>

#define D_ 1024
#define DI_ 2048
#define HS_ 16
#define PS_ 128
#define NS_ 64
#define HA_ 16
#define HKV_ 4
#define PA_ 64
#define B_ 2
#define L_ 2048
#define NT_ 4096          // B_*L_
#define NC_ 32            // L_/64
#define RMS_EPS_ 1.1920929e-7f

typedef __attribute__((ext_vector_type(8))) short short8;
typedef __attribute__((ext_vector_type(4))) float f32x4;

#define GLOAD_LDS16(gp, lp)                                                        \
  __builtin_amdgcn_global_load_lds(                                               \
      (const __attribute__((address_space(1))) unsigned int*)(gp),                \
      (__attribute__((address_space(3))) unsigned int*)(lp), 16, 0, 0)

// ---------------- transpose + fp32->bf16: W[K rows x N cols, row-stride ldw] -> Wt[N][K] ----------------
__global__ __launch_bounds__(256) void transpose_cvt(
    const float* __restrict__ W, __hip_bfloat16* __restrict__ Wt, int K, int N, int ldw) {
  __shared__ float t[32][33];
  int n0 = blockIdx.x * 32, k0 = blockIdx.y * 32;
  int tx = threadIdx.x & 31, ty = threadIdx.x >> 5;
#pragma unroll
  for (int i = 0; i < 4; i++)
    t[ty + i * 8][tx] = W[(size_t)(k0 + ty + i * 8) * ldw + n0 + tx];
  __syncthreads();
#pragma unroll
  for (int i = 0; i < 4; i++)
    Wt[(size_t)(n0 + ty + i * 8) * K + k0 + tx] = __float2bfloat16(t[tx][ty + i * 8]);
}

// ---------------- bf16 MFMA GEMM, double-buffered, tile 128 x BN ----------------
// mode 0: f32 out; 1: relu^2 -> bf16; 2: bf16; 3: f32 out = base + scale[col]*acc
template<int BN>
__global__ __launch_bounds__(256) void gemm_bf16_t(
    const unsigned short* __restrict__ A, const unsigned short* __restrict__ Wt,
    float* __restrict__ Cf, __hip_bfloat16* __restrict__ Cb,
    const float* __restrict__ baseb, const float* __restrict__ scale,
    int N, int K, int mode) {
  constexpr int nWc = BN / 64;
  constexpr int nWr = 4 / nWc;
  constexpr int MF  = 8 / nWr;
  __shared__ unsigned short As[2][128 * 64];
  __shared__ unsigned short Bs[2][BN * 64];
  int bm = blockIdx.y * 128, bn = blockIdx.x * BN;
  int tid = threadIdx.x;
  int w = tid >> 6, l = tid & 63;
  int wr = w / nWc, wc = w % nWc;
  int l15 = l & 15, lg = l >> 4;
  f32x4 acc[MF][4];
#pragma unroll
  for (int i = 0; i < MF; i++)
#pragma unroll
    for (int j = 0; j < 4; j++) acc[i][j] = (f32x4){0.f, 0.f, 0.f, 0.f};
  int r_ = tid >> 3;
  int s_ = tid & 7;

  auto STAGE = [&](int k0, int nb) {
#pragma unroll
    for (int i = 0; i < 4; i++) {
      int r = i * 32 + r_;
      int kq = s_ ^ (r & 7);
      GLOAD_LDS16(A + (size_t)(bm + r) * K + k0 + kq * 8, &As[nb][r * 64 + s_ * 8]);
    }
#pragma unroll
    for (int i = 0; i < BN / 32; i++) {
      int r = i * 32 + r_;
      int kq = s_ ^ (r & 7);
      GLOAD_LDS16(Wt + (size_t)(bn + r) * K + k0 + kq * 8, &Bs[nb][r * 64 + s_ * 8]);
    }
  };

  STAGE(0, 0);
  __syncthreads();
  int cur = 0;
  for (int k0 = 0; k0 < K; k0 += 64) {
    if (k0 + 64 < K) STAGE(k0 + 64, cur ^ 1);
#pragma unroll
    for (int h = 0; h < 2; h++) {
      short8 af[MF], bfr[4];
#pragma unroll
      for (int i = 0; i < MF; i++) {
        int row = wr * (16 * MF) + i * 16 + l15;
        int c = h * 4 + lg;
        af[i] = *(const short8*)&As[cur][row * 64 + ((c ^ (row & 7)) << 3)];
      }
#pragma unroll
      for (int j = 0; j < 4; j++) {
        int row = wc * 64 + j * 16 + l15;
        int c = h * 4 + lg;
        bfr[j] = *(const short8*)&Bs[cur][row * 64 + ((c ^ (row & 7)) << 3)];
      }
#pragma unroll
      for (int i = 0; i < MF; i++)
#pragma unroll
        for (int j = 0; j < 4; j++)
          acc[i][j] = __builtin_amdgcn_mfma_f32_16x16x32_bf16(af[i], bfr[j], acc[i][j], 0, 0, 0);
    }
    __syncthreads();
    cur ^= 1;
  }
  int rb = lg * 4, cb2 = l15;
#pragma unroll
  for (int i = 0; i < MF; i++)
#pragma unroll
    for (int j = 0; j < 4; j++) {
      int gr = bm + wr * (16 * MF) + i * 16 + rb;
      int gc = bn + wc * 64 + j * 16 + cb2;
#pragma unroll
      for (int reg = 0; reg < 4; reg++) {
        float v = acc[i][j][reg];
        size_t idx = (size_t)(gr + reg) * N + gc;
        if (mode == 0) {
          Cf[idx] = v;
        } else if (mode == 1) {
          v = fmaxf(v, 0.f);
          Cb[idx] = __float2bfloat16(v * v);
        } else if (mode == 2) {
          Cb[idx] = __float2bfloat16(v);
        } else {
          Cf[idx] = baseb[idx] + scale[gc] * v;
        }
      }
    }
}

// ---------------- mix + rmsnorm ----------------
__global__ __launch_bounds__(256) void mix_rms_kernel(
    const float* __restrict__ a, const float* __restrict__ b2,
    const float* __restrict__ mix, float* __restrict__ xout,
    __hip_bfloat16* __restrict__ nbf, __hip_bfloat16* __restrict__ rawbf) {
  int row = blockIdx.x;
  size_t base = (size_t)row * D_;
  float v[4]; float ss = 0.f;
#pragma unroll
  for (int i = 0; i < 4; i++) {
    int d = threadIdx.x + i * 256;
    float val = mix[d] * a[base + d] + mix[D_ + d] * b2[base + d];
    v[i] = val; ss += val * val;
  }
  for (int o = 32; o > 0; o >>= 1) ss += __shfl_down(ss, o, 64);
  __shared__ float red[4];
  if ((threadIdx.x & 63) == 0) red[threadIdx.x >> 6] = ss;
  __syncthreads();
  float inv = rsqrtf((red[0] + red[1] + red[2] + red[3]) * (1.f / D_) + RMS_EPS_);
#pragma unroll
  for (int i = 0; i < 4; i++) {
    int d = threadIdx.x + i * 256;
    xout[base + d] = v[i];
    nbf[base + d] = __float2bfloat16(v[i] * inv);
    if (rawbf) rawbf[base + d] = __float2bfloat16(v[i]);
  }
}

__global__ __launch_bounds__(256) void rms_kernel(
    const float* __restrict__ a, __hip_bfloat16* __restrict__ nbf) {
  int row = blockIdx.x;
  size_t base = (size_t)row * D_;
  float v[4]; float ss = 0.f;
#pragma unroll
  for (int i = 0; i < 4; i++) {
    int d = threadIdx.x + i * 256;
    float val = a[base + d];
    v[i] = val; ss += val * val;
  }
  for (int o = 32; o > 0; o >>= 1) ss += __shfl_down(ss, o, 64);
  __shared__ float red[4];
  if ((threadIdx.x & 63) == 0) red[threadIdx.x >> 6] = ss;
  __syncthreads();
  float inv = rsqrtf((red[0] + red[1] + red[2] + red[3]) * (1.f / D_) + RMS_EPS_);
#pragma unroll
  for (int i = 0; i < 4; i++) {
    int d = threadIdx.x + i * 256;
    nbf[base + d] = __float2bfloat16(v[i] * inv);
  }
}

// ---------------- depthwise causal conv (KC=4) + SiLU; vg bf16 [NT][4096] cols 0..2047 ----------------
__global__ __launch_bounds__(256) void conv_silu_kernel(
    const __hip_bfloat16* __restrict__ vg, const float* __restrict__ cw,
    const float* __restrict__ cb, float* __restrict__ xv) {
  int idx = blockIdx.x * 256 + threadIdx.x;
  int c = idx & (DI_ - 1);
  int bl = idx >> 11;
  int l = bl & (L_ - 1);
  float acc = cb[c];
  float w0 = cw[c * 4 + 0], w1 = cw[c * 4 + 1], w2 = cw[c * 4 + 2], w3 = cw[c * 4 + 3];
  size_t rb = (size_t)bl * 4096 + c;
  if (l >= 3) acc += __bfloat162float(vg[rb - (size_t)3 * 4096]) * w0;
  if (l >= 2) acc += __bfloat162float(vg[rb - (size_t)2 * 4096]) * w1;
  if (l >= 1) acc += __bfloat162float(vg[rb - (size_t)1 * 4096]) * w2;
  acc += __bfloat162float(vg[rb]) * w3;
  xv[idx] = acc / (1.f + __expf(-acc));
}

// ---------------- scan pass A1; BC combined [NT][2048]: B at +0 ----------------
__global__ __launch_bounds__(256) void scanA1_kernel(
    const float* __restrict__ xv, const __hip_bfloat16* __restrict__ BCm,
    const float* __restrict__ dt_bias, const float* __restrict__ A_log,
    float* __restrict__ st) {
  __shared__ __align__(16) float sm[4096 + 8192];
  float* Bs = sm;
  float* Xs = sm + 4096;
  int blk = blockIdx.x;
  int c = blk & 31, h = (blk >> 5) & 15, b = blk >> 9;
  float dt = log1pf(__expf(dt_bias[h]));
  float adt = -__expf(A_log[h]) * dt;
  int tid = threadIdx.x;
  int l0 = c * 64;
  size_t rB = ((size_t)(b * L_ + l0)) * 2048 + h * NS_;
#pragma unroll
  for (int i = 0; i < 16; i++) {
    int e = tid + i * 256;
    int t = e >> 6, n = e & 63;
    Bs[t * 64 + n] = __bfloat162float(BCm[rB + (size_t)t * 2048 + n]);
  }
  size_t rX = ((size_t)(b * L_ + l0)) * DI_ + h * PS_;
#pragma unroll
  for (int i = 0; i < 32; i++) {
    int e = tid + i * 256;
    int t = e >> 7, p = e & 127;
    Xs[t * 128 + p] = xv[rX + (size_t)t * DI_ + p];
  }
  __syncthreads();
  int pg = tid & 31;
  int ng = (tid >> 5) << 3;
  float acc[8][4];
#pragma unroll
  for (int nn = 0; nn < 8; nn++)
#pragma unroll
    for (int i = 0; i < 4; i++) acc[nn][i] = 0.f;
  for (int t = 0; t < 64; t++) {
    float dr = __expf(adt * (float)(63 - t));
    float4 x4 = *(const float4*)&Xs[t * 128 + pg * 4];
    float xd0 = x4.x * dr, xd1 = x4.y * dr, xd2 = x4.z * dr, xd3 = x4.w * dr;
#pragma unroll
    for (int nn = 0; nn < 8; nn++) {
      float bv = Bs[t * 64 + ng + nn];
      acc[nn][0] += bv * xd0; acc[nn][1] += bv * xd1;
      acc[nn][2] += bv * xd2; acc[nn][3] += bv * xd3;
    }
  }
  size_t sb = ((size_t)((b * HS_ + h) * NC_ + c)) * (NS_ * PS_);
#pragma unroll
  for (int nn = 0; nn < 8; nn++) {
    *(float4*)&st[sb + (size_t)(ng + nn) * PS_ + pg * 4] =
        make_float4(acc[nn][0] * dt, acc[nn][1] * dt, acc[nn][2] * dt, acc[nn][3] * dt);
  }
}

// ---------------- scan pass A2; BC combined: B at +0, C at +1024 ----------------
__global__ __launch_bounds__(256) void scanA2_kernel(
    const float* __restrict__ xv, const __hip_bfloat16* __restrict__ BCm,
    const float* __restrict__ dt_bias,
    const float* __restrict__ A_log, const float* __restrict__ D_param,
    float* __restrict__ y) {
  __shared__ __align__(16) float sm[4160 + 8192];
  float* Cb = sm;
  float* Bs = sm + 4160;
  float* Xs = sm + 4160;
  int blk = blockIdx.x;
  int c = blk & 31, h = (blk >> 5) & 15, b = blk >> 9;
  float dt = log1pf(__expf(dt_bias[h]));
  float adt = -__expf(A_log[h]) * dt;
  float Dp = D_param[h];
  int tid = threadIdx.x;
  int l0 = c * 64;
  size_t rB = ((size_t)(b * L_ + l0)) * 2048 + h * NS_;
#pragma unroll
  for (int i = 0; i < 16; i++) {
    int e = tid + i * 256;
    int t = e >> 6, n = e & 63;
    Bs[t * 64 + n] = __bfloat162float(BCm[rB + (size_t)t * 2048 + n]);
    Cb[t * 65 + n] = __bfloat162float(BCm[rB + 1024 + (size_t)t * 2048 + n]);
  }
  __syncthreads();
  int q = tid >> 2;
  int kb = (tid & 3) << 4;
  float cbl[16];
#pragma unroll
  for (int kk = 0; kk < 16; kk++) {
    int k = kb + kk;
    float a = 0.f;
    if (k <= q) {
      for (int n = 0; n < 64; n++) a += Cb[q * 65 + n] * Bs[k * 64 + n];
      a *= __expf(adt * (float)(q - k));
    }
    cbl[kk] = a;
  }
  __syncthreads();
#pragma unroll
  for (int kk = 0; kk < 16; kk++) Cb[q * 65 + kb + kk] = cbl[kk];
  size_t rX = ((size_t)(b * L_ + l0)) * DI_ + h * PS_;
#pragma unroll
  for (int i = 0; i < 32; i++) {
    int e = tid + i * 256;
    int t = e >> 7, p = e & 127;
    Xs[t * 128 + p] = xv[rX + (size_t)t * DI_ + p];
  }
  __syncthreads();
  int pg = tid & 31;
  int qg = (tid >> 5) << 3;
  float acc[8][4];
#pragma unroll
  for (int qq = 0; qq < 8; qq++)
#pragma unroll
    for (int i = 0; i < 4; i++) acc[qq][i] = 0.f;
  for (int k = 0; k < 64; k++) {
    float4 x4 = *(const float4*)&Xs[k * 128 + pg * 4];
#pragma unroll
    for (int qq = 0; qq < 8; qq++) {
      float s = Cb[(qg + qq) * 65 + k];
      acc[qq][0] += s * x4.x; acc[qq][1] += s * x4.y;
      acc[qq][2] += s * x4.z; acc[qq][3] += s * x4.w;
    }
  }
#pragma unroll
  for (int qq = 0; qq < 8; qq++) {
    int qr = qg + qq;
    float4 xq = *(const float4*)&Xs[qr * 128 + pg * 4];
    size_t yo = ((size_t)(b * L_ + l0 + qr)) * DI_ + h * PS_ + pg * 4;
    *(float4*)&y[yo] = make_float4(acc[qq][0] * dt + Dp * xq.x,
                                   acc[qq][1] * dt + Dp * xq.y,
                                   acc[qq][2] * dt + Dp * xq.z,
                                   acc[qq][3] * dt + Dp * xq.w);
  }
}

// ---------------- scan pass B1: inter-chunk recurrence, 128 blocks ----------------
__global__ __launch_bounds__(256) void scanB1_kernel(
    float* __restrict__ st, const float* __restrict__ dt_bias,
    const float* __restrict__ A_log) {
  int slice = blockIdx.x & 3;
  int h = (blockIdx.x >> 2) & 15, b = blockIdx.x >> 6;
  float dt = log1pf(__expf(dt_bias[h]));
  float adt = -__expf(A_log[h]) * dt;
  float cdec = __expf(adt * 64.f);
  size_t base = ((size_t)(b * HS_ + h)) * NC_ * (NS_ * PS_) + slice * 2048 + threadIdx.x;
  float hreg[8];
#pragma unroll
  for (int j = 0; j < 8; j++) hreg[j] = 0.f;
  for (int c = 0; c < NC_; c++) {
    size_t o = base + (size_t)c * (NS_ * PS_);
#pragma unroll
    for (int j = 0; j < 8; j++) {
      float tmp = st[o + (size_t)j * 256];
      st[o + (size_t)j * 256] = hreg[j];
      hreg[j] = cdec * hreg[j] + tmp;
    }
  }
}

// ---------------- scan pass B2: y_off + gate SiLU -> bf16; C at +1024 ----------------
__global__ __launch_bounds__(256) void scanB2_kernel(
    const __hip_bfloat16* __restrict__ BCm, const float* __restrict__ st,
    const __hip_bfloat16* __restrict__ vg, const float* __restrict__ dt_bias,
    const float* __restrict__ A_log, const float* __restrict__ y,
    __hip_bfloat16* __restrict__ yout) {
  __shared__ float Cs[64 * 64];
  __shared__ __align__(16) float Hs[64 * 128];
  int blk = blockIdx.x;
  int c = blk & 31, h = (blk >> 5) & 15, b = blk >> 9;
  float dt = log1pf(__expf(dt_bias[h]));
  float adt = -__expf(A_log[h]) * dt;
  int tid = threadIdx.x;
  int l0 = c * 64;
  size_t rC = ((size_t)(b * L_ + l0)) * 2048 + 1024 + h * NS_;
#pragma unroll
  for (int i = 0; i < 16; i++) {
    int e = tid + i * 256;
    int t = e >> 6, n = e & 63;
    Cs[t * 64 + n] = __bfloat162float(BCm[rC + (size_t)t * 2048 + n]);
  }
  size_t sb = ((size_t)((b * HS_ + h) * NC_ + c)) * (NS_ * PS_);
#pragma unroll
  for (int i = 0; i < 32; i++) {
    int e = tid + i * 256;
    Hs[e] = st[sb + e];
  }
  __syncthreads();
  int pg = tid & 31;
  int tg = (tid >> 5) << 3;
  float acc[8][4];
#pragma unroll
  for (int tt = 0; tt < 8; tt++)
#pragma unroll
    for (int i = 0; i < 4; i++) acc[tt][i] = 0.f;
  for (int n = 0; n < 64; n++) {
    float4 h4 = *(const float4*)&Hs[n * 128 + pg * 4];
#pragma unroll
    for (int tt = 0; tt < 8; tt++) {
      float cv = Cs[(tg + tt) * 64 + n];
      acc[tt][0] += cv * h4.x; acc[tt][1] += cv * h4.y;
      acc[tt][2] += cv * h4.z; acc[tt][3] += cv * h4.w;
    }
  }
#pragma unroll
  for (int tt = 0; tt < 8; tt++) {
    int t = tg + tt;
    float dout = __expf(adt * (float)(t + 1));
    size_t row = (size_t)(b * L_ + l0 + t);
#pragma unroll
    for (int i = 0; i < 4; i++) {
      int p = pg * 4 + i;
      float g = __bfloat162float(vg[row * 4096 + 2048 + h * PS_ + p]);
      float yv = y[row * DI_ + h * PS_ + p] + acc[tt][i] * dout;
      yout[row * DI_ + h * PS_ + p] = __float2bfloat16(yv * (g / (1.f + __expf(-g))));
    }
  }
}

// ---------------- rope tables ----------------
__global__ void rope_fill_kernel(float* __restrict__ cosb, float* __restrict__ sinb) {
  int idx = blockIdx.x * 256 + threadIdx.x;
  int i = idx & 31, l = idx >> 5;
  float inv = __expf(-(2.0f * (float)i / (float)PA_) * logf(10000.0f));
  float ang = (float)l * inv;
  cosb[idx] = cosf(ang);
  sinb[idx] = sinf(ang);
}

// ---------------- per-head rmsnorm + rope (+gain), strided src -> packed bf16 dst ----------------
__global__ __launch_bounds__(256) void qknorm_rope_bf16_kernel(
    const float* __restrict__ src, int srcstride, int srcofs,
    __hip_bfloat16* __restrict__ dst, int nh,
    const float* __restrict__ cosb, const float* __restrict__ sinb,
    const float* __restrict__ gain) {
  int row = blockIdx.x * 4 + (threadIdx.x >> 6);
  int lane = threadIdx.x & 63;
  int h = row % nh;
  int tok = row / nh;
  int l = tok & (L_ - 1);
  float v = src[(size_t)tok * srcstride + srcofs + h * 64 + lane];
  float ss = v * v;
  for (int o = 32; o > 0; o >>= 1) ss += __shfl_xor(ss, o, 64);
  v *= rsqrtf(ss * (1.f / PA_) + RMS_EPS_);
  float partner = __shfl_xor(v, 32, 64);
  int i = lane & 31;
  float cth = cosb[l * 32 + i], sth = sinb[l * 32 + i];
  float out = (lane < 32) ? (v * cth + partner * sth) : (v * cth - partner * sth);
  if (gain) out *= gain[h];
  dst[(size_t)tok * (nh * 64) + h * 64 + lane] = __float2bfloat16(out);
}

// ---------------- causal GQA flash attention, bf16 MFMA ----------------
// static-max softmax (|q|=8*gain, |k|=8 after RMS norm -> s <= 8*|gain|),
// deferred per-lane sum, single barrier/tile, async-split K/V staging.
__global__ __launch_bounds__(256) void attn_mfma_kernel(
    const unsigned short* __restrict__ qb, const unsigned short* __restrict__ kb,
    const unsigned short* __restrict__ vt, const float* __restrict__ qgain,
    __hip_bfloat16* __restrict__ ao) {
  __shared__ unsigned short Ks[64][72];
  __shared__ unsigned short Vs[64][72];
  __shared__ unsigned short Psm[4][16][72];
  int blk = blockIdx.x;
  int qi = blk & 15;                 // pair index: qt = qi and 31-qi
  int h  = (blk >> 4) & 15;
  int b  = blk >> 8;
  int hk = h >> 2;
  int tid = threadIdx.x;
  int w = tid >> 6, l = tid & 63;
  int l15 = l & 15, lg = l >> 4;
  int r0 = tid >> 3, s0 = tid & 7;   // staging: rows r0, r0+32; 16B chunk s0
  float mstat = 8.0f * fabsf(qgain[h]);
  const unsigned short* kbase = kb + (size_t)b * L_ * (HKV_ * PA_) + hk * PA_ + s0 * 8;
  const unsigned short* vbase = vt + ((size_t)(b * HKV_ + hk) * PA_) * L_ + s0 * 8;

  for (int pass = 0; pass < 2; pass++) {
    int qt = pass ? (31 - qi) : qi;
    int q0 = qt * 64;
    int qw = q0 + w * 16;
    short8 qf[2];
    {
      size_t qrow = ((size_t)(b * L_ + qw + l15)) * (HA_ * PA_) + h * PA_;
      qf[0] = *(const short8*)&qb[qrow + lg * 8];
      qf[1] = *(const short8*)&qb[qrow + 32 + lg * 8];
    }
    f32x4 o_acc[4];
#pragma unroll
    for (int db = 0; db < 4; db++) o_acc[db] = (f32x4){0.f, 0.f, 0.f, 0.f};
    f32x4 lsum = (f32x4){0.f, 0.f, 0.f, 0.f};
    int nkt = qt + 1;
    // prologue: load tile 0 into registers
    short8 kr0 = *(const short8*)&kbase[(size_t)r0 * (HKV_ * PA_)];
    short8 kr1 = *(const short8*)&kbase[(size_t)(r0 + 32) * (HKV_ * PA_)];
    short8 vr0 = *(const short8*)&vbase[(size_t)r0 * L_];
    short8 vr1 = *(const short8*)&vbase[(size_t)(r0 + 32) * L_];
    for (int kt = 0; kt < nkt; kt++) {
      int k0 = kt * 64;
      __syncthreads();                       // prior tile's LDS reads complete
      *(short8*)&Ks[r0][s0 * 8] = kr0;
      *(short8*)&Ks[r0 + 32][s0 * 8] = kr1;
      *(short8*)&Vs[r0][s0 * 8] = vr0;
      *(short8*)&Vs[r0 + 32][s0 * 8] = vr1;
      if (kt + 1 < nkt) {                    // async prefetch next tile -> regs
        int k1 = k0 + 64;
        kr0 = *(const short8*)&kbase[(size_t)(k1 + r0) * (HKV_ * PA_)];
        kr1 = *(const short8*)&kbase[(size_t)(k1 + r0 + 32) * (HKV_ * PA_)];
        vr0 = *(const short8*)&vbase[(size_t)r0 * L_ + k1];
        vr1 = *(const short8*)&vbase[(size_t)(r0 + 32) * L_ + k1];
      }
      __syncthreads();                       // K/V tile ready
      // QK^T
      f32x4 s_acc[4];
#pragma unroll
      for (int kb2 = 0; kb2 < 4; kb2++) {
        short8 b0 = *(const short8*)&Ks[kb2 * 16 + l15][lg * 8];
        short8 b1 = *(const short8*)&Ks[kb2 * 16 + l15][32 + lg * 8];
        f32x4 s = (f32x4){0.f, 0.f, 0.f, 0.f};
        s = __builtin_amdgcn_mfma_f32_16x16x32_bf16(qf[0], b0, s, 0, 0, 0);
        s = __builtin_amdgcn_mfma_f32_16x16x32_bf16(qf[1], b1, s, 0, 0, 0);
        s_acc[kb2] = s;
      }
      bool diag = (kt == qt);
      // static-max softmax: p = exp(s*0.125 - mstat), no reduce, no rescale
#pragma unroll
      for (int kb2 = 0; kb2 < 4; kb2++) {
        int key = k0 + kb2 * 16 + l15;
#pragma unroll
        for (int reg = 0; reg < 4; reg++) {
          float p = __expf(s_acc[kb2][reg] * 0.125f - mstat);
          if (diag && key > qw + lg * 4 + reg) p = 0.f;
          lsum[reg] += p;
          __hip_bfloat16 hv = __float2bfloat16(p);
          Psm[w][lg * 4 + reg][kb2 * 16 + l15] = *(unsigned short*)&hv;
        }
      }
      asm volatile("s_waitcnt lgkmcnt(0)" ::: "memory");   // Psm write->read, same wave
      // PV
#pragma unroll
      for (int ks = 0; ks < 2; ks++) {
        short8 pa = *(const short8*)&Psm[w][l15][ks * 32 + lg * 8];
#pragma unroll
        for (int db = 0; db < 4; db++) {
          short8 vb8 = *(const short8*)&Vs[db * 16 + l15][ks * 32 + lg * 8];
          o_acc[db] = __builtin_amdgcn_mfma_f32_16x16x32_bf16(pa, vb8, o_acc[db], 0, 0, 0);
        }
      }
    }
    // deferred sum reduce over the 16 lanes of this row group
#pragma unroll
    for (int of = 1; of < 16; of <<= 1) {
      lsum[0] += __shfl_xor(lsum[0], of, 64);
      lsum[1] += __shfl_xor(lsum[1], of, 64);
      lsum[2] += __shfl_xor(lsum[2], of, 64);
      lsum[3] += __shfl_xor(lsum[3], of, 64);
    }
#pragma unroll
    for (int reg = 0; reg < 4; reg++) {
      float invl = 1.0f / lsum[reg];
      size_t row = (size_t)(b * L_ + qw + lg * 4 + reg);
#pragma unroll
      for (int db = 0; db < 4; db++)
        ao[row * D_ + h * PA_ + db * 16 + l15] = __float2bfloat16(o_acc[db][reg] * invl);
    }
  }
}

// ---------------- host ----------------
extern "C" void kernel_launch(void* const* d_in, const int* in_sizes, int n_in,
                              void* d_out, int out_size, void* d_ws, size_t ws_size,
                              hipStream_t stream) {
  (void)in_sizes; (void)n_in; (void)out_size; (void)ws_size;
  const float* x           = (const float*)d_in[0];
  const float* in_proj_w   = (const float*)d_in[1];
  const float* conv_w      = (const float*)d_in[2];
  const float* conv_b      = (const float*)d_in[3];
  const float* B_proj_w    = (const float*)d_in[4];
  const float* C_proj_w    = (const float*)d_in[5];
  const float* dt_bias     = (const float*)d_in[6];
  const float* A_log       = (const float*)d_in[7];
  const float* D_param     = (const float*)d_in[8];
  const float* out_proj_w  = (const float*)d_in[9];
  const float* resid_mix_m = (const float*)d_in[10];
  const float* mamba_scale = (const float*)d_in[11];
  const float* m_fc_w      = (const float*)d_in[12];
  const float* m_proj_w    = (const float*)d_in[13];
  const float* m_mlp_scale = (const float*)d_in[14];
  const float* resid_mix_a = (const float*)d_in[15];
  const float* q_w         = (const float*)d_in[16];
  const float* k_w         = (const float*)d_in[17];
  const float* v_w         = (const float*)d_in[18];
  const float* o_w         = (const float*)d_in[19];
  const float* q_gain      = (const float*)d_in[20];
  const float* attn_scale  = (const float*)d_in[21];
  const float* a_fc_w      = (const float*)d_in[22];
  const float* a_proj_w    = (const float*)d_in[23];
  const float* a_mlp_scale = (const float*)d_in[24];
  float* ws  = (float*)d_ws;
  float* out = (float*)d_out;

  // ---- workspace layout (float units) ----
  float* xm    = ws;                                   // 4,194,304
  float* vgR   = ws + 4194304;                         // 8,388,608 (vg bf16 / qkv f32)
  float* xvR   = ws + 12582912;                        // 8,388,608 (xv f32 / attn bufs)
  float* stR   = ws + 20971520;                        // 8,388,608 (st f32 / hb bf16)
  float* nbR   = ws + 29360128;                        // 2,097,152 (nbb bf16 / ybb lo)
  float* xmbR  = ws + 31457280;                        // 2,097,152 (xmb bf16 / ybb hi)
  float* BCR   = ws + 33554432;                        // 4,194,304 (BC combined bf16)
  float* WtR   = ws + 37748736;                        // 13,893,632
  float* cosb  = ws + 51642368;                        // 65,536
  float* sinb  = cosb + 65536;

  __hip_bfloat16* vg  = (__hip_bfloat16*)vgR;
  float*          qkvf = vgR;
  float*          xv  = xvR;
  float*          st  = stR;
  __hip_bfloat16* hb  = (__hip_bfloat16*)stR;
  __hip_bfloat16* nbb = (__hip_bfloat16*)nbR;
  __hip_bfloat16* xmb = (__hip_bfloat16*)xmbR;
  __hip_bfloat16* ybb = (__hip_bfloat16*)nbR;
  __hip_bfloat16* BCm = (__hip_bfloat16*)BCR;
  __hip_bfloat16* qbb = (__hip_bfloat16*)xvR;
  __hip_bfloat16* kbb = (__hip_bfloat16*)(xvR + 2097152);
  __hip_bfloat16* vtb = (__hip_bfloat16*)(xvR + 2621440);
  __hip_bfloat16* aob = (__hip_bfloat16*)(xvR + 3145728);

  __hip_bfloat16* Wt = (__hip_bfloat16*)WtR;
  size_t o_in  = 0;
  size_t o_B   = o_in  + (size_t)4096 * 1024;
  size_t o_out = o_B   + (size_t)2048 * 1024;
  size_t o_mfc = o_out + (size_t)1024 * 2048;
  size_t o_mpj = o_mfc + (size_t)4096 * 1024;
  size_t o_qkv = o_mpj + (size_t)1024 * 4096;
  size_t o_o   = o_qkv + (size_t)1536 * 1024;
  size_t o_afc = o_o   + (size_t)1024 * 1024;
  size_t o_apj = o_afc + (size_t)4096 * 1024;

#define TCVT(Wp, off, K, N) \
  transpose_cvt<<<dim3((N) / 32, (K) / 32), 256, 0, stream>>>((Wp), Wt + (off), (K), (N), (N))
  TCVT(in_proj_w,  o_in,  1024, 4096);
  TCVT(B_proj_w,   o_B,   1024, 1024);
  TCVT(C_proj_w,   o_B + (size_t)1024 * 1024, 1024, 1024);
  TCVT(out_proj_w, o_out, 2048, 1024);
  TCVT(m_fc_w,     o_mfc, 1024, 4096);
  TCVT(m_proj_w,   o_mpj, 4096, 1024);
  TCVT(q_w,        o_qkv, 1024, 1024);
  TCVT(k_w,        o_qkv + (size_t)1024 * 1024, 1024, 256);
  TCVT(v_w,        o_qkv + (size_t)1280 * 1024, 1024, 256);
  TCVT(o_w,        o_o,   1024, 1024);
  TCVT(a_fc_w,     o_afc, 1024, 4096);
  TCVT(a_proj_w,   o_apj, 4096, 1024);
#undef TCVT

#define GEMM(BN, Abuf, Woff, Cfp, Cbp, basep, scalep, N, K, mode) \
  gemm_bf16_t<BN><<<dim3((N) / (BN), NT_ / 128), 256, 0, stream>>>( \
      (const unsigned short*)(Abuf), (const unsigned short*)(Wt + (Woff)), \
      (Cfp), (Cbp), (basep), (scalep), (N), (K), (mode))

  // --- mamba branch ---
  mix_rms_kernel<<<NT_, 256, 0, stream>>>(x, x, resid_mix_m, xm, nbb, xmb);
  GEMM(128, nbb, o_in, (float*)0, vg, (const float*)0, (const float*)0, 4096, 1024, 2);
  GEMM(128, xmb, o_B, (float*)0, BCm, (const float*)0, (const float*)0, 2048, 1024, 2);
  conv_silu_kernel<<<NT_ * DI_ / 256, 256, 0, stream>>>(vg, conv_w, conv_b, xv);
  scanA1_kernel<<<B_ * HS_ * NC_, 256, 0, stream>>>(xv, BCm, dt_bias, A_log, st);
  scanA2_kernel<<<B_ * HS_ * NC_, 256, 0, stream>>>(xv, BCm, dt_bias, A_log, D_param, xv);
  scanB1_kernel<<<B_ * HS_ * 4, 256, 0, stream>>>(st, dt_bias, A_log);
  scanB2_kernel<<<B_ * HS_ * NC_, 256, 0, stream>>>(BCm, st, vg, dt_bias, A_log, xv, ybb);
  GEMM(64, ybb, o_out, xm, (__hip_bfloat16*)0, xm, mamba_scale, 1024, 2048, 3);
  // --- mamba MLP ---
  rms_kernel<<<NT_, 256, 0, stream>>>(xm, nbb);
  GEMM(128, nbb, o_mfc, (float*)0, hb, (const float*)0, (const float*)0, 4096, 1024, 1);
  GEMM(64, hb, o_mpj, xm, (__hip_bfloat16*)0, xm, m_mlp_scale, 1024, 4096, 3);
  // --- attention branch ---
  mix_rms_kernel<<<NT_, 256, 0, stream>>>(xm, x, resid_mix_a, xm, nbb, (__hip_bfloat16*)0);
  GEMM(64, nbb, o_qkv, qkvf, (__hip_bfloat16*)0, (const float*)0, (const float*)0, 1536, 1024, 0);
  rope_fill_kernel<<<L_ * 32 / 256, 256, 0, stream>>>(cosb, sinb);
  qknorm_rope_bf16_kernel<<<NT_ * HA_ / 4, 256, 0, stream>>>(qkvf, 1536, 0, qbb, HA_, cosb, sinb, q_gain);
  qknorm_rope_bf16_kernel<<<NT_ * HKV_ / 4, 256, 0, stream>>>(qkvf, 1536, 1024, kbb, HKV_, cosb, sinb, (const float*)0);
  transpose_cvt<<<dim3(256 / 32, 2048 / 32), 256, 0, stream>>>(qkvf + 1280, vtb, 2048, 256, 1536);
  transpose_cvt<<<dim3(256 / 32, 2048 / 32), 256, 0, stream>>>(qkvf + (size_t)L_ * 1536 + 1280, vtb + (size_t)256 * L_, 2048, 256, 1536);
  attn_mfma_kernel<<<B_ * HA_ * 16, 256, 0, stream>>>(
      (const unsigned short*)qbb, (const unsigned short*)kbb, (const unsigned short*)vtb,
      q_gain, aob);
  GEMM(64, aob, o_o, xm, (__hip_bfloat16*)0, xm, attn_scale, 1024, 1024, 3);
  // --- attention MLP ---
  rms_kernel<<<NT_, 256, 0, stream>>>(xm, nbb);
  GEMM(128, nbb, o_afc, (float*)0, hb, (const float*)0, (const float*)0, 4096, 1024, 1);
  GEMM(64, hb, o_apj, out, (__hip_bfloat16*)0, xm, a_mlp_scale, 1024, 4096, 3);
#undef GEMM
}

// Round 8
// 708.749 us; speedup vs baseline: 6.6652x; 1.0036x over previous
//
#include <hip/hip_runtime.h>
#include <hip/hip_bf16.h>
#include <math.h>

#define D_ 1024
#define DI_ 2048
#define HS_ 16
#define PS_ 128
#define NS_ 64
#define HA_ 16
#define HKV_ 4
#define PA_ 64
#define B_ 2
#define L_ 2048
#define NT_ 4096          // B_*L_
#define NC_ 32            // L_/64
#define RMS_EPS_ 1.1920929e-7f

typedef __attribute__((ext_vector_type(8))) short short8;
typedef __attribute__((ext_vector_type(4))) float f32x4;

#define GLOAD_LDS16(gp, lp)                                                        \
  __builtin_amdgcn_global_load_lds(                                               \
      (const __attribute__((address_space(1))) unsigned int*)(gp),                \
      (__attribute__((address_space(3))) unsigned int*)(lp), 16, 0, 0)

// ---------------- transpose + fp32->bf16: W[K rows x N cols, row-stride ldw] -> Wt[N][K] ----------------
__global__ __launch_bounds__(256) void transpose_cvt(
    const float* __restrict__ W, __hip_bfloat16* __restrict__ Wt, int K, int N, int ldw) {
  __shared__ float t[32][33];
  int n0 = blockIdx.x * 32, k0 = blockIdx.y * 32;
  int tx = threadIdx.x & 31, ty = threadIdx.x >> 5;
#pragma unroll
  for (int i = 0; i < 4; i++)
    t[ty + i * 8][tx] = W[(size_t)(k0 + ty + i * 8) * ldw + n0 + tx];
  __syncthreads();
#pragma unroll
  for (int i = 0; i < 4; i++)
    Wt[(size_t)(n0 + ty + i * 8) * K + k0 + tx] = __float2bfloat16(t[tx][ty + i * 8]);
}

// ---------------- bf16 MFMA GEMM, double-buffered, tile 128 x BN ----------------
// Grid: 1D, gm=32 fixed rows (M=4096), gn = N/BN cols (must be %4==0).
// XCD-rect swizzle: each XCD owns one contiguous 16 x (gn/4) tile rectangle.
// mode 0: f32 out; 1: relu^2 -> bf16; 2: bf16; 3: f32 out = base + scale[col]*acc
template<int BN>
__global__ __launch_bounds__(256) void gemm_bf16_t(
    const unsigned short* __restrict__ A, const unsigned short* __restrict__ Wt,
    float* __restrict__ Cf, __hip_bfloat16* __restrict__ Cb,
    const float* __restrict__ baseb, const float* __restrict__ scale,
    int N, int K, int gn, int mode) {
  constexpr int nWc = BN / 64;
  constexpr int nWr = 4 / nWc;
  constexpr int MF  = 8 / nWr;
  __shared__ unsigned short As[2][128 * 64];
  __shared__ unsigned short Bs[2][BN * 64];
  // --- XCD-rectangle block swizzle (gm=32 x gn tiles; 8 rects of 16 x gn/4) ---
  int lid = blockIdx.x;
  int x = lid & 7, r = lid >> 3;       // XCD slot, rank within XCD
  int RN = gn >> 2;
  int bm = ((x >> 2) * 16 + (r & 15)) * 128;
  int bn = ((x & 3) * RN + (r >> 4)) * BN;
  int tid = threadIdx.x;
  int w = tid >> 6, l = tid & 63;
  int wr = w / nWc, wc = w % nWc;
  int l15 = l & 15, lg = l >> 4;
  f32x4 acc[MF][4];
#pragma unroll
  for (int i = 0; i < MF; i++)
#pragma unroll
    for (int j = 0; j < 4; j++) acc[i][j] = (f32x4){0.f, 0.f, 0.f, 0.f};
  int r_ = tid >> 3;
  int s_ = tid & 7;

  auto STAGE = [&](int k0, int nb) {
#pragma unroll
    for (int i = 0; i < 4; i++) {
      int rr = i * 32 + r_;
      int kq = s_ ^ (rr & 7);
      GLOAD_LDS16(A + (size_t)(bm + rr) * K + k0 + kq * 8, &As[nb][rr * 64 + s_ * 8]);
    }
#pragma unroll
    for (int i = 0; i < BN / 32; i++) {
      int rr = i * 32 + r_;
      int kq = s_ ^ (rr & 7);
      GLOAD_LDS16(Wt + (size_t)(bn + rr) * K + k0 + kq * 8, &Bs[nb][rr * 64 + s_ * 8]);
    }
  };

  STAGE(0, 0);
  __syncthreads();
  int cur = 0;
  for (int k0 = 0; k0 < K; k0 += 64) {
    if (k0 + 64 < K) STAGE(k0 + 64, cur ^ 1);
#pragma unroll
    for (int h = 0; h < 2; h++) {
      short8 af[MF], bfr[4];
#pragma unroll
      for (int i = 0; i < MF; i++) {
        int row = wr * (16 * MF) + i * 16 + l15;
        int c = h * 4 + lg;
        af[i] = *(const short8*)&As[cur][row * 64 + ((c ^ (row & 7)) << 3)];
      }
#pragma unroll
      for (int j = 0; j < 4; j++) {
        int row = wc * 64 + j * 16 + l15;
        int c = h * 4 + lg;
        bfr[j] = *(const short8*)&Bs[cur][row * 64 + ((c ^ (row & 7)) << 3)];
      }
#pragma unroll
      for (int i = 0; i < MF; i++)
#pragma unroll
        for (int j = 0; j < 4; j++)
          acc[i][j] = __builtin_amdgcn_mfma_f32_16x16x32_bf16(af[i], bfr[j], acc[i][j], 0, 0, 0);
    }
    __syncthreads();
    cur ^= 1;
  }
  int rb = lg * 4, cb2 = l15;
#pragma unroll
  for (int i = 0; i < MF; i++)
#pragma unroll
    for (int j = 0; j < 4; j++) {
      int gr = bm + wr * (16 * MF) + i * 16 + rb;
      int gc = bn + wc * 64 + j * 16 + cb2;
#pragma unroll
      for (int reg = 0; reg < 4; reg++) {
        float v = acc[i][j][reg];
        size_t idx = (size_t)(gr + reg) * N + gc;
        if (mode == 0) {
          Cf[idx] = v;
        } else if (mode == 1) {
          v = fmaxf(v, 0.f);
          Cb[idx] = __float2bfloat16(v * v);
        } else if (mode == 2) {
          Cb[idx] = __float2bfloat16(v);
        } else {
          Cf[idx] = baseb[idx] + scale[gc] * v;
        }
      }
    }
}

// ---------------- mix + rmsnorm ----------------
__global__ __launch_bounds__(256) void mix_rms_kernel(
    const float* __restrict__ a, const float* __restrict__ b2,
    const float* __restrict__ mix, float* __restrict__ xout,
    __hip_bfloat16* __restrict__ nbf, __hip_bfloat16* __restrict__ rawbf) {
  int row = blockIdx.x;
  size_t base = (size_t)row * D_;
  float v[4]; float ss = 0.f;
#pragma unroll
  for (int i = 0; i < 4; i++) {
    int d = threadIdx.x + i * 256;
    float val = mix[d] * a[base + d] + mix[D_ + d] * b2[base + d];
    v[i] = val; ss += val * val;
  }
  for (int o = 32; o > 0; o >>= 1) ss += __shfl_down(ss, o, 64);
  __shared__ float red[4];
  if ((threadIdx.x & 63) == 0) red[threadIdx.x >> 6] = ss;
  __syncthreads();
  float inv = rsqrtf((red[0] + red[1] + red[2] + red[3]) * (1.f / D_) + RMS_EPS_);
#pragma unroll
  for (int i = 0; i < 4; i++) {
    int d = threadIdx.x + i * 256;
    xout[base + d] = v[i];
    nbf[base + d] = __float2bfloat16(v[i] * inv);
    if (rawbf) rawbf[base + d] = __float2bfloat16(v[i]);
  }
}

__global__ __launch_bounds__(256) void rms_kernel(
    const float* __restrict__ a, __hip_bfloat16* __restrict__ nbf) {
  int row = blockIdx.x;
  size_t base = (size_t)row * D_;
  float v[4]; float ss = 0.f;
#pragma unroll
  for (int i = 0; i < 4; i++) {
    int d = threadIdx.x + i * 256;
    float val = a[base + d];
    v[i] = val; ss += val * val;
  }
  for (int o = 32; o > 0; o >>= 1) ss += __shfl_down(ss, o, 64);
  __shared__ float red[4];
  if ((threadIdx.x & 63) == 0) red[threadIdx.x >> 6] = ss;
  __syncthreads();
  float inv = rsqrtf((red[0] + red[1] + red[2] + red[3]) * (1.f / D_) + RMS_EPS_);
#pragma unroll
  for (int i = 0; i < 4; i++) {
    int d = threadIdx.x + i * 256;
    nbf[base + d] = __float2bfloat16(v[i] * inv);
  }
}

// ---------------- depthwise causal conv (KC=4) + SiLU; vg bf16 [NT][4096] cols 0..2047 ----------------
__global__ __launch_bounds__(256) void conv_silu_kernel(
    const __hip_bfloat16* __restrict__ vg, const float* __restrict__ cw,
    const float* __restrict__ cb, float* __restrict__ xv) {
  int idx = blockIdx.x * 256 + threadIdx.x;
  int c = idx & (DI_ - 1);
  int bl = idx >> 11;
  int l = bl & (L_ - 1);
  float acc = cb[c];
  float w0 = cw[c * 4 + 0], w1 = cw[c * 4 + 1], w2 = cw[c * 4 + 2], w3 = cw[c * 4 + 3];
  size_t rb = (size_t)bl * 4096 + c;
  if (l >= 3) acc += __bfloat162float(vg[rb - (size_t)3 * 4096]) * w0;
  if (l >= 2) acc += __bfloat162float(vg[rb - (size_t)2 * 4096]) * w1;
  if (l >= 1) acc += __bfloat162float(vg[rb - (size_t)1 * 4096]) * w2;
  acc += __bfloat162float(vg[rb]) * w3;
  xv[idx] = acc / (1.f + __expf(-acc));
}

// ---------------- scan pass A1; BC combined [NT][2048]: B at +0 ----------------
__global__ __launch_bounds__(256) void scanA1_kernel(
    const float* __restrict__ xv, const __hip_bfloat16* __restrict__ BCm,
    const float* __restrict__ dt_bias, const float* __restrict__ A_log,
    float* __restrict__ st) {
  __shared__ __align__(16) float sm[4096 + 8192];
  float* Bs = sm;
  float* Xs = sm + 4096;
  int blk = blockIdx.x;
  int c = blk & 31, h = (blk >> 5) & 15, b = blk >> 9;
  float dt = log1pf(__expf(dt_bias[h]));
  float adt = -__expf(A_log[h]) * dt;
  int tid = threadIdx.x;
  int l0 = c * 64;
  size_t rB = ((size_t)(b * L_ + l0)) * 2048 + h * NS_;
#pragma unroll
  for (int i = 0; i < 16; i++) {
    int e = tid + i * 256;
    int t = e >> 6, n = e & 63;
    Bs[t * 64 + n] = __bfloat162float(BCm[rB + (size_t)t * 2048 + n]);
  }
  size_t rX = ((size_t)(b * L_ + l0)) * DI_ + h * PS_;
#pragma unroll
  for (int i = 0; i < 32; i++) {
    int e = tid + i * 256;
    int t = e >> 7, p = e & 127;
    Xs[t * 128 + p] = xv[rX + (size_t)t * DI_ + p];
  }
  __syncthreads();
  int pg = tid & 31;
  int ng = (tid >> 5) << 3;
  float acc[8][4];
#pragma unroll
  for (int nn = 0; nn < 8; nn++)
#pragma unroll
    for (int i = 0; i < 4; i++) acc[nn][i] = 0.f;
  for (int t = 0; t < 64; t++) {
    float dr = __expf(adt * (float)(63 - t));
    float4 x4 = *(const float4*)&Xs[t * 128 + pg * 4];
    float xd0 = x4.x * dr, xd1 = x4.y * dr, xd2 = x4.z * dr, xd3 = x4.w * dr;
#pragma unroll
    for (int nn = 0; nn < 8; nn++) {
      float bv = Bs[t * 64 + ng + nn];
      acc[nn][0] += bv * xd0; acc[nn][1] += bv * xd1;
      acc[nn][2] += bv * xd2; acc[nn][3] += bv * xd3;
    }
  }
  size_t sb = ((size_t)((b * HS_ + h) * NC_ + c)) * (NS_ * PS_);
#pragma unroll
  for (int nn = 0; nn < 8; nn++) {
    *(float4*)&st[sb + (size_t)(ng + nn) * PS_ + pg * 4] =
        make_float4(acc[nn][0] * dt, acc[nn][1] * dt, acc[nn][2] * dt, acc[nn][3] * dt);
  }
}

// ---------------- scan pass A2; BC combined: B at +0, C at +1024 ----------------
__global__ __launch_bounds__(256) void scanA2_kernel(
    const float* __restrict__ xv, const __hip_bfloat16* __restrict__ BCm,
    const float* __restrict__ dt_bias,
    const float* __restrict__ A_log, const float* __restrict__ D_param,
    float* __restrict__ y) {
  __shared__ __align__(16) float sm[4160 + 8192];
  float* Cb = sm;
  float* Bs = sm + 4160;
  float* Xs = sm + 4160;
  int blk = blockIdx.x;
  int c = blk & 31, h = (blk >> 5) & 15, b = blk >> 9;
  float dt = log1pf(__expf(dt_bias[h]));
  float adt = -__expf(A_log[h]) * dt;
  float Dp = D_param[h];
  int tid = threadIdx.x;
  int l0 = c * 64;
  size_t rB = ((size_t)(b * L_ + l0)) * 2048 + h * NS_;
#pragma unroll
  for (int i = 0; i < 16; i++) {
    int e = tid + i * 256;
    int t = e >> 6, n = e & 63;
    Bs[t * 64 + n] = __bfloat162float(BCm[rB + (size_t)t * 2048 + n]);
    Cb[t * 65 + n] = __bfloat162float(BCm[rB + 1024 + (size_t)t * 2048 + n]);
  }
  __syncthreads();
  int q = tid >> 2;
  int kb = (tid & 3) << 4;
  float cbl[16];
#pragma unroll
  for (int kk = 0; kk < 16; kk++) {
    int k = kb + kk;
    float a = 0.f;
    if (k <= q) {
      for (int n = 0; n < 64; n++) a += Cb[q * 65 + n] * Bs[k * 64 + n];
      a *= __expf(adt * (float)(q - k));
    }
    cbl[kk] = a;
  }
  __syncthreads();
#pragma unroll
  for (int kk = 0; kk < 16; kk++) Cb[q * 65 + kb + kk] = cbl[kk];
  size_t rX = ((size_t)(b * L_ + l0)) * DI_ + h * PS_;
#pragma unroll
  for (int i = 0; i < 32; i++) {
    int e = tid + i * 256;
    int t = e >> 7, p = e & 127;
    Xs[t * 128 + p] = xv[rX + (size_t)t * DI_ + p];
  }
  __syncthreads();
  int pg = tid & 31;
  int qg = (tid >> 5) << 3;
  float acc[8][4];
#pragma unroll
  for (int qq = 0; qq < 8; qq++)
#pragma unroll
    for (int i = 0; i < 4; i++) acc[qq][i] = 0.f;
  for (int k = 0; k < 64; k++) {
    float4 x4 = *(const float4*)&Xs[k * 128 + pg * 4];
#pragma unroll
    for (int qq = 0; qq < 8; qq++) {
      float s = Cb[(qg + qq) * 65 + k];
      acc[qq][0] += s * x4.x; acc[qq][1] += s * x4.y;
      acc[qq][2] += s * x4.z; acc[qq][3] += s * x4.w;
    }
  }
#pragma unroll
  for (int qq = 0; qq < 8; qq++) {
    int qr = qg + qq;
    float4 xq = *(const float4*)&Xs[qr * 128 + pg * 4];
    size_t yo = ((size_t)(b * L_ + l0 + qr)) * DI_ + h * PS_ + pg * 4;
    *(float4*)&y[yo] = make_float4(acc[qq][0] * dt + Dp * xq.x,
                                   acc[qq][1] * dt + Dp * xq.y,
                                   acc[qq][2] * dt + Dp * xq.z,
                                   acc[qq][3] * dt + Dp * xq.w);
  }
}

// ---------------- scan pass B1: inter-chunk recurrence, 128 blocks ----------------
__global__ __launch_bounds__(256) void scanB1_kernel(
    float* __restrict__ st, const float* __restrict__ dt_bias,
    const float* __restrict__ A_log) {
  int slice = blockIdx.x & 3;
  int h = (blockIdx.x >> 2) & 15, b = blockIdx.x >> 6;
  float dt = log1pf(__expf(dt_bias[h]));
  float adt = -__expf(A_log[h]) * dt;
  float cdec = __expf(adt * 64.f);
  size_t base = ((size_t)(b * HS_ + h)) * NC_ * (NS_ * PS_) + slice * 2048 + threadIdx.x;
  float hreg[8];
#pragma unroll
  for (int j = 0; j < 8; j++) hreg[j] = 0.f;
  for (int c = 0; c < NC_; c++) {
    size_t o = base + (size_t)c * (NS_ * PS_);
#pragma unroll
    for (int j = 0; j < 8; j++) {
      float tmp = st[o + (size_t)j * 256];
      st[o + (size_t)j * 256] = hreg[j];
      hreg[j] = cdec * hreg[j] + tmp;
    }
  }
}

// ---------------- scan pass B2: y_off + gate SiLU -> bf16; C at +1024 ----------------
__global__ __launch_bounds__(256) void scanB2_kernel(
    const __hip_bfloat16* __restrict__ BCm, const float* __restrict__ st,
    const __hip_bfloat16* __restrict__ vg, const float* __restrict__ dt_bias,
    const float* __restrict__ A_log, const float* __restrict__ y,
    __hip_bfloat16* __restrict__ yout) {
  __shared__ float Cs[64 * 64];
  __shared__ __align__(16) float Hs[64 * 128];
  int blk = blockIdx.x;
  int c = blk & 31, h = (blk >> 5) & 15, b = blk >> 9;
  float dt = log1pf(__expf(dt_bias[h]));
  float adt = -__expf(A_log[h]) * dt;
  int tid = threadIdx.x;
  int l0 = c * 64;
  size_t rC = ((size_t)(b * L_ + l0)) * 2048 + 1024 + h * NS_;
#pragma unroll
  for (int i = 0; i < 16; i++) {
    int e = tid + i * 256;
    int t = e >> 6, n = e & 63;
    Cs[t * 64 + n] = __bfloat162float(BCm[rC + (size_t)t * 2048 + n]);
  }
  size_t sb = ((size_t)((b * HS_ + h) * NC_ + c)) * (NS_ * PS_);
#pragma unroll
  for (int i = 0; i < 32; i++) {
    int e = tid + i * 256;
    Hs[e] = st[sb + e];
  }
  __syncthreads();
  int pg = tid & 31;
  int tg = (tid >> 5) << 3;
  float acc[8][4];
#pragma unroll
  for (int tt = 0; tt < 8; tt++)
#pragma unroll
    for (int i = 0; i < 4; i++) acc[tt][i] = 0.f;
  for (int n = 0; n < 64; n++) {
    float4 h4 = *(const float4*)&Hs[n * 128 + pg * 4];
#pragma unroll
    for (int tt = 0; tt < 8; tt++) {
      float cv = Cs[(tg + tt) * 64 + n];
      acc[tt][0] += cv * h4.x; acc[tt][1] += cv * h4.y;
      acc[tt][2] += cv * h4.z; acc[tt][3] += cv * h4.w;
    }
  }
#pragma unroll
  for (int tt = 0; tt < 8; tt++) {
    int t = tg + tt;
    float dout = __expf(adt * (float)(t + 1));
    size_t row = (size_t)(b * L_ + l0 + t);
#pragma unroll
    for (int i = 0; i < 4; i++) {
      int p = pg * 4 + i;
      float g = __bfloat162float(vg[row * 4096 + 2048 + h * PS_ + p]);
      float yv = y[row * DI_ + h * PS_ + p] + acc[tt][i] * dout;
      yout[row * DI_ + h * PS_ + p] = __float2bfloat16(yv * (g / (1.f + __expf(-g))));
    }
  }
}

// ---------------- rope tables ----------------
__global__ void rope_fill_kernel(float* __restrict__ cosb, float* __restrict__ sinb) {
  int idx = blockIdx.x * 256 + threadIdx.x;
  int i = idx & 31, l = idx >> 5;
  float inv = __expf(-(2.0f * (float)i / (float)PA_) * logf(10000.0f));
  float ang = (float)l * inv;
  cosb[idx] = cosf(ang);
  sinb[idx] = sinf(ang);
}

// ---------------- per-head rmsnorm + rope (+gain), strided src -> packed bf16 dst ----------------
__global__ __launch_bounds__(256) void qknorm_rope_bf16_kernel(
    const float* __restrict__ src, int srcstride, int srcofs,
    __hip_bfloat16* __restrict__ dst, int nh,
    const float* __restrict__ cosb, const float* __restrict__ sinb,
    const float* __restrict__ gain) {
  int row = blockIdx.x * 4 + (threadIdx.x >> 6);
  int lane = threadIdx.x & 63;
  int h = row % nh;
  int tok = row / nh;
  int l = tok & (L_ - 1);
  float v = src[(size_t)tok * srcstride + srcofs + h * 64 + lane];
  float ss = v * v;
  for (int o = 32; o > 0; o >>= 1) ss += __shfl_xor(ss, o, 64);
  v *= rsqrtf(ss * (1.f / PA_) + RMS_EPS_);
  float partner = __shfl_xor(v, 32, 64);
  int i = lane & 31;
  float cth = cosb[l * 32 + i], sth = sinb[l * 32 + i];
  float out = (lane < 32) ? (v * cth + partner * sth) : (v * cth - partner * sth);
  if (gain) out *= gain[h];
  dst[(size_t)tok * (nh * 64) + h * 64 + lane] = __float2bfloat16(out);
}

// ---------------- causal GQA flash attention, bf16 MFMA ----------------
__global__ __launch_bounds__(256) void attn_mfma_kernel(
    const unsigned short* __restrict__ qb, const unsigned short* __restrict__ kb,
    const unsigned short* __restrict__ vt, const float* __restrict__ qgain,
    __hip_bfloat16* __restrict__ ao) {
  __shared__ unsigned short Ks[64][72];
  __shared__ unsigned short Vs[64][72];
  __shared__ unsigned short Psm[4][16][72];
  int blk = blockIdx.x;
  int qi = blk & 15;
  int h  = (blk >> 4) & 15;
  int b  = blk >> 8;
  int hk = h >> 2;
  int tid = threadIdx.x;
  int w = tid >> 6, l = tid & 63;
  int l15 = l & 15, lg = l >> 4;
  int r0 = tid >> 3, s0 = tid & 7;
  float mstat = 8.0f * fabsf(qgain[h]);
  const unsigned short* kbase = kb + (size_t)b * L_ * (HKV_ * PA_) + hk * PA_ + s0 * 8;
  const unsigned short* vbase = vt + ((size_t)(b * HKV_ + hk) * PA_) * L_ + s0 * 8;

  for (int pass = 0; pass < 2; pass++) {
    int qt = pass ? (31 - qi) : qi;
    int q0 = qt * 64;
    int qw = q0 + w * 16;
    short8 qf[2];
    {
      size_t qrow = ((size_t)(b * L_ + qw + l15)) * (HA_ * PA_) + h * PA_;
      qf[0] = *(const short8*)&qb[qrow + lg * 8];
      qf[1] = *(const short8*)&qb[qrow + 32 + lg * 8];
    }
    f32x4 o_acc[4];
#pragma unroll
    for (int db = 0; db < 4; db++) o_acc[db] = (f32x4){0.f, 0.f, 0.f, 0.f};
    f32x4 lsum = (f32x4){0.f, 0.f, 0.f, 0.f};
    int nkt = qt + 1;
    short8 kr0 = *(const short8*)&kbase[(size_t)r0 * (HKV_ * PA_)];
    short8 kr1 = *(const short8*)&kbase[(size_t)(r0 + 32) * (HKV_ * PA_)];
    short8 vr0 = *(const short8*)&vbase[(size_t)r0 * L_];
    short8 vr1 = *(const short8*)&vbase[(size_t)(r0 + 32) * L_];
    for (int kt = 0; kt < nkt; kt++) {
      int k0 = kt * 64;
      __syncthreads();
      *(short8*)&Ks[r0][s0 * 8] = kr0;
      *(short8*)&Ks[r0 + 32][s0 * 8] = kr1;
      *(short8*)&Vs[r0][s0 * 8] = vr0;
      *(short8*)&Vs[r0 + 32][s0 * 8] = vr1;
      if (kt + 1 < nkt) {
        int k1 = k0 + 64;
        kr0 = *(const short8*)&kbase[(size_t)(k1 + r0) * (HKV_ * PA_)];
        kr1 = *(const short8*)&kbase[(size_t)(k1 + r0 + 32) * (HKV_ * PA_)];
        vr0 = *(const short8*)&vbase[(size_t)r0 * L_ + k1];
        vr1 = *(const short8*)&vbase[(size_t)(r0 + 32) * L_ + k1];
      }
      __syncthreads();
      f32x4 s_acc[4];
#pragma unroll
      for (int kb2 = 0; kb2 < 4; kb2++) {
        short8 b0 = *(const short8*)&Ks[kb2 * 16 + l15][lg * 8];
        short8 b1 = *(const short8*)&Ks[kb2 * 16 + l15][32 + lg * 8];
        f32x4 s = (f32x4){0.f, 0.f, 0.f, 0.f};
        s = __builtin_amdgcn_mfma_f32_16x16x32_bf16(qf[0], b0, s, 0, 0, 0);
        s = __builtin_amdgcn_mfma_f32_16x16x32_bf16(qf[1], b1, s, 0, 0, 0);
        s_acc[kb2] = s;
      }
      bool diag = (kt == qt);
#pragma unroll
      for (int kb2 = 0; kb2 < 4; kb2++) {
        int key = k0 + kb2 * 16 + l15;
#pragma unroll
        for (int reg = 0; reg < 4; reg++) {
          float p = __expf(s_acc[kb2][reg] * 0.125f - mstat);
          if (diag && key > qw + lg * 4 + reg) p = 0.f;
          lsum[reg] += p;
          __hip_bfloat16 hv = __float2bfloat16(p);
          Psm[w][lg * 4 + reg][kb2 * 16 + l15] = *(unsigned short*)&hv;
        }
      }
      asm volatile("s_waitcnt lgkmcnt(0)" ::: "memory");
#pragma unroll
      for (int ks = 0; ks < 2; ks++) {
        short8 pa = *(const short8*)&Psm[w][l15][ks * 32 + lg * 8];
#pragma unroll
        for (int db = 0; db < 4; db++) {
          short8 vb8 = *(const short8*)&Vs[db * 16 + l15][ks * 32 + lg * 8];
          o_acc[db] = __builtin_amdgcn_mfma_f32_16x16x32_bf16(pa, vb8, o_acc[db], 0, 0, 0);
        }
      }
    }
#pragma unroll
    for (int of = 1; of < 16; of <<= 1) {
      lsum[0] += __shfl_xor(lsum[0], of, 64);
      lsum[1] += __shfl_xor(lsum[1], of, 64);
      lsum[2] += __shfl_xor(lsum[2], of, 64);
      lsum[3] += __shfl_xor(lsum[3], of, 64);
    }
#pragma unroll
    for (int reg = 0; reg < 4; reg++) {
      float invl = 1.0f / lsum[reg];
      size_t row = (size_t)(b * L_ + qw + lg * 4 + reg);
#pragma unroll
      for (int db = 0; db < 4; db++)
        ao[row * D_ + h * PA_ + db * 16 + l15] = __float2bfloat16(o_acc[db][reg] * invl);
    }
  }
}

// ---------------- host ----------------
extern "C" void kernel_launch(void* const* d_in, const int* in_sizes, int n_in,
                              void* d_out, int out_size, void* d_ws, size_t ws_size,
                              hipStream_t stream) {
  (void)in_sizes; (void)n_in; (void)out_size; (void)ws_size;
  const float* x           = (const float*)d_in[0];
  const float* in_proj_w   = (const float*)d_in[1];
  const float* conv_w      = (const float*)d_in[2];
  const float* conv_b      = (const float*)d_in[3];
  const float* B_proj_w    = (const float*)d_in[4];
  const float* C_proj_w    = (const float*)d_in[5];
  const float* dt_bias     = (const float*)d_in[6];
  const float* A_log       = (const float*)d_in[7];
  const float* D_param     = (const float*)d_in[8];
  const float* out_proj_w  = (const float*)d_in[9];
  const float* resid_mix_m = (const float*)d_in[10];
  const float* mamba_scale = (const float*)d_in[11];
  const float* m_fc_w      = (const float*)d_in[12];
  const float* m_proj_w    = (const float*)d_in[13];
  const float* m_mlp_scale = (const float*)d_in[14];
  const float* resid_mix_a = (const float*)d_in[15];
  const float* q_w         = (const float*)d_in[16];
  const float* k_w         = (const float*)d_in[17];
  const float* v_w         = (const float*)d_in[18];
  const float* o_w         = (const float*)d_in[19];
  const float* q_gain      = (const float*)d_in[20];
  const float* attn_scale  = (const float*)d_in[21];
  const float* a_fc_w      = (const float*)d_in[22];
  const float* a_proj_w    = (const float*)d_in[23];
  const float* a_mlp_scale = (const float*)d_in[24];
  float* ws  = (float*)d_ws;
  float* out = (float*)d_out;

  // ---- workspace layout (float units) ----
  float* xm    = ws;
  float* vgR   = ws + 4194304;
  float* xvR   = ws + 12582912;
  float* stR   = ws + 20971520;
  float* nbR   = ws + 29360128;
  float* xmbR  = ws + 31457280;
  float* BCR   = ws + 33554432;
  float* WtR   = ws + 37748736;
  float* cosb  = ws + 51642368;
  float* sinb  = cosb + 65536;

  __hip_bfloat16* vg  = (__hip_bfloat16*)vgR;
  float*          qkvf = vgR;
  float*          xv  = xvR;
  float*          st  = stR;
  __hip_bfloat16* hb  = (__hip_bfloat16*)stR;
  __hip_bfloat16* nbb = (__hip_bfloat16*)nbR;
  __hip_bfloat16* xmb = (__hip_bfloat16*)xmbR;
  __hip_bfloat16* ybb = (__hip_bfloat16*)nbR;
  __hip_bfloat16* BCm = (__hip_bfloat16*)BCR;
  __hip_bfloat16* qbb = (__hip_bfloat16*)xvR;
  __hip_bfloat16* kbb = (__hip_bfloat16*)(xvR + 2097152);
  __hip_bfloat16* vtb = (__hip_bfloat16*)(xvR + 2621440);
  __hip_bfloat16* aob = (__hip_bfloat16*)(xvR + 3145728);

  __hip_bfloat16* Wt = (__hip_bfloat16*)WtR;
  size_t o_in  = 0;
  size_t o_B   = o_in  + (size_t)4096 * 1024;
  size_t o_out = o_B   + (size_t)2048 * 1024;
  size_t o_mfc = o_out + (size_t)1024 * 2048;
  size_t o_mpj = o_mfc + (size_t)4096 * 1024;
  size_t o_qkv = o_mpj + (size_t)1024 * 4096;
  size_t o_o   = o_qkv + (size_t)1536 * 1024;
  size_t o_afc = o_o   + (size_t)1024 * 1024;
  size_t o_apj = o_afc + (size_t)4096 * 1024;

#define TCVT(Wp, off, K, N) \
  transpose_cvt<<<dim3((N) / 32, (K) / 32), 256, 0, stream>>>((Wp), Wt + (off), (K), (N), (N))
  TCVT(in_proj_w,  o_in,  1024, 4096);
  TCVT(B_proj_w,   o_B,   1024, 1024);
  TCVT(C_proj_w,   o_B + (size_t)1024 * 1024, 1024, 1024);
  TCVT(out_proj_w, o_out, 2048, 1024);
  TCVT(m_fc_w,     o_mfc, 1024, 4096);
  TCVT(m_proj_w,   o_mpj, 4096, 1024);
  TCVT(q_w,        o_qkv, 1024, 1024);
  TCVT(k_w,        o_qkv + (size_t)1024 * 1024, 1024, 256);
  TCVT(v_w,        o_qkv + (size_t)1280 * 1024, 1024, 256);
  TCVT(o_w,        o_o,   1024, 1024);
  TCVT(a_fc_w,     o_afc, 1024, 4096);
  TCVT(a_proj_w,   o_apj, 4096, 1024);
#undef TCVT

  // 1D grid = gm(32) * gn; swizzle decodes (bm,bn) in-kernel
#define GEMM(BN, Abuf, Woff, Cfp, Cbp, basep, scalep, N, K, mode) \
  gemm_bf16_t<BN><<<32 * ((N) / (BN)), 256, 0, stream>>>( \
      (const unsigned short*)(Abuf), (const unsigned short*)(Wt + (Woff)), \
      (Cfp), (Cbp), (basep), (scalep), (N), (K), (N) / (BN), (mode))

  // --- mamba branch ---
  mix_rms_kernel<<<NT_, 256, 0, stream>>>(x, x, resid_mix_m, xm, nbb, xmb);
  GEMM(128, nbb, o_in, (float*)0, vg, (const float*)0, (const float*)0, 4096, 1024, 2);
  GEMM(128, xmb, o_B, (float*)0, BCm, (const float*)0, (const float*)0, 2048, 1024, 2);
  conv_silu_kernel<<<NT_ * DI_ / 256, 256, 0, stream>>>(vg, conv_w, conv_b, xv);
  scanA1_kernel<<<B_ * HS_ * NC_, 256, 0, stream>>>(xv, BCm, dt_bias, A_log, st);
  scanA2_kernel<<<B_ * HS_ * NC_, 256, 0, stream>>>(xv, BCm, dt_bias, A_log, D_param, xv);
  scanB1_kernel<<<B_ * HS_ * 4, 256, 0, stream>>>(st, dt_bias, A_log);
  scanB2_kernel<<<B_ * HS_ * NC_, 256, 0, stream>>>(BCm, st, vg, dt_bias, A_log, xv, ybb);
  GEMM(64, ybb, o_out, xm, (__hip_bfloat16*)0, xm, mamba_scale, 1024, 2048, 3);
  // --- mamba MLP ---
  rms_kernel<<<NT_, 256, 0, stream>>>(xm, nbb);
  GEMM(128, nbb, o_mfc, (float*)0, hb, (const float*)0, (const float*)0, 4096, 1024, 1);
  GEMM(64, hb, o_mpj, xm, (__hip_bfloat16*)0, xm, m_mlp_scale, 1024, 4096, 3);
  // --- attention branch ---
  mix_rms_kernel<<<NT_, 256, 0, stream>>>(xm, x, resid_mix_a, xm, nbb, (__hip_bfloat16*)0);
  GEMM(64, nbb, o_qkv, qkvf, (__hip_bfloat16*)0, (const float*)0, (const float*)0, 1536, 1024, 0);
  rope_fill_kernel<<<L_ * 32 / 256, 256, 0, stream>>>(cosb, sinb);
  qknorm_rope_bf16_kernel<<<NT_ * HA_ / 4, 256, 0, stream>>>(qkvf, 1536, 0, qbb, HA_, cosb, sinb, q_gain);
  qknorm_rope_bf16_kernel<<<NT_ * HKV_ / 4, 256, 0, stream>>>(qkvf, 1536, 1024, kbb, HKV_, cosb, sinb, (const float*)0);
  transpose_cvt<<<dim3(256 / 32, 2048 / 32), 256, 0, stream>>>(qkvf + 1280, vtb, 2048, 256, 1536);
  transpose_cvt<<<dim3(256 / 32, 2048 / 32), 256, 0, stream>>>(qkvf + (size_t)L_ * 1536 + 1280, vtb + (size_t)256 * L_, 2048, 256, 1536);
  attn_mfma_kernel<<<B_ * HA_ * 16, 256, 0, stream>>>(
      (const unsigned short*)qbb, (const unsigned short*)kbb, (const unsigned short*)vtb,
      q_gain, aob);
  GEMM(64, aob, o_o, xm, (__hip_bfloat16*)0, xm, attn_scale, 1024, 1024, 3);
  // --- attention MLP ---
  rms_kernel<<<NT_, 256, 0, stream>>>(xm, nbb);
  GEMM(128, nbb, o_afc, (float*)0, hb, (const float*)0, (const float*)0, 4096, 1024, 1);
  GEMM(64, hb, o_apj, out, (__hip_bfloat16*)0, xm, a_mlp_scale, 1024, 4096, 3);
#undef GEMM
}

// Round 9
// 680.622 us; speedup vs baseline: 6.9406x; 1.0413x over previous
//
#include <hip/hip_runtime.h>
#include <hip/hip_bf16.h>
#include <math.h>

#define D_ 1024
#define DI_ 2048
#define HS_ 16
#define PS_ 128
#define NS_ 64
#define HA_ 16
#define HKV_ 4
#define PA_ 64
#define B_ 2
#define L_ 2048
#define NT_ 4096          // B_*L_
#define NC_ 32            // L_/64
#define RMS_EPS_ 1.1920929e-7f

typedef __attribute__((ext_vector_type(8))) short short8;
typedef __attribute__((ext_vector_type(4))) float f32x4;

#define GLOAD_LDS16(gp, lp)                                                        \
  __builtin_amdgcn_global_load_lds(                                               \
      (const __attribute__((address_space(1))) unsigned int*)(gp),                \
      (__attribute__((address_space(3))) unsigned int*)(lp), 16, 0, 0)

// ---------------- transpose + fp32->bf16: W[K rows x N cols, row-stride ldw] -> Wt[N][K] ----------------
__global__ __launch_bounds__(256) void transpose_cvt(
    const float* __restrict__ W, __hip_bfloat16* __restrict__ Wt, int K, int N, int ldw) {
  __shared__ float t[32][33];
  int n0 = blockIdx.x * 32, k0 = blockIdx.y * 32;
  int tx = threadIdx.x & 31, ty = threadIdx.x >> 5;
#pragma unroll
  for (int i = 0; i < 4; i++)
    t[ty + i * 8][tx] = W[(size_t)(k0 + ty + i * 8) * ldw + n0 + tx];
  __syncthreads();
#pragma unroll
  for (int i = 0; i < 4; i++)
    Wt[(size_t)(n0 + ty + i * 8) * K + k0 + tx] = __float2bfloat16(t[tx][ty + i * 8]);
}

// ---------------- 256x256 tile, BK=32, 3-stage pipelined bf16 GEMM ----------------
// M=4096 fixed (16 row-tiles), N=4096 (16 col-tiles). 512 thr = 8 waves (2Mw x 4Nw).
// Raw s_barrier + counted vmcnt(4): 2 K-tiles always in flight (T3/T4).
// MODE 1: relu^2 -> bf16;  MODE 2: bf16.
template<int MODE>
__global__ __launch_bounds__(512) void gemm256_k32(
    const unsigned short* __restrict__ A, const unsigned short* __restrict__ Wt,
    __hip_bfloat16* __restrict__ Cb, int N, int K) {
  __shared__ unsigned short As[3][256 * 32];   // 3 x 16 KB
  __shared__ unsigned short Bs[3][256 * 32];   // 3 x 16 KB
  // XCD-rect swizzle: 16x16 tile grid, 8 rects of 8bm x 4bn
  int lid = blockIdx.x;
  int x = lid & 7, r = lid >> 3;               // r in 0..31
  int bm = ((x >> 2) * 8 + (r & 7)) * 256;
  int bn = ((x & 3) * 4 + (r >> 3)) * 256;
  int tid = threadIdx.x;
  int w = tid >> 6, l = tid & 63;
  int wr = w >> 2, wc = w & 3;                 // 2 x 4 waves
  int l15 = l & 15, lg = l >> 4;               // lg = k-chunk 0..3
  int rr = tid >> 2, ss = tid & 3;             // staging: row rr/rr+128, chunk ss

  f32x4 acc[8][4];
#pragma unroll
  for (int i = 0; i < 8; i++)
#pragma unroll
    for (int j = 0; j < 4; j++) acc[i][j] = (f32x4){0.f, 0.f, 0.f, 0.f};

  auto STAGE = [&](int kt, int nb) {
    int k0 = kt * 32;
#pragma unroll
    for (int p = 0; p < 2; p++) {
      int row = p * 128 + rr;
      int kq = ss ^ ((row >> 1) & 3);          // pre-swizzled source chunk
      GLOAD_LDS16(A + (size_t)(bm + row) * K + k0 + kq * 8, &As[nb][row * 32 + ss * 8]);
    }
#pragma unroll
    for (int p = 0; p < 2; p++) {
      int row = p * 128 + rr;
      int kq = ss ^ ((row >> 1) & 3);
      GLOAD_LDS16(Wt + (size_t)(bn + row) * K + k0 + kq * 8, &Bs[nb][row * 32 + ss * 8]);
    }
  };

  int KT = K >> 5;
  STAGE(0, 0);
  STAGE(1, 1);
  int buf = 0;
  for (int t = 0; t < KT; ++t) {
    asm volatile("s_waitcnt vmcnt(4)" ::: "memory");   // own S(t) complete; S(t+1) may fly
    __builtin_amdgcn_s_barrier();                      // all waves: S(t) in LDS; prior reads done
    __builtin_amdgcn_sched_barrier(0);
    if (t + 2 < KT) STAGE(t + 2, (t + 2) % 3);
    // compute tile t from buf
    short8 bf[4];
#pragma unroll
    for (int j = 0; j < 4; j++) {
      int row = wc * 64 + j * 16 + l15;
      bf[j] = *(const short8*)&Bs[buf][row * 32 + ((lg ^ ((row >> 1) & 3)) << 3)];
    }
#pragma unroll
    for (int i = 0; i < 8; i++) {
      int row = wr * 128 + i * 16 + l15;
      short8 af = *(const short8*)&As[buf][row * 32 + ((lg ^ ((row >> 1) & 3)) << 3)];
#pragma unroll
      for (int j = 0; j < 4; j++)
        acc[i][j] = __builtin_amdgcn_mfma_f32_16x16x32_bf16(af, bf[j], acc[i][j], 0, 0, 0);
    }
    buf = (buf + 1) % 3;
  }
  // epilogue
#pragma unroll
  for (int i = 0; i < 8; i++)
#pragma unroll
    for (int j = 0; j < 4; j++) {
      int gr = bm + wr * 128 + i * 16 + lg * 4;
      int gc = bn + wc * 64 + j * 16 + l15;
#pragma unroll
      for (int reg = 0; reg < 4; reg++) {
        float v = acc[i][j][reg];
        if (MODE == 1) { v = fmaxf(v, 0.f); v = v * v; }
        Cb[(size_t)(gr + reg) * N + gc] = __float2bfloat16(v);
      }
    }
}

// ---------------- bf16 MFMA GEMM, double-buffered, tile 128 x BN ----------------
// mode 0: f32 out; 1: relu^2 -> bf16; 2: bf16; 3: f32 out = base + scale[col]*acc
template<int BN>
__global__ __launch_bounds__(256) void gemm_bf16_t(
    const unsigned short* __restrict__ A, const unsigned short* __restrict__ Wt,
    float* __restrict__ Cf, __hip_bfloat16* __restrict__ Cb,
    const float* __restrict__ baseb, const float* __restrict__ scale,
    int N, int K, int gn, int mode) {
  constexpr int nWc = BN / 64;
  constexpr int nWr = 4 / nWc;
  constexpr int MF  = 8 / nWr;
  __shared__ unsigned short As[2][128 * 64];
  __shared__ unsigned short Bs[2][BN * 64];
  int lid = blockIdx.x;
  int x = lid & 7, r = lid >> 3;
  int RN = gn >> 2;
  int bm = ((x >> 2) * 16 + (r & 15)) * 128;
  int bn = ((x & 3) * RN + (r >> 4)) * BN;
  int tid = threadIdx.x;
  int w = tid >> 6, l = tid & 63;
  int wr = w / nWc, wc = w % nWc;
  int l15 = l & 15, lg = l >> 4;
  f32x4 acc[MF][4];
#pragma unroll
  for (int i = 0; i < MF; i++)
#pragma unroll
    for (int j = 0; j < 4; j++) acc[i][j] = (f32x4){0.f, 0.f, 0.f, 0.f};
  int r_ = tid >> 3;
  int s_ = tid & 7;

  auto STAGE = [&](int k0, int nb) {
#pragma unroll
    for (int i = 0; i < 4; i++) {
      int rr = i * 32 + r_;
      int kq = s_ ^ (rr & 7);
      GLOAD_LDS16(A + (size_t)(bm + rr) * K + k0 + kq * 8, &As[nb][rr * 64 + s_ * 8]);
    }
#pragma unroll
    for (int i = 0; i < BN / 32; i++) {
      int rr = i * 32 + r_;
      int kq = s_ ^ (rr & 7);
      GLOAD_LDS16(Wt + (size_t)(bn + rr) * K + k0 + kq * 8, &Bs[nb][rr * 64 + s_ * 8]);
    }
  };

  STAGE(0, 0);
  __syncthreads();
  int cur = 0;
  for (int k0 = 0; k0 < K; k0 += 64) {
    if (k0 + 64 < K) STAGE(k0 + 64, cur ^ 1);
#pragma unroll
    for (int h = 0; h < 2; h++) {
      short8 af[MF], bfr[4];
#pragma unroll
      for (int i = 0; i < MF; i++) {
        int row = wr * (16 * MF) + i * 16 + l15;
        int c = h * 4 + lg;
        af[i] = *(const short8*)&As[cur][row * 64 + ((c ^ (row & 7)) << 3)];
      }
#pragma unroll
      for (int j = 0; j < 4; j++) {
        int row = wc * 64 + j * 16 + l15;
        int c = h * 4 + lg;
        bfr[j] = *(const short8*)&Bs[cur][row * 64 + ((c ^ (row & 7)) << 3)];
      }
#pragma unroll
      for (int i = 0; i < MF; i++)
#pragma unroll
        for (int j = 0; j < 4; j++)
          acc[i][j] = __builtin_amdgcn_mfma_f32_16x16x32_bf16(af[i], bfr[j], acc[i][j], 0, 0, 0);
    }
    __syncthreads();
    cur ^= 1;
  }
  int rb = lg * 4, cb2 = l15;
#pragma unroll
  for (int i = 0; i < MF; i++)
#pragma unroll
    for (int j = 0; j < 4; j++) {
      int gr = bm + wr * (16 * MF) + i * 16 + rb;
      int gc = bn + wc * 64 + j * 16 + cb2;
#pragma unroll
      for (int reg = 0; reg < 4; reg++) {
        float v = acc[i][j][reg];
        size_t idx = (size_t)(gr + reg) * N + gc;
        if (mode == 0) {
          Cf[idx] = v;
        } else if (mode == 1) {
          v = fmaxf(v, 0.f);
          Cb[idx] = __float2bfloat16(v * v);
        } else if (mode == 2) {
          Cb[idx] = __float2bfloat16(v);
        } else {
          Cf[idx] = baseb[idx] + scale[gc] * v;
        }
      }
    }
}

// ---------------- mix + rmsnorm ----------------
__global__ __launch_bounds__(256) void mix_rms_kernel(
    const float* __restrict__ a, const float* __restrict__ b2,
    const float* __restrict__ mix, float* __restrict__ xout,
    __hip_bfloat16* __restrict__ nbf, __hip_bfloat16* __restrict__ rawbf) {
  int row = blockIdx.x;
  size_t base = (size_t)row * D_;
  float v[4]; float ss = 0.f;
#pragma unroll
  for (int i = 0; i < 4; i++) {
    int d = threadIdx.x + i * 256;
    float val = mix[d] * a[base + d] + mix[D_ + d] * b2[base + d];
    v[i] = val; ss += val * val;
  }
  for (int o = 32; o > 0; o >>= 1) ss += __shfl_down(ss, o, 64);
  __shared__ float red[4];
  if ((threadIdx.x & 63) == 0) red[threadIdx.x >> 6] = ss;
  __syncthreads();
  float inv = rsqrtf((red[0] + red[1] + red[2] + red[3]) * (1.f / D_) + RMS_EPS_);
#pragma unroll
  for (int i = 0; i < 4; i++) {
    int d = threadIdx.x + i * 256;
    xout[base + d] = v[i];
    nbf[base + d] = __float2bfloat16(v[i] * inv);
    if (rawbf) rawbf[base + d] = __float2bfloat16(v[i]);
  }
}

__global__ __launch_bounds__(256) void rms_kernel(
    const float* __restrict__ a, __hip_bfloat16* __restrict__ nbf) {
  int row = blockIdx.x;
  size_t base = (size_t)row * D_;
  float v[4]; float ss = 0.f;
#pragma unroll
  for (int i = 0; i < 4; i++) {
    int d = threadIdx.x + i * 256;
    float val = a[base + d];
    v[i] = val; ss += val * val;
  }
  for (int o = 32; o > 0; o >>= 1) ss += __shfl_down(ss, o, 64);
  __shared__ float red[4];
  if ((threadIdx.x & 63) == 0) red[threadIdx.x >> 6] = ss;
  __syncthreads();
  float inv = rsqrtf((red[0] + red[1] + red[2] + red[3]) * (1.f / D_) + RMS_EPS_);
#pragma unroll
  for (int i = 0; i < 4; i++) {
    int d = threadIdx.x + i * 256;
    nbf[base + d] = __float2bfloat16(v[i] * inv);
  }
}

// ---------------- depthwise causal conv (KC=4) + SiLU; vg bf16 [NT][4096] cols 0..2047 ----------------
__global__ __launch_bounds__(256) void conv_silu_kernel(
    const __hip_bfloat16* __restrict__ vg, const float* __restrict__ cw,
    const float* __restrict__ cb, float* __restrict__ xv) {
  int idx = blockIdx.x * 256 + threadIdx.x;
  int c = idx & (DI_ - 1);
  int bl = idx >> 11;
  int l = bl & (L_ - 1);
  float acc = cb[c];
  float w0 = cw[c * 4 + 0], w1 = cw[c * 4 + 1], w2 = cw[c * 4 + 2], w3 = cw[c * 4 + 3];
  size_t rb = (size_t)bl * 4096 + c;
  if (l >= 3) acc += __bfloat162float(vg[rb - (size_t)3 * 4096]) * w0;
  if (l >= 2) acc += __bfloat162float(vg[rb - (size_t)2 * 4096]) * w1;
  if (l >= 1) acc += __bfloat162float(vg[rb - (size_t)1 * 4096]) * w2;
  acc += __bfloat162float(vg[rb]) * w3;
  xv[idx] = acc / (1.f + __expf(-acc));
}

// ---------------- scan pass A1; BC combined [NT][2048]: B at +0 ----------------
__global__ __launch_bounds__(256) void scanA1_kernel(
    const float* __restrict__ xv, const __hip_bfloat16* __restrict__ BCm,
    const float* __restrict__ dt_bias, const float* __restrict__ A_log,
    float* __restrict__ st) {
  __shared__ __align__(16) float sm[4096 + 8192];
  float* Bs = sm;
  float* Xs = sm + 4096;
  int blk = blockIdx.x;
  int c = blk & 31, h = (blk >> 5) & 15, b = blk >> 9;
  float dt = log1pf(__expf(dt_bias[h]));
  float adt = -__expf(A_log[h]) * dt;
  int tid = threadIdx.x;
  int l0 = c * 64;
  size_t rB = ((size_t)(b * L_ + l0)) * 2048 + h * NS_;
#pragma unroll
  for (int i = 0; i < 16; i++) {
    int e = tid + i * 256;
    int t = e >> 6, n = e & 63;
    Bs[t * 64 + n] = __bfloat162float(BCm[rB + (size_t)t * 2048 + n]);
  }
  size_t rX = ((size_t)(b * L_ + l0)) * DI_ + h * PS_;
#pragma unroll
  for (int i = 0; i < 32; i++) {
    int e = tid + i * 256;
    int t = e >> 7, p = e & 127;
    Xs[t * 128 + p] = xv[rX + (size_t)t * DI_ + p];
  }
  __syncthreads();
  int pg = tid & 31;
  int ng = (tid >> 5) << 3;
  float acc[8][4];
#pragma unroll
  for (int nn = 0; nn < 8; nn++)
#pragma unroll
    for (int i = 0; i < 4; i++) acc[nn][i] = 0.f;
  for (int t = 0; t < 64; t++) {
    float dr = __expf(adt * (float)(63 - t));
    float4 x4 = *(const float4*)&Xs[t * 128 + pg * 4];
    float xd0 = x4.x * dr, xd1 = x4.y * dr, xd2 = x4.z * dr, xd3 = x4.w * dr;
#pragma unroll
    for (int nn = 0; nn < 8; nn++) {
      float bv = Bs[t * 64 + ng + nn];
      acc[nn][0] += bv * xd0; acc[nn][1] += bv * xd1;
      acc[nn][2] += bv * xd2; acc[nn][3] += bv * xd3;
    }
  }
  size_t sb = ((size_t)((b * HS_ + h) * NC_ + c)) * (NS_ * PS_);
#pragma unroll
  for (int nn = 0; nn < 8; nn++) {
    *(float4*)&st[sb + (size_t)(ng + nn) * PS_ + pg * 4] =
        make_float4(acc[nn][0] * dt, acc[nn][1] * dt, acc[nn][2] * dt, acc[nn][3] * dt);
  }
}

// ---------------- scan pass A2; BC combined: B at +0, C at +1024 ----------------
__global__ __launch_bounds__(256) void scanA2_kernel(
    const float* __restrict__ xv, const __hip_bfloat16* __restrict__ BCm,
    const float* __restrict__ dt_bias,
    const float* __restrict__ A_log, const float* __restrict__ D_param,
    float* __restrict__ y) {
  __shared__ __align__(16) float sm[4160 + 8192];
  float* Cb = sm;
  float* Bs = sm + 4160;
  float* Xs = sm + 4160;
  int blk = blockIdx.x;
  int c = blk & 31, h = (blk >> 5) & 15, b = blk >> 9;
  float dt = log1pf(__expf(dt_bias[h]));
  float adt = -__expf(A_log[h]) * dt;
  float Dp = D_param[h];
  int tid = threadIdx.x;
  int l0 = c * 64;
  size_t rB = ((size_t)(b * L_ + l0)) * 2048 + h * NS_;
#pragma unroll
  for (int i = 0; i < 16; i++) {
    int e = tid + i * 256;
    int t = e >> 6, n = e & 63;
    Bs[t * 64 + n] = __bfloat162float(BCm[rB + (size_t)t * 2048 + n]);
    Cb[t * 65 + n] = __bfloat162float(BCm[rB + 1024 + (size_t)t * 2048 + n]);
  }
  __syncthreads();
  int q = tid >> 2;
  int kb = (tid & 3) << 4;
  float cbl[16];
#pragma unroll
  for (int kk = 0; kk < 16; kk++) {
    int k = kb + kk;
    float a = 0.f;
    if (k <= q) {
      for (int n = 0; n < 64; n++) a += Cb[q * 65 + n] * Bs[k * 64 + n];
      a *= __expf(adt * (float)(q - k));
    }
    cbl[kk] = a;
  }
  __syncthreads();
#pragma unroll
  for (int kk = 0; kk < 16; kk++) Cb[q * 65 + kb + kk] = cbl[kk];
  size_t rX = ((size_t)(b * L_ + l0)) * DI_ + h * PS_;
#pragma unroll
  for (int i = 0; i < 32; i++) {
    int e = tid + i * 256;
    int t = e >> 7, p = e & 127;
    Xs[t * 128 + p] = xv[rX + (size_t)t * DI_ + p];
  }
  __syncthreads();
  int pg = tid & 31;
  int qg = (tid >> 5) << 3;
  float acc[8][4];
#pragma unroll
  for (int qq = 0; qq < 8; qq++)
#pragma unroll
    for (int i = 0; i < 4; i++) acc[qq][i] = 0.f;
  for (int k = 0; k < 64; k++) {
    float4 x4 = *(const float4*)&Xs[k * 128 + pg * 4];
#pragma unroll
    for (int qq = 0; qq < 8; qq++) {
      float s = Cb[(qg + qq) * 65 + k];
      acc[qq][0] += s * x4.x; acc[qq][1] += s * x4.y;
      acc[qq][2] += s * x4.z; acc[qq][3] += s * x4.w;
    }
  }
#pragma unroll
  for (int qq = 0; qq < 8; qq++) {
    int qr = qg + qq;
    float4 xq = *(const float4*)&Xs[qr * 128 + pg * 4];
    size_t yo = ((size_t)(b * L_ + l0 + qr)) * DI_ + h * PS_ + pg * 4;
    *(float4*)&y[yo] = make_float4(acc[qq][0] * dt + Dp * xq.x,
                                   acc[qq][1] * dt + Dp * xq.y,
                                   acc[qq][2] * dt + Dp * xq.z,
                                   acc[qq][3] * dt + Dp * xq.w);
  }
}

// ---------------- scan pass B1: inter-chunk recurrence, 128 blocks ----------------
__global__ __launch_bounds__(256) void scanB1_kernel(
    float* __restrict__ st, const float* __restrict__ dt_bias,
    const float* __restrict__ A_log) {
  int slice = blockIdx.x & 3;
  int h = (blockIdx.x >> 2) & 15, b = blockIdx.x >> 6;
  float dt = log1pf(__expf(dt_bias[h]));
  float adt = -__expf(A_log[h]) * dt;
  float cdec = __expf(adt * 64.f);
  size_t base = ((size_t)(b * HS_ + h)) * NC_ * (NS_ * PS_) + slice * 2048 + threadIdx.x;
  float hreg[8];
#pragma unroll
  for (int j = 0; j < 8; j++) hreg[j] = 0.f;
  for (int c = 0; c < NC_; c++) {
    size_t o = base + (size_t)c * (NS_ * PS_);
#pragma unroll
    for (int j = 0; j < 8; j++) {
      float tmp = st[o + (size_t)j * 256];
      st[o + (size_t)j * 256] = hreg[j];
      hreg[j] = cdec * hreg[j] + tmp;
    }
  }
}

// ---------------- scan pass B2: y_off + gate SiLU -> bf16; C at +1024 ----------------
__global__ __launch_bounds__(256) void scanB2_kernel(
    const __hip_bfloat16* __restrict__ BCm, const float* __restrict__ st,
    const __hip_bfloat16* __restrict__ vg, const float* __restrict__ dt_bias,
    const float* __restrict__ A_log, const float* __restrict__ y,
    __hip_bfloat16* __restrict__ yout) {
  __shared__ float Cs[64 * 64];
  __shared__ __align__(16) float Hs[64 * 128];
  int blk = blockIdx.x;
  int c = blk & 31, h = (blk >> 5) & 15, b = blk >> 9;
  float dt = log1pf(__expf(dt_bias[h]));
  float adt = -__expf(A_log[h]) * dt;
  int tid = threadIdx.x;
  int l0 = c * 64;
  size_t rC = ((size_t)(b * L_ + l0)) * 2048 + 1024 + h * NS_;
#pragma unroll
  for (int i = 0; i < 16; i++) {
    int e = tid + i * 256;
    int t = e >> 6, n = e & 63;
    Cs[t * 64 + n] = __bfloat162float(BCm[rC + (size_t)t * 2048 + n]);
  }
  size_t sb = ((size_t)((b * HS_ + h) * NC_ + c)) * (NS_ * PS_);
#pragma unroll
  for (int i = 0; i < 32; i++) {
    int e = tid + i * 256;
    Hs[e] = st[sb + e];
  }
  __syncthreads();
  int pg = tid & 31;
  int tg = (tid >> 5) << 3;
  float acc[8][4];
#pragma unroll
  for (int tt = 0; tt < 8; tt++)
#pragma unroll
    for (int i = 0; i < 4; i++) acc[tt][i] = 0.f;
  for (int n = 0; n < 64; n++) {
    float4 h4 = *(const float4*)&Hs[n * 128 + pg * 4];
#pragma unroll
    for (int tt = 0; tt < 8; tt++) {
      float cv = Cs[(tg + tt) * 64 + n];
      acc[tt][0] += cv * h4.x; acc[tt][1] += cv * h4.y;
      acc[tt][2] += cv * h4.z; acc[tt][3] += cv * h4.w;
    }
  }
#pragma unroll
  for (int tt = 0; tt < 8; tt++) {
    int t = tg + tt;
    float dout = __expf(adt * (float)(t + 1));
    size_t row = (size_t)(b * L_ + l0 + t);
#pragma unroll
    for (int i = 0; i < 4; i++) {
      int p = pg * 4 + i;
      float g = __bfloat162float(vg[row * 4096 + 2048 + h * PS_ + p]);
      float yv = y[row * DI_ + h * PS_ + p] + acc[tt][i] * dout;
      yout[row * DI_ + h * PS_ + p] = __float2bfloat16(yv * (g / (1.f + __expf(-g))));
    }
  }
}

// ---------------- rope tables ----------------
__global__ void rope_fill_kernel(float* __restrict__ cosb, float* __restrict__ sinb) {
  int idx = blockIdx.x * 256 + threadIdx.x;
  int i = idx & 31, l = idx >> 5;
  float inv = __expf(-(2.0f * (float)i / (float)PA_) * logf(10000.0f));
  float ang = (float)l * inv;
  cosb[idx] = cosf(ang);
  sinb[idx] = sinf(ang);
}

// ---------------- per-head rmsnorm + rope (+gain), strided src -> packed bf16 dst ----------------
__global__ __launch_bounds__(256) void qknorm_rope_bf16_kernel(
    const float* __restrict__ src, int srcstride, int srcofs,
    __hip_bfloat16* __restrict__ dst, int nh,
    const float* __restrict__ cosb, const float* __restrict__ sinb,
    const float* __restrict__ gain) {
  int row = blockIdx.x * 4 + (threadIdx.x >> 6);
  int lane = threadIdx.x & 63;
  int h = row % nh;
  int tok = row / nh;
  int l = tok & (L_ - 1);
  float v = src[(size_t)tok * srcstride + srcofs + h * 64 + lane];
  float ss = v * v;
  for (int o = 32; o > 0; o >>= 1) ss += __shfl_xor(ss, o, 64);
  v *= rsqrtf(ss * (1.f / PA_) + RMS_EPS_);
  float partner = __shfl_xor(v, 32, 64);
  int i = lane & 31;
  float cth = cosb[l * 32 + i], sth = sinb[l * 32 + i];
  float out = (lane < 32) ? (v * cth + partner * sth) : (v * cth - partner * sth);
  if (gain) out *= gain[h];
  dst[(size_t)tok * (nh * 64) + h * 64 + lane] = __float2bfloat16(out);
}

// ---------------- causal GQA flash attention, bf16 MFMA ----------------
__global__ __launch_bounds__(256) void attn_mfma_kernel(
    const unsigned short* __restrict__ qb, const unsigned short* __restrict__ kb,
    const unsigned short* __restrict__ vt, const float* __restrict__ qgain,
    __hip_bfloat16* __restrict__ ao) {
  __shared__ unsigned short Ks[64][72];
  __shared__ unsigned short Vs[64][72];
  __shared__ unsigned short Psm[4][16][72];
  int blk = blockIdx.x;
  int qi = blk & 15;
  int h  = (blk >> 4) & 15;
  int b  = blk >> 8;
  int hk = h >> 2;
  int tid = threadIdx.x;
  int w = tid >> 6, l = tid & 63;
  int l15 = l & 15, lg = l >> 4;
  int r0 = tid >> 3, s0 = tid & 7;
  float mstat = 8.0f * fabsf(qgain[h]);
  const unsigned short* kbase = kb + (size_t)b * L_ * (HKV_ * PA_) + hk * PA_ + s0 * 8;
  const unsigned short* vbase = vt + ((size_t)(b * HKV_ + hk) * PA_) * L_ + s0 * 8;

  for (int pass = 0; pass < 2; pass++) {
    int qt = pass ? (31 - qi) : qi;
    int q0 = qt * 64;
    int qw = q0 + w * 16;
    short8 qf[2];
    {
      size_t qrow = ((size_t)(b * L_ + qw + l15)) * (HA_ * PA_) + h * PA_;
      qf[0] = *(const short8*)&qb[qrow + lg * 8];
      qf[1] = *(const short8*)&qb[qrow + 32 + lg * 8];
    }
    f32x4 o_acc[4];
#pragma unroll
    for (int db = 0; db < 4; db++) o_acc[db] = (f32x4){0.f, 0.f, 0.f, 0.f};
    f32x4 lsum = (f32x4){0.f, 0.f, 0.f, 0.f};
    int nkt = qt + 1;
    short8 kr0 = *(const short8*)&kbase[(size_t)r0 * (HKV_ * PA_)];
    short8 kr1 = *(const short8*)&kbase[(size_t)(r0 + 32) * (HKV_ * PA_)];
    short8 vr0 = *(const short8*)&vbase[(size_t)r0 * L_];
    short8 vr1 = *(const short8*)&vbase[(size_t)(r0 + 32) * L_];
    for (int kt = 0; kt < nkt; kt++) {
      int k0 = kt * 64;
      __syncthreads();
      *(short8*)&Ks[r0][s0 * 8] = kr0;
      *(short8*)&Ks[r0 + 32][s0 * 8] = kr1;
      *(short8*)&Vs[r0][s0 * 8] = vr0;
      *(short8*)&Vs[r0 + 32][s0 * 8] = vr1;
      if (kt + 1 < nkt) {
        int k1 = k0 + 64;
        kr0 = *(const short8*)&kbase[(size_t)(k1 + r0) * (HKV_ * PA_)];
        kr1 = *(const short8*)&kbase[(size_t)(k1 + r0 + 32) * (HKV_ * PA_)];
        vr0 = *(const short8*)&vbase[(size_t)r0 * L_ + k1];
        vr1 = *(const short8*)&vbase[(size_t)(r0 + 32) * L_ + k1];
      }
      __syncthreads();
      f32x4 s_acc[4];
#pragma unroll
      for (int kb2 = 0; kb2 < 4; kb2++) {
        short8 b0 = *(const short8*)&Ks[kb2 * 16 + l15][lg * 8];
        short8 b1 = *(const short8*)&Ks[kb2 * 16 + l15][32 + lg * 8];
        f32x4 s = (f32x4){0.f, 0.f, 0.f, 0.f};
        s = __builtin_amdgcn_mfma_f32_16x16x32_bf16(qf[0], b0, s, 0, 0, 0);
        s = __builtin_amdgcn_mfma_f32_16x16x32_bf16(qf[1], b1, s, 0, 0, 0);
        s_acc[kb2] = s;
      }
      bool diag = (kt == qt);
#pragma unroll
      for (int kb2 = 0; kb2 < 4; kb2++) {
        int key = k0 + kb2 * 16 + l15;
#pragma unroll
        for (int reg = 0; reg < 4; reg++) {
          float p = __expf(s_acc[kb2][reg] * 0.125f - mstat);
          if (diag && key > qw + lg * 4 + reg) p = 0.f;
          lsum[reg] += p;
          __hip_bfloat16 hv = __float2bfloat16(p);
          Psm[w][lg * 4 + reg][kb2 * 16 + l15] = *(unsigned short*)&hv;
        }
      }
      asm volatile("s_waitcnt lgkmcnt(0)" ::: "memory");
#pragma unroll
      for (int ks = 0; ks < 2; ks++) {
        short8 pa = *(const short8*)&Psm[w][l15][ks * 32 + lg * 8];
#pragma unroll
        for (int db = 0; db < 4; db++) {
          short8 vb8 = *(const short8*)&Vs[db * 16 + l15][ks * 32 + lg * 8];
          o_acc[db] = __builtin_amdgcn_mfma_f32_16x16x32_bf16(pa, vb8, o_acc[db], 0, 0, 0);
        }
      }
    }
#pragma unroll
    for (int of = 1; of < 16; of <<= 1) {
      lsum[0] += __shfl_xor(lsum[0], of, 64);
      lsum[1] += __shfl_xor(lsum[1], of, 64);
      lsum[2] += __shfl_xor(lsum[2], of, 64);
      lsum[3] += __shfl_xor(lsum[3], of, 64);
    }
#pragma unroll
    for (int reg = 0; reg < 4; reg++) {
      float invl = 1.0f / lsum[reg];
      size_t row = (size_t)(b * L_ + qw + lg * 4 + reg);
#pragma unroll
      for (int db = 0; db < 4; db++)
        ao[row * D_ + h * PA_ + db * 16 + l15] = __float2bfloat16(o_acc[db][reg] * invl);
    }
  }
}

// ---------------- host ----------------
extern "C" void kernel_launch(void* const* d_in, const int* in_sizes, int n_in,
                              void* d_out, int out_size, void* d_ws, size_t ws_size,
                              hipStream_t stream) {
  (void)in_sizes; (void)n_in; (void)out_size; (void)ws_size;
  const float* x           = (const float*)d_in[0];
  const float* in_proj_w   = (const float*)d_in[1];
  const float* conv_w      = (const float*)d_in[2];
  const float* conv_b      = (const float*)d_in[3];
  const float* B_proj_w    = (const float*)d_in[4];
  const float* C_proj_w    = (const float*)d_in[5];
  const float* dt_bias     = (const float*)d_in[6];
  const float* A_log       = (const float*)d_in[7];
  const float* D_param     = (const float*)d_in[8];
  const float* out_proj_w  = (const float*)d_in[9];
  const float* resid_mix_m = (const float*)d_in[10];
  const float* mamba_scale = (const float*)d_in[11];
  const float* m_fc_w      = (const float*)d_in[12];
  const float* m_proj_w    = (const float*)d_in[13];
  const float* m_mlp_scale = (const float*)d_in[14];
  const float* resid_mix_a = (const float*)d_in[15];
  const float* q_w         = (const float*)d_in[16];
  const float* k_w         = (const float*)d_in[17];
  const float* v_w         = (const float*)d_in[18];
  const float* o_w         = (const float*)d_in[19];
  const float* q_gain      = (const float*)d_in[20];
  const float* attn_scale  = (const float*)d_in[21];
  const float* a_fc_w      = (const float*)d_in[22];
  const float* a_proj_w    = (const float*)d_in[23];
  const float* a_mlp_scale = (const float*)d_in[24];
  float* ws  = (float*)d_ws;
  float* out = (float*)d_out;

  // ---- workspace layout (float units) ----
  float* xm    = ws;
  float* vgR   = ws + 4194304;
  float* xvR   = ws + 12582912;
  float* stR   = ws + 20971520;
  float* nbR   = ws + 29360128;
  float* xmbR  = ws + 31457280;
  float* BCR   = ws + 33554432;
  float* WtR   = ws + 37748736;
  float* cosb  = ws + 51642368;
  float* sinb  = cosb + 65536;

  __hip_bfloat16* vg  = (__hip_bfloat16*)vgR;
  float*          qkvf = vgR;
  float*          xv  = xvR;
  float*          st  = stR;
  __hip_bfloat16* hb  = (__hip_bfloat16*)stR;
  __hip_bfloat16* nbb = (__hip_bfloat16*)nbR;
  __hip_bfloat16* xmb = (__hip_bfloat16*)xmbR;
  __hip_bfloat16* ybb = (__hip_bfloat16*)nbR;
  __hip_bfloat16* BCm = (__hip_bfloat16*)BCR;
  __hip_bfloat16* qbb = (__hip_bfloat16*)xvR;
  __hip_bfloat16* kbb = (__hip_bfloat16*)(xvR + 2097152);
  __hip_bfloat16* vtb = (__hip_bfloat16*)(xvR + 2621440);
  __hip_bfloat16* aob = (__hip_bfloat16*)(xvR + 3145728);

  __hip_bfloat16* Wt = (__hip_bfloat16*)WtR;
  size_t o_in  = 0;
  size_t o_B   = o_in  + (size_t)4096 * 1024;
  size_t o_out = o_B   + (size_t)2048 * 1024;
  size_t o_mfc = o_out + (size_t)1024 * 2048;
  size_t o_mpj = o_mfc + (size_t)4096 * 1024;
  size_t o_qkv = o_mpj + (size_t)1024 * 4096;
  size_t o_o   = o_qkv + (size_t)1536 * 1024;
  size_t o_afc = o_o   + (size_t)1024 * 1024;
  size_t o_apj = o_afc + (size_t)4096 * 1024;

#define TCVT(Wp, off, K, N) \
  transpose_cvt<<<dim3((N) / 32, (K) / 32), 256, 0, stream>>>((Wp), Wt + (off), (K), (N), (N))
  TCVT(in_proj_w,  o_in,  1024, 4096);
  TCVT(B_proj_w,   o_B,   1024, 1024);
  TCVT(C_proj_w,   o_B + (size_t)1024 * 1024, 1024, 1024);
  TCVT(out_proj_w, o_out, 2048, 1024);
  TCVT(m_fc_w,     o_mfc, 1024, 4096);
  TCVT(m_proj_w,   o_mpj, 4096, 1024);
  TCVT(q_w,        o_qkv, 1024, 1024);
  TCVT(k_w,        o_qkv + (size_t)1024 * 1024, 1024, 256);
  TCVT(v_w,        o_qkv + (size_t)1280 * 1024, 1024, 256);
  TCVT(o_w,        o_o,   1024, 1024);
  TCVT(a_fc_w,     o_afc, 1024, 4096);
  TCVT(a_proj_w,   o_apj, 4096, 1024);
#undef TCVT

#define GEMM(BN, Abuf, Woff, Cfp, Cbp, basep, scalep, N, K, mode) \
  gemm_bf16_t<BN><<<32 * ((N) / (BN)), 256, 0, stream>>>( \
      (const unsigned short*)(Abuf), (const unsigned short*)(Wt + (Woff)), \
      (Cfp), (Cbp), (basep), (scalep), (N), (K), (N) / (BN), (mode))
#define GEMM256(MODE, Abuf, Woff, Cbp) \
  gemm256_k32<MODE><<<256, 512, 0, stream>>>( \
      (const unsigned short*)(Abuf), (const unsigned short*)(Wt + (Woff)), \
      (Cbp), 4096, 1024)

  // --- mamba branch ---
  mix_rms_kernel<<<NT_, 256, 0, stream>>>(x, x, resid_mix_m, xm, nbb, xmb);
  GEMM256(2, nbb, o_in, vg);
  GEMM(128, xmb, o_B, (float*)0, BCm, (const float*)0, (const float*)0, 2048, 1024, 2);
  conv_silu_kernel<<<NT_ * DI_ / 256, 256, 0, stream>>>(vg, conv_w, conv_b, xv);
  scanA1_kernel<<<B_ * HS_ * NC_, 256, 0, stream>>>(xv, BCm, dt_bias, A_log, st);
  scanA2_kernel<<<B_ * HS_ * NC_, 256, 0, stream>>>(xv, BCm, dt_bias, A_log, D_param, xv);
  scanB1_kernel<<<B_ * HS_ * 4, 256, 0, stream>>>(st, dt_bias, A_log);
  scanB2_kernel<<<B_ * HS_ * NC_, 256, 0, stream>>>(BCm, st, vg, dt_bias, A_log, xv, ybb);
  GEMM(64, ybb, o_out, xm, (__hip_bfloat16*)0, xm, mamba_scale, 1024, 2048, 3);
  // --- mamba MLP ---
  rms_kernel<<<NT_, 256, 0, stream>>>(xm, nbb);
  GEMM256(1, nbb, o_mfc, hb);
  GEMM(64, hb, o_mpj, xm, (__hip_bfloat16*)0, xm, m_mlp_scale, 1024, 4096, 3);
  // --- attention branch ---
  mix_rms_kernel<<<NT_, 256, 0, stream>>>(xm, x, resid_mix_a, xm, nbb, (__hip_bfloat16*)0);
  GEMM(64, nbb, o_qkv, qkvf, (__hip_bfloat16*)0, (const float*)0, (const float*)0, 1536, 1024, 0);
  rope_fill_kernel<<<L_ * 32 / 256, 256, 0, stream>>>(cosb, sinb);
  qknorm_rope_bf16_kernel<<<NT_ * HA_ / 4, 256, 0, stream>>>(qkvf, 1536, 0, qbb, HA_, cosb, sinb, q_gain);
  qknorm_rope_bf16_kernel<<<NT_ * HKV_ / 4, 256, 0, stream>>>(qkvf, 1536, 1024, kbb, HKV_, cosb, sinb, (const float*)0);
  transpose_cvt<<<dim3(256 / 32, 2048 / 32), 256, 0, stream>>>(qkvf + 1280, vtb, 2048, 256, 1536);
  transpose_cvt<<<dim3(256 / 32, 2048 / 32), 256, 0, stream>>>(qkvf + (size_t)L_ * 1536 + 1280, vtb + (size_t)256 * L_, 2048, 256, 1536);
  attn_mfma_kernel<<<B_ * HA_ * 16, 256, 0, stream>>>(
      (const unsigned short*)qbb, (const unsigned short*)kbb, (const unsigned short*)vtb,
      q_gain, aob);
  GEMM(64, aob, o_o, xm, (__hip_bfloat16*)0, xm, attn_scale, 1024, 1024, 3);
  // --- attention MLP ---
  rms_kernel<<<NT_, 256, 0, stream>>>(xm, nbb);
  GEMM256(1, nbb, o_afc, hb);
  GEMM(64, hb, o_apj, out, (__hip_bfloat16*)0, xm, a_mlp_scale, 1024, 4096, 3);
#undef GEMM
#undef GEMM256
}